// Round 1
// baseline (322.936 us; speedup 1.0000x reference)
//
#include <hip/hip_runtime.h>
#include <math.h>

#define BB   4
#define NN   8192
#define BN   (BB*NN)       // 32768 points per cloud-set; 8 clouds of 8192 total
#define KNN  10
#define G    32            // grid cells per dim
#define NCELLS (G*G*G)     // 32768 cells per cloud
#define GRID_LO (-5.0f)
#define H    0.3125f       // 10/32
#define INV_H 3.2f
#define RCAP 2             // rho<=2 region; beyond -> brute overflow

#define SEPS    5.9604645e-8f        // slamch('E') = 2^-24
#define SEPS2   (SEPS*SEPS)
#define SSAFMIN 1.1754944e-38f

__device__ __forceinline__ int cellc(float v) {
    int c = (int)floorf((v - GRID_LO) * INV_H);
    return min(G - 1, max(0, c));
}

// ---------------------------------------------------------------------------
// Kernel A: build P4[8][8192] = (x,y,z, bitcast orig-idx); clouds 0-3 = gt
// batches, 4-7 = pred[idx12] batches. Histogram cells + zero accumulators.
// ---------------------------------------------------------------------------
__global__ __launch_bounds__(256) void prep_kernel(
    const float* __restrict__ gt, const float* __restrict__ pred,
    const unsigned* __restrict__ idxw, float4* __restrict__ P4,
    int* __restrict__ hist, float* __restrict__ accum,
    unsigned* __restrict__ counter, int* __restrict__ ovf_count)
{
    __shared__ int s_is32;
    int tid = threadIdx.x;
    if (tid == 0) s_is32 = 0;
    __syncthreads();
    if (idxw[2*tid + 1] != 0u) s_is32 = 1;   // int64 => all high words 0
    __syncthreads();
    bool is64 = (s_is32 == 0);

    if (blockIdx.x == 0 && tid == 0) {
        *accum = 0.0f; *counter = 0u; *ovf_count = 0;
    }

    int point = blockIdx.x * 256 + tid;        // 0 .. 2*BN-1
    int pair = point >> 13;                    // 0..7
    int r    = point & (NN - 1);               // idx within cloud
    float x, y, z;
    if (point < BN) {
        const float* s = gt + (size_t)point*3;
        x = s[0]; y = s[1]; z = s[2];
    } else {
        int rr = point - BN;
        int b = rr >> 13;
        unsigned idx = is64 ? idxw[2*(size_t)rr] : idxw[rr];
        const float* s = pred + ((size_t)b*NN + idx)*3;
        x = s[0]; y = s[1]; z = s[2];
    }
    P4[point] = make_float4(x, y, z, __int_as_float(r));
    int cell = (cellc(z)*G + cellc(y))*G + cellc(x);
    atomicAdd(&hist[(size_t)pair*NCELLS + cell], 1);
}

// ---------------------------------------------------------------------------
// Kernel B: per-cloud exclusive scan -> combo[c] = int2(start, count).
// ---------------------------------------------------------------------------
__global__ __launch_bounds__(1024) void scan_kernel(
    const int* __restrict__ hist, int2* __restrict__ combo)
{
    int cloud = blockIdx.x;
    int tid = threadIdx.x;
    int lane = tid & 63, wid = tid >> 6;
    const int* h = hist + (size_t)cloud * NCELLS;
    int2* cb = combo + (size_t)cloud * NCELLS;

    int loc[32];
    int base = tid * 32;
    const int4* h4 = (const int4*)(h + base);
    int sum = 0;
    #pragma unroll
    for (int i = 0; i < 8; ++i) {
        int4 a = h4[i];
        loc[4*i+0] = a.x; loc[4*i+1] = a.y; loc[4*i+2] = a.z; loc[4*i+3] = a.w;
        sum += a.x + a.y + a.z + a.w;
    }
    // inclusive wave scan of sums
    int v = sum;
    #pragma unroll
    for (int off = 1; off < 64; off <<= 1) {
        int o = __shfl_up(v, off, 64);
        if (lane >= off) v += o;
    }
    __shared__ int ws[16], wsx[16];
    if (lane == 63) ws[wid] = v;
    __syncthreads();
    if (tid < 16) {
        int acc = 0;
        for (int i = 0; i < tid; ++i) acc += ws[i];
        wsx[tid] = acc;
    }
    __syncthreads();
    int run = (v - sum) + wsx[wid];            // exclusive prefix for this thread

    int4* cb4 = (int4*)(cb + base);            // 2 cells per int4 store
    #pragma unroll
    for (int i = 0; i < 16; ++i) {
        int4 o;
        o.x = run; o.y = loc[2*i];     run += loc[2*i];
        o.z = run; o.w = loc[2*i+1];   run += loc[2*i+1];
        cb4[i] = o;
    }
}

// ---------------------------------------------------------------------------
// Kernel C: scatter points into cell-sorted S.
// ---------------------------------------------------------------------------
__global__ __launch_bounds__(256) void scatter_kernel(
    const float4* __restrict__ P4, int* __restrict__ hist,
    const int2* __restrict__ combo, float4* __restrict__ S)
{
    int point = blockIdx.x * 256 + threadIdx.x;
    float4 p = P4[point];
    int pair = point >> 13;
    int cell = (cellc(p.z)*G + cellc(p.y))*G + cellc(p.x);
    int old = atomicSub(&hist[(size_t)pair*NCELLS + cell], 1);
    int pos = combo[(size_t)pair*NCELLS + cell].x + old - 1;
    S[(size_t)pair*NN + pos] = p;
}

// ---------------------------------------------------------------------------
// LAPACK ssyevd 3x3 path: ssytrd('L') + sorgtr + ssteqr('V'). Sign-faithful.
// (verified absmax 0.0 in rounds 2-18 — do not touch)
// ---------------------------------------------------------------------------
__device__ __forceinline__ float f_sign(float a, float b) {
    return copysignf(a, b);
}
__device__ __forceinline__ float slapy2(float x, float y) {
#pragma clang fp contract(off)
    float xa = fabsf(x), ya = fabsf(y);
    float w = fmaxf(xa, ya), z = fminf(xa, ya);
    if (z == 0.0f) return w;
    float t = z / w;
    return w * __fsqrt_rn(1.0f + t*t);
}
__device__ __forceinline__ void slartg_(float f, float g, float* cs, float* sn, float* r) {
#pragma clang fp contract(off)
    if (g == 0.0f)      { *cs = 1.0f; *sn = 0.0f; *r = f; }
    else if (f == 0.0f) { *cs = 0.0f; *sn = f_sign(1.0f, g); *r = fabsf(g); }
    else {
        float f1 = fabsf(f);
        float d = __fsqrt_rn(f*f + g*g);
        float p = 1.0f / d;
        *cs = f1 * p;
        *sn = g * f_sign(p, f);
        *r  = f_sign(d, f);
    }
}
__device__ void slaev2_(float a, float b, float c,
                        float* rt1, float* rt2, float* cs1, float* sn1) {
#pragma clang fp contract(off)
    float sm = a + c, df = a - c;
    float adf = fabsf(df);
    float tb = b + b;
    float ab = fabsf(tb);
    float acmx, acmn;
    if (fabsf(a) > fabsf(c)) { acmx = a; acmn = c; } else { acmx = c; acmn = a; }
    float rt;
    if (adf > ab)      { float t = ab/adf; rt = adf*__fsqrt_rn(1.0f + t*t); }
    else if (adf < ab) { float t = adf/ab; rt = ab*__fsqrt_rn(1.0f + t*t); }
    else               { rt = ab*__fsqrt_rn(2.0f); }
    int sgn1;
    if (sm < 0.0f)      { *rt1 = 0.5f*(sm - rt); sgn1 = -1;
                          *rt2 = (acmx / *rt1)*acmn - (b / *rt1)*b; }
    else if (sm > 0.0f) { *rt1 = 0.5f*(sm + rt); sgn1 = 1;
                          *rt2 = (acmx / *rt1)*acmn - (b / *rt1)*b; }
    else                { *rt1 = 0.5f*rt; *rt2 = -0.5f*rt; sgn1 = 1; }
    float cs; int sgn2;
    if (df >= 0.0f) { cs = df + rt; sgn2 = 1; } else { cs = df - rt; sgn2 = -1; }
    float acs = fabsf(cs);
    float c1, s1;
    if (acs > ab) { float ct = -tb/cs; s1 = 1.0f/__fsqrt_rn(1.0f + ct*ct); c1 = ct*s1; }
    else {
        if (ab == 0.0f) { c1 = 1.0f; s1 = 0.0f; }
        else { float tn = -cs/tb; c1 = 1.0f/__fsqrt_rn(1.0f + tn*tn); s1 = tn*c1; }
    }
    if (sgn1 == sgn2) { float tn = c1; c1 = -s1; s1 = tn; }
    *cs1 = c1; *sn1 = s1;
}

__device__ void eigh3_smallest(float c00, float c01, float c02,
                               float c11, float c12, float c22, float nv[3])
{
#pragma clang fp contract(off)
    // ---- ssytrd('L') ----
    float d[4], e[3], z[4][4];
    float tau1, v2 = 0.0f;
    float e1, d2, d3, e2;
    float alpha = c01, x = c02;
    if (x == 0.0f) {
        tau1 = 0.0f; e1 = alpha;
        d2 = c11; d3 = c22; e2 = c12;
    } else {
        float beta = -f_sign(slapy2(alpha, fabsf(x)), alpha);
        tau1 = (beta - alpha) / beta;
        v2 = x / (alpha - beta);
        e1 = beta;
        float w1 = tau1*(c11 + c12*v2);
        float w2 = tau1*(c12 + c22*v2);
        float al = -0.5f*tau1*(w1 + w2*v2);
        w1 = w1 + al;
        w2 = w2 + al*v2;
        d2 = (c11 - w1) - w1;
        e2 = (c12 - v2*w1) - w2;
        d3 = (c22 - v2*w2) - w2*v2;
    }
    d[1] = c00; d[2] = d2; d[3] = d3;
    e[1] = e1;  e[2] = e2;
    z[1][1] = 1.0f; z[1][2] = 0.0f; z[1][3] = 0.0f;
    z[2][1] = 0.0f; z[3][1] = 0.0f;
    z[2][2] = 1.0f - tau1;
    float mtv = -tau1*v2;
    z[2][3] = mtv; z[3][2] = mtv;
    z[3][3] = 1.0f + mtv*v2;

    // ---- ssteqr('V', 3) ----
    const int n = 3, nm1 = 2;
    int l1 = 1, jtot = 0;
    const int nmaxit = 90;
    float cw[3], sw[3];
    int guard = 0;
    while (guard++ < 64) {
        if (l1 > n) break;
        if (l1 > 1) e[l1-1] = 0.0f;
        int m = n;
        if (l1 <= nm1) {
            for (int mi = l1; mi <= nm1; ++mi) {
                float tst = fabsf(e[mi]);
                if (tst == 0.0f) { m = mi; break; }
                if (tst <= (__fsqrt_rn(fabsf(d[mi]))*__fsqrt_rn(fabsf(d[mi+1])))*SEPS) {
                    e[mi] = 0.0f; m = mi; break;
                }
            }
        }
        int l = l1;
        int lsv = l, lend = m, lendsv = lend;
        l1 = m + 1;
        if (lend == l) continue;
        if (fabsf(d[lend]) < fabsf(d[l])) { lend = lsv; l = lendsv; }

        if (lend > l) {
            // QL
            while (true) {
                int m_ = lend;
                if (l != lend) {
                    for (int mi = l; mi <= lend-1; ++mi) {
                        float em = e[mi];
                        float tst = em*em;
                        if (tst <= (SEPS2*fabsf(d[mi]))*fabsf(d[mi+1]) + SSAFMIN) { m_ = mi; break; }
                    }
                }
                if (m_ < lend) e[m_] = 0.0f;
                float p = d[l];
                if (m_ == l) {
                    d[l] = p; l = l + 1;
                    if (l <= lend) continue; else break;
                }
                if (m_ == l + 1) {
                    float rt1, rt2, cc, ss;
                    slaev2_(d[l], e[l], d[l+1], &rt1, &rt2, &cc, &ss);
                    for (int i = 1; i <= 3; ++i) {
                        float tmp = z[i][l+1];
                        z[i][l+1] = cc*tmp - ss*z[i][l];
                        z[i][l]   = ss*tmp + cc*z[i][l];
                    }
                    d[l] = rt1; d[l+1] = rt2; e[l] = 0.0f;
                    l = l + 2;
                    if (l <= lend) continue; else break;
                }
                if (jtot == nmaxit) break;
                jtot++;
                float g = (d[l+1] - p) / (2.0f*e[l]);
                float r = slapy2(g, 1.0f);
                g = d[m_] - p + (e[l] / (g + f_sign(r, g)));
                float s = 1.0f, c = 1.0f;
                p = 0.0f;
                for (int i = m_-1; i >= l; --i) {
                    float f = s*e[i];
                    float b = c*e[i];
                    slartg_(g, f, &c, &s, &r);
                    if (i != m_-1) e[i+1] = r;
                    g = d[i+1] - p;
                    r = (d[i] - g)*s + (2.0f*c)*b;
                    p = s*r;
                    d[i+1] = g + p;
                    g = c*r - b;
                    cw[i] = c; sw[i] = -s;
                }
                for (int j = m_-1; j >= l; --j) {
                    float cc = cw[j], ss = sw[j];
                    for (int i = 1; i <= 3; ++i) {
                        float tmp = z[i][j+1];
                        z[i][j+1] = cc*tmp - ss*z[i][j];
                        z[i][j]   = ss*tmp + cc*z[i][j];
                    }
                }
                d[l] = d[l] - p;
                e[l] = g;
            }
        } else {
            // QR
            while (true) {
                int m_ = lend;
                if (l != lend) {
                    for (int mi = l; mi >= lend+1; --mi) {
                        float em = e[mi-1];
                        float tst = em*em;
                        if (tst <= (SEPS2*fabsf(d[mi]))*fabsf(d[mi-1]) + SSAFMIN) { m_ = mi; break; }
                    }
                }
                if (m_ > lend) e[m_-1] = 0.0f;
                float p = d[l];
                if (m_ == l) {
                    d[l] = p; l = l - 1;
                    if (l >= lend) continue; else break;
                }
                if (m_ == l - 1) {
                    float rt1, rt2, cc, ss;
                    slaev2_(d[l-1], e[l-1], d[l], &rt1, &rt2, &cc, &ss);
                    for (int i = 1; i <= 3; ++i) {
                        float tmp = z[i][l];
                        z[i][l]   = cc*tmp - ss*z[i][l-1];
                        z[i][l-1] = ss*tmp + cc*z[i][l-1];
                    }
                    d[l-1] = rt1; d[l] = rt2; e[l-1] = 0.0f;
                    l = l - 2;
                    if (l >= lend) continue; else break;
                }
                if (jtot == nmaxit) break;
                jtot++;
                float g = (d[l-1] - p) / (2.0f*e[l-1]);
                float r = slapy2(g, 1.0f);
                g = d[m_] - p + (e[l-1] / (g + f_sign(r, g)));
                float s = 1.0f, c = 1.0f;
                p = 0.0f;
                for (int i = m_; i <= l-1; ++i) {
                    float f = s*e[i];
                    float b = c*e[i];
                    slartg_(g, f, &c, &s, &r);
                    if (i != m_) e[i-1] = r;
                    g = d[i] - p;
                    r = (d[i+1] - g)*s + (2.0f*c)*b;
                    p = s*r;
                    d[i] = g + p;
                    g = c*r - b;
                    cw[i] = c; sw[i] = s;
                }
                for (int j = m_; j <= l-1; ++j) {
                    float cc = cw[j], ss = sw[j];
                    for (int i = 1; i <= 3; ++i) {
                        float tmp = z[i][j+1];
                        z[i][j+1] = cc*tmp - ss*z[i][j];
                        z[i][j]   = ss*tmp + cc*z[i][j];
                    }
                }
                d[l] = d[l] - p;
                e[l-1] = g;
            }
        }
    }
    for (int ii = 2; ii <= 3; ++ii) {
        int i = ii - 1, k = i;
        float p = d[i];
        for (int j = ii; j <= 3; ++j) if (d[j] < p) { k = j; p = d[j]; }
        if (k != i) {
            d[k] = d[i]; d[i] = p;
            for (int r2 = 1; r2 <= 3; ++r2) {
                float t = z[r2][i]; z[r2][i] = z[r2][k]; z[r2][k] = t;
            }
        }
    }
    nv[0] = z[1][1]; nv[1] = z[2][1]; nv[2] = z[3][1];
}

// Covariance of the sorted 10-neighborhood (same op order as rounds 2-18).
__device__ void cov_compute(const float4* __restrict__ cl,
                            const unsigned long long keys[KNN], float c[6])
{
#pragma clang fp contract(off)
    float px[KNN], py[KNN], pz[KNN];
    float sx = 0.f, sy = 0.f, sz = 0.f;
    #pragma unroll
    for (int s = 0; s < KNN; ++s) {
        int ni = (int)(unsigned)(keys[s] & 0xFFFFFFFFull);
        float4 np = cl[ni];
        px[s] = np.x; py[s] = np.y; pz[s] = np.z;
        sx = sx + px[s]; sy = sy + py[s]; sz = sz + pz[s];
    }
    float mx = sx / 10.0f, my = sy / 10.0f, mz = sz / 10.0f;
    float c00=0.f,c01=0.f,c02=0.f,c11=0.f,c12=0.f,c22=0.f;
    #pragma unroll
    for (int s = 0; s < KNN; ++s) {
        float dx = px[s]-mx, dy = py[s]-my, dz = pz[s]-mz;
        c00 = c00 + dx*dx; c01 = c01 + dx*dy; c02 = c02 + dx*dz;
        c11 = c11 + dy*dy; c12 = c12 + dy*dz; c22 = c22 + dz*dz;
    }
    c[0] = c00/10.0f; c[1] = c01/10.0f; c[2] = c02/10.0f;
    c[3] = c11/10.0f; c[4] = c12/10.0f; c[5] = c22/10.0f;
}

// ---------------------------------------------------------------------------
// R20 phase-1 insert: gate = min(own 10th, quad bound). Dropping candidates
// >= the quad bound is exact: some lane already holds 10 strictly-better keys.
// ---------------------------------------------------------------------------
#define PROC(p) do { \
    float ddx = qx - (p).x, ddy = qy - (p).y, ddz = qz - (p).z; \
    float dd = fmaf(ddz, ddz, fmaf(ddy, ddy, ddx*ddx)); \
    unsigned long long key = \
        ((unsigned long long)__float_as_uint(dd) << 32) | \
        (unsigned)__float_as_int((p).w); \
    if (key < kgate) { \
        unsigned long long ck = key; \
        _Pragma("unroll") \
        for (int s = 0; s < KNN; ++s) { \
            unsigned long long ok2 = keys[s]; \
            bool sw = ok2 > ck; \
            keys[s] = sw ? ck : ok2; \
            ck      = sw ? ok2 : ck; \
        } \
        k9 = keys[KNN-1]; \
        kgate = (k9 < qbK) ? k9 : qbK; \
    } \
} while (0)

// R20 phase-2 insert into the SECOND list, gated by min(exact cube 10th, own
// 10th). Candidates >= k9M can never enter the final top-10 (10 better exist).
#define PROC2(p) do { \
    float ddx = qx - (p).x, ddy = qy - (p).y, ddz = qz - (p).z; \
    float dd = fmaf(ddz, ddz, fmaf(ddy, ddy, ddx*ddx)); \
    unsigned long long key = \
        ((unsigned long long)__float_as_uint(dd) << 32) | \
        (unsigned)__float_as_int((p).w); \
    if (key < kgate2) { \
        unsigned long long ck = key; \
        _Pragma("unroll") \
        for (int s = 0; s < KNN; ++s) { \
            unsigned long long ok2 = keys2[s]; \
            bool sw = ok2 > ck; \
            keys2[s] = sw ? ck : ok2; \
            ck      = sw ? ok2 : ck; \
        } \
        k92 = keys2[KNN-1]; \
        kgate2 = (k92 < k9M) ? k92 : k9M; \
    } \
} while (0)

// stream a contiguous candidate segment [b, b+n) of S — 2 loads in flight
#define SEGPROC(b, n) do { \
    int _j = (b), _je = (b) + (n); \
    for (; _j + 2 <= _je; _j += 2) { \
        float4 _p0 = cs[_j]; float4 _p1 = cs[_j+1]; \
        PROC(_p0); PROC(_p1); \
    } \
    if (_j < _je) { float4 _p0 = cs[_j]; PROC(_p0); } \
} while (0)

#define SEGPROC2(b, n) do { \
    int _j = (b), _je = (b) + (n); \
    for (; _j + 2 <= _je; _j += 2) { \
        float4 _p0 = cs[_j]; float4 _p1 = cs[_j+1]; \
        PROC2(_p0); PROC2(_p1); \
    } \
    if (_j < _je) { float4 _p0 = cs[_j]; PROC2(_p0); } \
} while (0)

// quad-min of the four lanes' current 10th keys; low word forced to all-ones
// so ties on the distance bits still pass the gate (tie-exact).
#define QEXCH() do { \
    unsigned long long _o1 = __shfl_xor(k9, 1, 4); \
    unsigned long long _m1 = (_o1 < k9) ? _o1 : k9; \
    unsigned long long _o2 = __shfl_xor(_m1, 2, 4); \
    unsigned long long _qm = (_o2 < _m1) ? _o2 : _m1; \
    qbK = _qm | 0xFFFFFFFFull; \
    kgate = (k9 < qbK) ? k9 : qbK; \
} while (0)

// 4-way compile-time coordinate select (3 cndmasks, once per slot)
#define SEL4(A,B,C,D) (sub == 0 ? (A) : (sub == 1 ? (B) : (sub == 2 ? (C) : (D))))

// ---------------------------------------------------------------------------
// Kernel D (R20 structure): grid 10-NN, FOUR lanes per query.
// R20: merge the 4 phase-1 lists IMMEDIATELY after the rho<=1 cube walk.
// All lanes then hold the EXACT cube top-10 -> (a) exact phase-2 skip test
// (H^2 > worstM: any exterior point is >= H away), (b) tight row/cell pruning
// with pw = worstM, (c) phase-2 inserts go to a separate empty list keys2
// gated by min(k9M, k92) so the 75-instr chain almost never fires.
// Phase-1/phase-2 cells and lane partitions are disjoint -> final combine
// (merge keys2 across lanes, fold into merged cube list) is the exact top-10
// of everything examined => bit-identical output to R18/R19.
// ---------------------------------------------------------------------------
__global__ __launch_bounds__(256) void knn_main_kernel(
    const float4* __restrict__ P4, const float4* __restrict__ S,
    const int2* __restrict__ combo, float4* __restrict__ Cov,
    int* __restrict__ ovf, unsigned long long* __restrict__ ovf_key,
    int* __restrict__ ovf_count)
{
    int tidg = blockIdx.x * 256 + threadIdx.x;  // 0..262143
    int qid  = tidg >> 2;                       // 0..65535
    int sub  = tidg & 3;
    int pair = qid >> 13;                       // 8 clouds
    int spos = qid & (NN - 1);                  // sorted position
    const float4* __restrict__ cl = P4 + (size_t)pair * NN;
    const float4* __restrict__ cs = S  + (size_t)pair * NN;
    const int2*   __restrict__ cb = combo + (size_t)pair * NCELLS;

    float4 q = cs[spos];
    float qx = q.x, qy = q.y, qz = q.z;
    int qi = __float_as_int(q.w);               // original index in cloud
    int qcx = cellc(qx), qcy = cellc(qy), qcz = cellc(qz);

    unsigned long long keys[KNN];
    #pragma unroll
    for (int s = 0; s < KNN; ++s) keys[s] = 0xFFFFFFFFFFFFFFFFull;
    unsigned long long k9    = 0xFFFFFFFFFFFFFFFFull;
    unsigned long long qbK   = 0xFFFFFFFFFFFFFFFFull;
    unsigned long long kgate = 0xFFFFFFFFFFFFFFFFull;

    // ---- phase 1: rho<=1 cube, 9 rows checkerboarded 3/2/2/2.
    // R20: each lane's CENTRAL row first, so lists fill with near candidates
    // and the inter-slot quad bound (QEXCH) tightens early.
    int x0 = max(qcx - 1, 0), x1 = min(qcx + 1, G - 1);
#define P1SLOT(i, ZA,YA, ZB,YB, ZC,YC, ZD,YD) \
    int rb##i = 0, re##i = 0; \
    { int zz = qcz + SEL4(ZA,ZB,ZC,ZD); \
      int yy = qcy + SEL4(YA,YB,YC,YD); \
      if ((unsigned)zz < G && (unsigned)yy < G) { \
          int cbase = (zz*G + yy)*G; \
          int2 a = cb[cbase + x0]; \
          int2 b = cb[cbase + x1]; \
          rb##i = a.x; re##i = b.x + b.y; } }
    P1SLOT(0,  0, 0,  0,1, -1,1, 0,-1)
    P1SLOT(1, -1,-1, -1,0,  1,-1, 1, 0)
    P1SLOT(2,  1, 1, 99,99, 99,99, 99,99)   // lanes 1-3 invalid -> bounds fail
#undef P1SLOT
    SEGPROC(rb0, re0 - rb0);
    QEXCH();
    SEGPROC(rb1, re1 - rb1);
    QEXCH();
    SEGPROC(rb2, re2 - rb2);

    // ---- R20: merge the 4 phase-1 lists NOW -> exact top-10 over the cube,
    // identical in all 4 lanes (symmetric butterfly).
    #pragma unroll
    for (int m = 1; m < 4; m <<= 1) {
        unsigned long long other[KNN];
        #pragma unroll
        for (int s = 0; s < KNN; ++s)
            other[s] = __shfl_xor(keys[s], m, 4);   // snapshot before inserts
        #pragma unroll
        for (int s = 0; s < KNN; ++s) {
            unsigned long long key = other[s];
            if (key < k9) {
                unsigned long long ck = key;
                #pragma unroll
                for (int t = 0; t < KNN; ++t) {
                    unsigned long long ok2 = keys[t];
                    bool sw = ok2 > ck;
                    keys[t] = sw ? ck : ok2;
                    ck      = sw ? ok2 : ck;
                }
                k9 = keys[KNN-1];
            }
        }
    }
    const unsigned long long k9M = k9;          // exact cube 10th (u64 key)
    float worstM = __uint_as_float((unsigned)(k9M >> 32)); // NaN if <10 found

    // ---- phase 2: rho=2 shell. Exterior of the cube is >= H from q, so
    // skip iff H^2 > worstM is EXACT (NaN-safe: NaN -> walk shell).
    bool skip = (H*H > worstM);

    unsigned long long keys2[KNN];
    #pragma unroll
    for (int s = 0; s < KNN; ++s) keys2[s] = 0xFFFFFFFFFFFFFFFFull;
    unsigned long long k92    = 0xFFFFFFFFFFFFFFFFull;
    unsigned long long kgate2 = k9M;            // min(k9M, k92) = k9M initially
    {
        int xs0 = max(qcx - 2, 0), xs1 = min(qcx + 2, G - 1);
        // 16 outer rows, checkerboarded 4/4/4/4; prune with exact bound worstM
#define S2SLOT(i, ZA,YA, ZB,YB, ZC,YC, ZD,YD) \
        int sb##i = 0, sn##i = 0; \
        if (!skip) { \
          int zz = qcz + SEL4(ZA,ZB,ZC,ZD); \
          int yy = qcy + SEL4(YA,YB,YC,YD); \
          if ((unsigned)zz < G && (unsigned)yy < G) { \
              float loy = fmaf((float)yy, H, GRID_LO); \
              float loz = fmaf((float)zz, H, GRID_LO); \
              float py = fmaxf(0.0f, fmaxf(loy - qy, qy - (loy + H))); \
              float pz = fmaxf(0.0f, fmaxf(loz - qz, qz - (loz + H))); \
              float pyz = fmaf(pz, pz, py*py); \
              if (!(pyz > worstM)) { \
                  int cbase = (zz*G + yy)*G; \
                  int2 a = cb[cbase + xs0]; \
                  int2 b = cb[cbase + xs1]; \
                  sb##i = a.x; sn##i = (b.x + b.y) - a.x; } } }
        S2SLOT(0, -2,-2, -2,-1, -2,0, -2,1)
        S2SLOT(1, -2, 2,  2,-2,  2,-1, 2,0)
        S2SLOT(2,  2, 1,  2, 2, -1,-2, -1,2)
        S2SLOT(3,  0,-2,  0, 2,  1,-2,  1,2)
#undef S2SLOT
        // 18 isolated cells (|dz|<=1,|dy|<=1, dx=+/-2), 5 slots x 4 lanes
#define CSLOT(i, ZA,YA,XA, ZB,YB,XB, ZC,YC,XC, ZD,YD,XD) \
        int tb##i = 0, tn##i = 0; \
        if (!skip) { \
          int zz = qcz + SEL4(ZA,ZB,ZC,ZD); \
          int yy = qcy + SEL4(YA,YB,YC,YD); \
          int xx = qcx + SEL4(XA,XB,XC,XD); \
          if ((unsigned)zz < G && (unsigned)yy < G && (unsigned)xx < G) { \
              float lox = fmaf((float)xx, H, GRID_LO); \
              float loy = fmaf((float)yy, H, GRID_LO); \
              float loz = fmaf((float)zz, H, GRID_LO); \
              float px = fmaxf(0.0f, fmaxf(lox - qx, qx - (lox + H))); \
              float py = fmaxf(0.0f, fmaxf(loy - qy, qy - (loy + H))); \
              float pz = fmaxf(0.0f, fmaxf(loz - qz, qz - (loz + H))); \
              float m2 = fmaf(pz, pz, fmaf(py, py, px*px)); \
              if (!(m2 > worstM)) { \
                  int2 a = cb[(zz*G + yy)*G + xx]; \
                  tb##i = a.x; tn##i = a.y; } } }
        CSLOT(0, -1,-1,-2, -1,-1,2, -1,0,-2, -1,0,2)
        CSLOT(1, -1, 1,-2, -1, 1,2,  0,-1,-2, 0,-1,2)
        CSLOT(2,  0, 0,-2,  0, 0,2,  0, 1,-2, 0, 1,2)
        CSLOT(3,  1,-1,-2,  1,-1,2,  1, 0,-2, 1, 0,2)
        CSLOT(4,  1, 1,-2,  1, 1,2, 99,99,0, 99,99,0)
#undef CSLOT
#define S2GO(i) SEGPROC2(sb##i, sn##i);
        S2GO(0) S2GO(1) S2GO(2) S2GO(3)
#undef S2GO
#define CGO(i) SEGPROC2(tb##i, tn##i);
        CGO(0) CGO(1) CGO(2) CGO(3) CGO(4)
#undef CGO
    }

    // ---- final: merge the 4 per-lane phase-2 lists, fold into cube list.
    // skip is quad-uniform (worstM shared), so the shfls inside are safe.
    if (!skip) {
        #pragma unroll
        for (int m = 1; m < 4; m <<= 1) {
            unsigned long long other[KNN];
            #pragma unroll
            for (int s = 0; s < KNN; ++s)
                other[s] = __shfl_xor(keys2[s], m, 4);  // snapshot
            #pragma unroll
            for (int s = 0; s < KNN; ++s) {
                unsigned long long key = other[s];
                if (key < kgate2) {
                    unsigned long long ck = key;
                    #pragma unroll
                    for (int t = 0; t < KNN; ++t) {
                        unsigned long long ok2 = keys2[t];
                        bool sw = ok2 > ck;
                        keys2[t] = sw ? ck : ok2;
                        ck      = sw ? ok2 : ck;
                    }
                    k92 = keys2[KNN-1];
                    kgate2 = (k92 < k9M) ? k92 : k9M;
                }
            }
        }
        // fold merged phase-2 list into the cube list (both sorted, disjoint)
        #pragma unroll
        for (int s = 0; s < KNN; ++s) {
            unsigned long long key = keys2[s];
            if (key >= k9) break;               // sorted ascending
            unsigned long long ck = key;
            #pragma unroll
            for (int t = 0; t < KNN; ++t) {
                unsigned long long ok2 = keys[t];
                bool sw = ok2 > ck;
                keys[t] = sw ? ck : ok2;
                ck      = sw ? ok2 : ck;
            }
            k9 = keys[KNN-1];
        }
    }
    float worst_m = __uint_as_float((unsigned)(k9 >> 32));

    // resolved iff cells beyond the rho<=2 region (gap >= 2H) cannot contribute
    float bf = (float)RCAP * H;
    bool resolved = (bf*bf > worst_m);          // strict; NaN (unfilled) -> false
    if (resolved && sub == 0) {
        float c[6];
        cov_compute(cl, keys, c);               // sub==0 only: 1/4 gather loads
        size_t o = ((size_t)pair*NN + qi)*2;
        Cov[o]   = make_float4(c[0], c[1], c[2], c[3]);
        Cov[o+1] = make_float4(c[4], c[5], 0.0f, 0.0f);
    } else if (!resolved && sub == 0) {
        int pos = atomicAdd(ovf_count, 1);
        ovf[pos] = (pair << 13) | qi;
        ovf_key[pos] = k9;      // merged 10th-best: valid upper bound on true
    }                           // 10th key (subset 10th >= full-set 10th)
}

// ---------------------------------------------------------------------------
// Kernel D2: brute-force overflow (R14 config), one query per block. Bound
// gate skips the insert chain for provably-excluded candidates. Writes
// covariance (eigh relocated to eigh_loss).
// ---------------------------------------------------------------------------
#define BRUTE_BLOCKS 4096
__global__ __launch_bounds__(256) void brute_kernel(
    const float4* __restrict__ P4, const int* __restrict__ ovf,
    const unsigned long long* __restrict__ ovf_key,
    const int* __restrict__ ovf_count, float4* __restrict__ Cov)
{
    __shared__ unsigned long long wl[4][KNN];
    int tid = threadIdx.x;
    int lane = tid & 63;
    int wid = tid >> 6;
    int count = *ovf_count;

    for (int oi = blockIdx.x; oi < count; oi += BRUTE_BLOCKS) {
        int rec = ovf[oi];
        unsigned long long bound = ovf_key[oi];
        float bound_d = __uint_as_float((unsigned)(bound >> 32)); // NaN if unfilled
        int pair = rec >> 13;
        int qi = rec & (NN - 1);
        const float4* __restrict__ cl = P4 + (size_t)pair * NN;
        float4 q = cl[qi];
        float qx = q.x, qy = q.y, qz = q.z;

        unsigned long long keys[KNN];
        #pragma unroll
        for (int s = 0; s < KNN; ++s) keys[s] = 0xFFFFFFFFFFFFFFFFull;
        unsigned long long k9 = keys[KNN-1];

        // per-lane scan with bound gate; ties at dd==bound_d pass (exact)
#define BPROC(p, jj) do { \
        float ddx = qx - (p).x, ddy = qy - (p).y, ddz = qz - (p).z; \
        float dd = fmaf(ddz, ddz, fmaf(ddy, ddy, ddx*ddx)); \
        if (!(dd > bound_d)) { \
            unsigned long long key = \
                ((unsigned long long)__float_as_uint(dd) << 32) | (unsigned)(jj); \
            if (key < k9) { \
                unsigned long long ck = key; \
                _Pragma("unroll") \
                for (int s = 0; s < KNN; ++s) { \
                    unsigned long long ok2 = keys[s]; \
                    bool sw = ok2 > ck; \
                    keys[s] = sw ? ck : ok2; \
                    ck      = sw ? ok2 : ck; \
                } \
                k9 = keys[KNN-1]; \
            } \
        } \
    } while (0)
        #pragma unroll 1
        for (int j = tid; j < NN; j += 1024) {  // 8 iterations, 4 loads each
            float4 p0 = cl[j];
            float4 p1 = cl[j + 256];
            float4 p2 = cl[j + 512];
            float4 p3 = cl[j + 768];
            BPROC(p0, j);
            BPROC(p1, j + 256);
            BPROC(p2, j + 512);
            BPROC(p3, j + 768);
        }
#undef BPROC

        // in-wave tree merge -> every lane holds its wave's top-10
        #pragma unroll
        for (int m = 1; m < 64; m <<= 1) {
            unsigned long long other[KNN];
            #pragma unroll
            for (int s = 0; s < KNN; ++s)
                other[s] = __shfl_xor(keys[s], m);  // snapshot before inserts
            #pragma unroll
            for (int s = 0; s < KNN; ++s) {
                unsigned long long key = other[s];
                if (key < k9) {
                    unsigned long long ck = key;
                    #pragma unroll
                    for (int t = 0; t < KNN; ++t) {
                        unsigned long long ok2 = keys[t];
                        bool sw = ok2 > ck;
                        keys[t] = sw ? ck : ok2;
                        ck      = sw ? ok2 : ck;
                    }
                    k9 = keys[KNN-1];
                }
            }
        }

        // cross-wave merge via LDS (4 sorted lists)
        if (lane == 0) {
            #pragma unroll
            for (int s = 0; s < KNN; ++s) wl[wid][s] = keys[s];
        }
        __syncthreads();
        if (wid == 0) {
            for (int w2 = 1; w2 < 4; ++w2) {
                #pragma unroll
                for (int s = 0; s < KNN; ++s) {
                    unsigned long long key = wl[w2][s];
                    if (key >= k9) break;       // lists sorted ascending
                    unsigned long long ck = key;
                    #pragma unroll
                    for (int t = 0; t < KNN; ++t) {
                        unsigned long long ok2 = keys[t];
                        bool sw = ok2 > ck;
                        keys[t] = sw ? ck : ok2;
                        ck      = sw ? ok2 : ck;
                    }
                    k9 = keys[KNN-1];
                }
            }
            if (lane == 0) {
                float c[6];
                cov_compute(cl, keys, c);
                size_t o = ((size_t)pair*NN + qi)*2;
                Cov[o]   = make_float4(c[0], c[1], c[2], c[3]);
                Cov[o+1] = make_float4(c[4], c[5], 0.0f, 0.0f);
            }
        }
        __syncthreads();                        // protect wl for next query
    }
}

// ---------------------------------------------------------------------------
// Kernel E (R19): fused eigh + loss, ONE eigh per thread over 2*BN threads.
// Thread 2k handles gt[k], thread 2k+1 handles pred[k]; normals exchanged
// in-wave via shfl_xor(1); even lanes compute 1-cos; block reduce; atomic.
// Identical eigh inputs -> bit-identical normals (summation grouping only).
// ---------------------------------------------------------------------------
__global__ __launch_bounds__(256) void eigh_loss_kernel(
    const float4* __restrict__ Cov, float* __restrict__ accum,
    unsigned* __restrict__ counter, float* __restrict__ out)
{
    int tid = threadIdx.x;
    int t = blockIdx.x * 256 + tid;            // 0..2*BN-1
    int k = t >> 1;                            // pair index 0..BN-1
    int cld = t & 1;                           // 0 = gt, 1 = pred
    size_t ci = ((size_t)(cld ? BN + k : k)) * 2;
    float4 a0 = Cov[ci], a1 = Cov[ci + 1];
    float n[3];
    eigh3_smallest(a0.x, a0.y, a0.z, a0.w, a1.x, a1.y, n);

    // exchange with partner lane (2k <-> 2k+1 always share a wave)
    float ox = __shfl_xor(n[0], 1);
    float oy = __shfl_xor(n[1], 1);
    float oz = __shfl_xor(n[2], 1);

    float v = 0.0f;
    if (cld == 0) {
        float gx=n[0], gy=n[1], gz=n[2];
        float hx=ox,  hy=oy,  hz=oz;
        float dot = fmaf(gx,hx,fmaf(gy,hy,gz*hz));
        float ng  = sqrtf(fmaf(gx,gx,fmaf(gy,gy,gz*gz)));
        float nh  = sqrtf(fmaf(hx,hx,fmaf(hy,hy,hz*hz)));
        float den = fmaxf(ng*nh, 1e-8f);
        v = 1.0f - dot/den;
    }

    __shared__ float red[256];
    red[tid] = v;                              // odd lanes contribute 0
    __syncthreads();
    for (int s = 128; s > 0; s >>= 1) {
        if (tid < s) red[tid] += red[tid+s];
        __syncthreads();
    }
    if (tid == 0) {
        atomicAdd(accum, red[0]);
        __threadfence();
        unsigned old = atomicAdd(counter, 1u);
        if (old == (unsigned)(2*BN/256 - 1)) {
            float tot = atomicAdd(accum, 0.0f);
            out[0] = tot * (1.0f/(float)BN);
        }
    }
}

// ---------------------------------------------------------------------------
extern "C" void kernel_launch(void* const* d_in, const int* in_sizes, int n_in,
                              void* d_out, int out_size, void* d_ws, size_t ws_size,
                              hipStream_t stream)
{
    (void)in_sizes; (void)n_in; (void)out_size; (void)ws_size;
    const float*    gt   = (const float*)d_in[0];
    const float*    pred = (const float*)d_in[1];
    const unsigned* idxw = (const unsigned*)d_in[2];
    float* out = (float*)d_out;

    char* w = (char*)d_ws;
    float4* P4   = (float4*)w;                         w += (size_t)2*BN*16;   // 1 MB
    float4* S    = (float4*)w;                         w += (size_t)2*BN*16;   // 1 MB
    int*    hist = (int*)w;                            w += (size_t)8*NCELLS*4;   // 1 MB
    int2*   combo = (int2*)w;                          w += (size_t)8*NCELLS*8;   // 2 MB
    float4* Cov  = (float4*)w;                         w += (size_t)2*BN*32;   // 2 MB
    float*  accum = (float*)w;                         w += 16;
    unsigned* counter = (unsigned*)(accum + 1);
    int*    ovf_count = (int*)(accum + 2);
    int*    ovf  = (int*)w;                            w += (size_t)2*BN*4;    // 0.25 MB
    unsigned long long* ovf_key = (unsigned long long*)w;  w += (size_t)2*BN*8; // 0.5 MB

    hipMemsetAsync(hist, 0, (size_t)8*NCELLS*4, stream);
    hipLaunchKernelGGL(prep_kernel,    dim3(2*BN/256), dim3(256),  0, stream,
                       gt, pred, idxw, P4, hist, accum, counter, ovf_count);
    hipLaunchKernelGGL(scan_kernel,    dim3(8),        dim3(1024), 0, stream,
                       hist, combo);
    hipLaunchKernelGGL(scatter_kernel, dim3(2*BN/256), dim3(256),  0, stream,
                       P4, hist, combo, S);
    hipLaunchKernelGGL(knn_main_kernel, dim3(2*BN*4/256), dim3(256), 0, stream,
                       P4, S, combo, Cov, ovf, ovf_key, ovf_count);
    hipLaunchKernelGGL(brute_kernel,   dim3(BRUTE_BLOCKS), dim3(256), 0, stream,
                       P4, ovf, ovf_key, ovf_count, Cov);
    hipLaunchKernelGGL(eigh_loss_kernel, dim3(2*BN/256), dim3(256), 0, stream,
                       Cov, accum, counter, out);
}

// Round 2
// 311.052 us; speedup vs baseline: 1.0382x; 1.0382x over previous
//
#include <hip/hip_runtime.h>
#include <math.h>

#define BB   4
#define NN   8192
#define BN   (BB*NN)       // 32768 points per cloud-set; 8 clouds of 8192 total
#define KNN  10
#define G    32            // grid cells per dim
#define NCELLS (G*G*G)     // 32768 cells per cloud
#define GRID_LO (-5.0f)
#define H    0.3125f       // 10/32
#define INV_H 3.2f
#define RCAP 2             // rho<=2 region; beyond -> brute overflow

#define SEPS    5.9604645e-8f        // slamch('E') = 2^-24
#define SEPS2   (SEPS*SEPS)
#define SSAFMIN 1.1754944e-38f

__device__ __forceinline__ int cellc(float v) {
    int c = (int)floorf((v - GRID_LO) * INV_H);
    return min(G - 1, max(0, c));
}

// ---------------------------------------------------------------------------
// Kernel A: build P4[8][8192] = (x,y,z, bitcast orig-idx); clouds 0-3 = gt
// batches, 4-7 = pred[idx12] batches. Histogram cells + zero accumulators.
// ---------------------------------------------------------------------------
__global__ __launch_bounds__(256) void prep_kernel(
    const float* __restrict__ gt, const float* __restrict__ pred,
    const unsigned* __restrict__ idxw, float4* __restrict__ P4,
    int* __restrict__ hist, float* __restrict__ accum,
    unsigned* __restrict__ counter, int* __restrict__ ovf_count)
{
    __shared__ int s_is32;
    int tid = threadIdx.x;
    if (tid == 0) s_is32 = 0;
    __syncthreads();
    if (idxw[2*tid + 1] != 0u) s_is32 = 1;   // int64 => all high words 0
    __syncthreads();
    bool is64 = (s_is32 == 0);

    if (blockIdx.x == 0 && tid == 0) {
        *accum = 0.0f; *counter = 0u; *ovf_count = 0;
    }

    int point = blockIdx.x * 256 + tid;        // 0 .. 2*BN-1
    int pair = point >> 13;                    // 0..7
    int r    = point & (NN - 1);               // idx within cloud
    float x, y, z;
    if (point < BN) {
        const float* s = gt + (size_t)point*3;
        x = s[0]; y = s[1]; z = s[2];
    } else {
        int rr = point - BN;
        int b = rr >> 13;
        unsigned idx = is64 ? idxw[2*(size_t)rr] : idxw[rr];
        const float* s = pred + ((size_t)b*NN + idx)*3;
        x = s[0]; y = s[1]; z = s[2];
    }
    P4[point] = make_float4(x, y, z, __int_as_float(r));
    int cell = (cellc(z)*G + cellc(y))*G + cellc(x);
    atomicAdd(&hist[(size_t)pair*NCELLS + cell], 1);
}

// ---------------------------------------------------------------------------
// Kernel B: per-cloud exclusive scan -> combo[c] = int2(start, count).
// ---------------------------------------------------------------------------
__global__ __launch_bounds__(1024) void scan_kernel(
    const int* __restrict__ hist, int2* __restrict__ combo)
{
    int cloud = blockIdx.x;
    int tid = threadIdx.x;
    int lane = tid & 63, wid = tid >> 6;
    const int* h = hist + (size_t)cloud * NCELLS;
    int2* cb = combo + (size_t)cloud * NCELLS;

    int loc[32];
    int base = tid * 32;
    const int4* h4 = (const int4*)(h + base);
    int sum = 0;
    #pragma unroll
    for (int i = 0; i < 8; ++i) {
        int4 a = h4[i];
        loc[4*i+0] = a.x; loc[4*i+1] = a.y; loc[4*i+2] = a.z; loc[4*i+3] = a.w;
        sum += a.x + a.y + a.z + a.w;
    }
    // inclusive wave scan of sums
    int v = sum;
    #pragma unroll
    for (int off = 1; off < 64; off <<= 1) {
        int o = __shfl_up(v, off, 64);
        if (lane >= off) v += o;
    }
    __shared__ int ws[16], wsx[16];
    if (lane == 63) ws[wid] = v;
    __syncthreads();
    if (tid < 16) {
        int acc = 0;
        for (int i = 0; i < tid; ++i) acc += ws[i];
        wsx[tid] = acc;
    }
    __syncthreads();
    int run = (v - sum) + wsx[wid];            // exclusive prefix for this thread

    int4* cb4 = (int4*)(cb + base);            // 2 cells per int4 store
    #pragma unroll
    for (int i = 0; i < 16; ++i) {
        int4 o;
        o.x = run; o.y = loc[2*i];     run += loc[2*i];
        o.z = run; o.w = loc[2*i+1];   run += loc[2*i+1];
        cb4[i] = o;
    }
}

// ---------------------------------------------------------------------------
// Kernel C: scatter points into cell-sorted S.
// ---------------------------------------------------------------------------
__global__ __launch_bounds__(256) void scatter_kernel(
    const float4* __restrict__ P4, int* __restrict__ hist,
    const int2* __restrict__ combo, float4* __restrict__ S)
{
    int point = blockIdx.x * 256 + threadIdx.x;
    float4 p = P4[point];
    int pair = point >> 13;
    int cell = (cellc(p.z)*G + cellc(p.y))*G + cellc(p.x);
    int old = atomicSub(&hist[(size_t)pair*NCELLS + cell], 1);
    int pos = combo[(size_t)pair*NCELLS + cell].x + old - 1;
    S[(size_t)pair*NN + pos] = p;
}

// ---------------------------------------------------------------------------
// LAPACK ssyevd 3x3 path: ssytrd('L') + sorgtr + ssteqr('V'). Sign-faithful.
// (verified absmax 0.0 in rounds 2-18 — do not touch)
// ---------------------------------------------------------------------------
__device__ __forceinline__ float f_sign(float a, float b) {
    return copysignf(a, b);
}
__device__ __forceinline__ float slapy2(float x, float y) {
#pragma clang fp contract(off)
    float xa = fabsf(x), ya = fabsf(y);
    float w = fmaxf(xa, ya), z = fminf(xa, ya);
    if (z == 0.0f) return w;
    float t = z / w;
    return w * __fsqrt_rn(1.0f + t*t);
}
__device__ __forceinline__ void slartg_(float f, float g, float* cs, float* sn, float* r) {
#pragma clang fp contract(off)
    if (g == 0.0f)      { *cs = 1.0f; *sn = 0.0f; *r = f; }
    else if (f == 0.0f) { *cs = 0.0f; *sn = f_sign(1.0f, g); *r = fabsf(g); }
    else {
        float f1 = fabsf(f);
        float d = __fsqrt_rn(f*f + g*g);
        float p = 1.0f / d;
        *cs = f1 * p;
        *sn = g * f_sign(p, f);
        *r  = f_sign(d, f);
    }
}
__device__ void slaev2_(float a, float b, float c,
                        float* rt1, float* rt2, float* cs1, float* sn1) {
#pragma clang fp contract(off)
    float sm = a + c, df = a - c;
    float adf = fabsf(df);
    float tb = b + b;
    float ab = fabsf(tb);
    float acmx, acmn;
    if (fabsf(a) > fabsf(c)) { acmx = a; acmn = c; } else { acmx = c; acmn = a; }
    float rt;
    if (adf > ab)      { float t = ab/adf; rt = adf*__fsqrt_rn(1.0f + t*t); }
    else if (adf < ab) { float t = adf/ab; rt = ab*__fsqrt_rn(1.0f + t*t); }
    else               { rt = ab*__fsqrt_rn(2.0f); }
    int sgn1;
    if (sm < 0.0f)      { *rt1 = 0.5f*(sm - rt); sgn1 = -1;
                          *rt2 = (acmx / *rt1)*acmn - (b / *rt1)*b; }
    else if (sm > 0.0f) { *rt1 = 0.5f*(sm + rt); sgn1 = 1;
                          *rt2 = (acmx / *rt1)*acmn - (b / *rt1)*b; }
    else                { *rt1 = 0.5f*rt; *rt2 = -0.5f*rt; sgn1 = 1; }
    float cs; int sgn2;
    if (df >= 0.0f) { cs = df + rt; sgn2 = 1; } else { cs = df - rt; sgn2 = -1; }
    float acs = fabsf(cs);
    float c1, s1;
    if (acs > ab) { float ct = -tb/cs; s1 = 1.0f/__fsqrt_rn(1.0f + ct*ct); c1 = ct*s1; }
    else {
        if (ab == 0.0f) { c1 = 1.0f; s1 = 0.0f; }
        else { float tn = -cs/tb; c1 = 1.0f/__fsqrt_rn(1.0f + tn*tn); s1 = tn*c1; }
    }
    if (sgn1 == sgn2) { float tn = c1; c1 = -s1; s1 = tn; }
    *cs1 = c1; *sn1 = s1;
}

__device__ void eigh3_smallest(float c00, float c01, float c02,
                               float c11, float c12, float c22, float nv[3])
{
#pragma clang fp contract(off)
    // ---- ssytrd('L') ----
    float d[4], e[3], z[4][4];
    float tau1, v2 = 0.0f;
    float e1, d2, d3, e2;
    float alpha = c01, x = c02;
    if (x == 0.0f) {
        tau1 = 0.0f; e1 = alpha;
        d2 = c11; d3 = c22; e2 = c12;
    } else {
        float beta = -f_sign(slapy2(alpha, fabsf(x)), alpha);
        tau1 = (beta - alpha) / beta;
        v2 = x / (alpha - beta);
        e1 = beta;
        float w1 = tau1*(c11 + c12*v2);
        float w2 = tau1*(c12 + c22*v2);
        float al = -0.5f*tau1*(w1 + w2*v2);
        w1 = w1 + al;
        w2 = w2 + al*v2;
        d2 = (c11 - w1) - w1;
        e2 = (c12 - v2*w1) - w2;
        d3 = (c22 - v2*w2) - w2*v2;
    }
    d[1] = c00; d[2] = d2; d[3] = d3;
    e[1] = e1;  e[2] = e2;
    z[1][1] = 1.0f; z[1][2] = 0.0f; z[1][3] = 0.0f;
    z[2][1] = 0.0f; z[3][1] = 0.0f;
    z[2][2] = 1.0f - tau1;
    float mtv = -tau1*v2;
    z[2][3] = mtv; z[3][2] = mtv;
    z[3][3] = 1.0f + mtv*v2;

    // ---- ssteqr('V', 3) ----
    const int n = 3, nm1 = 2;
    int l1 = 1, jtot = 0;
    const int nmaxit = 90;
    float cw[3], sw[3];
    int guard = 0;
    while (guard++ < 64) {
        if (l1 > n) break;
        if (l1 > 1) e[l1-1] = 0.0f;
        int m = n;
        if (l1 <= nm1) {
            for (int mi = l1; mi <= nm1; ++mi) {
                float tst = fabsf(e[mi]);
                if (tst == 0.0f) { m = mi; break; }
                if (tst <= (__fsqrt_rn(fabsf(d[mi]))*__fsqrt_rn(fabsf(d[mi+1])))*SEPS) {
                    e[mi] = 0.0f; m = mi; break;
                }
            }
        }
        int l = l1;
        int lsv = l, lend = m, lendsv = lend;
        l1 = m + 1;
        if (lend == l) continue;
        if (fabsf(d[lend]) < fabsf(d[l])) { lend = lsv; l = lendsv; }

        if (lend > l) {
            // QL
            while (true) {
                int m_ = lend;
                if (l != lend) {
                    for (int mi = l; mi <= lend-1; ++mi) {
                        float em = e[mi];
                        float tst = em*em;
                        if (tst <= (SEPS2*fabsf(d[mi]))*fabsf(d[mi+1]) + SSAFMIN) { m_ = mi; break; }
                    }
                }
                if (m_ < lend) e[m_] = 0.0f;
                float p = d[l];
                if (m_ == l) {
                    d[l] = p; l = l + 1;
                    if (l <= lend) continue; else break;
                }
                if (m_ == l + 1) {
                    float rt1, rt2, cc, ss;
                    slaev2_(d[l], e[l], d[l+1], &rt1, &rt2, &cc, &ss);
                    for (int i = 1; i <= 3; ++i) {
                        float tmp = z[i][l+1];
                        z[i][l+1] = cc*tmp - ss*z[i][l];
                        z[i][l]   = ss*tmp + cc*z[i][l];
                    }
                    d[l] = rt1; d[l+1] = rt2; e[l] = 0.0f;
                    l = l + 2;
                    if (l <= lend) continue; else break;
                }
                if (jtot == nmaxit) break;
                jtot++;
                float g = (d[l+1] - p) / (2.0f*e[l]);
                float r = slapy2(g, 1.0f);
                g = d[m_] - p + (e[l] / (g + f_sign(r, g)));
                float s = 1.0f, c = 1.0f;
                p = 0.0f;
                for (int i = m_-1; i >= l; --i) {
                    float f = s*e[i];
                    float b = c*e[i];
                    slartg_(g, f, &c, &s, &r);
                    if (i != m_-1) e[i+1] = r;
                    g = d[i+1] - p;
                    r = (d[i] - g)*s + (2.0f*c)*b;
                    p = s*r;
                    d[i+1] = g + p;
                    g = c*r - b;
                    cw[i] = c; sw[i] = -s;
                }
                for (int j = m_-1; j >= l; --j) {
                    float cc = cw[j], ss = sw[j];
                    for (int i = 1; i <= 3; ++i) {
                        float tmp = z[i][j+1];
                        z[i][j+1] = cc*tmp - ss*z[i][j];
                        z[i][j]   = ss*tmp + cc*z[i][j];
                    }
                }
                d[l] = d[l] - p;
                e[l] = g;
            }
        } else {
            // QR
            while (true) {
                int m_ = lend;
                if (l != lend) {
                    for (int mi = l; mi >= lend+1; --mi) {
                        float em = e[mi-1];
                        float tst = em*em;
                        if (tst <= (SEPS2*fabsf(d[mi]))*fabsf(d[mi-1]) + SSAFMIN) { m_ = mi; break; }
                    }
                }
                if (m_ > lend) e[m_-1] = 0.0f;
                float p = d[l];
                if (m_ == l) {
                    d[l] = p; l = l - 1;
                    if (l >= lend) continue; else break;
                }
                if (m_ == l - 1) {
                    float rt1, rt2, cc, ss;
                    slaev2_(d[l-1], e[l-1], d[l], &rt1, &rt2, &cc, &ss);
                    for (int i = 1; i <= 3; ++i) {
                        float tmp = z[i][l];
                        z[i][l]   = cc*tmp - ss*z[i][l-1];
                        z[i][l-1] = ss*tmp + cc*z[i][l-1];
                    }
                    d[l-1] = rt1; d[l] = rt2; e[l-1] = 0.0f;
                    l = l - 2;
                    if (l >= lend) continue; else break;
                }
                if (jtot == nmaxit) break;
                jtot++;
                float g = (d[l-1] - p) / (2.0f*e[l-1]);
                float r = slapy2(g, 1.0f);
                g = d[m_] - p + (e[l-1] / (g + f_sign(r, g)));
                float s = 1.0f, c = 1.0f;
                p = 0.0f;
                for (int i = m_; i <= l-1; ++i) {
                    float f = s*e[i];
                    float b = c*e[i];
                    slartg_(g, f, &c, &s, &r);
                    if (i != m_) e[i-1] = r;
                    g = d[i] - p;
                    r = (d[i+1] - g)*s + (2.0f*c)*b;
                    p = s*r;
                    d[i] = g + p;
                    g = c*r - b;
                    cw[i] = c; sw[i] = s;
                }
                for (int j = m_; j <= l-1; ++j) {
                    float cc = cw[j], ss = sw[j];
                    for (int i = 1; i <= 3; ++i) {
                        float tmp = z[i][j+1];
                        z[i][j+1] = cc*tmp - ss*z[i][j];
                        z[i][j]   = ss*tmp + cc*z[i][j];
                    }
                }
                d[l] = d[l] - p;
                e[l-1] = g;
            }
        }
    }
    for (int ii = 2; ii <= 3; ++ii) {
        int i = ii - 1, k = i;
        float p = d[i];
        for (int j = ii; j <= 3; ++j) if (d[j] < p) { k = j; p = d[j]; }
        if (k != i) {
            d[k] = d[i]; d[i] = p;
            for (int r2 = 1; r2 <= 3; ++r2) {
                float t = z[r2][i]; z[r2][i] = z[r2][k]; z[r2][k] = t;
            }
        }
    }
    nv[0] = z[1][1]; nv[1] = z[2][1]; nv[2] = z[3][1];
}

// Covariance of the sorted 10-neighborhood (same op order as rounds 2-18).
__device__ void cov_compute(const float4* __restrict__ cl,
                            const unsigned long long keys[KNN], float c[6])
{
#pragma clang fp contract(off)
    float px[KNN], py[KNN], pz[KNN];
    float sx = 0.f, sy = 0.f, sz = 0.f;
    #pragma unroll
    for (int s = 0; s < KNN; ++s) {
        int ni = (int)(unsigned)(keys[s] & 0xFFFFFFFFull);
        float4 np = cl[ni];
        px[s] = np.x; py[s] = np.y; pz[s] = np.z;
        sx = sx + px[s]; sy = sy + py[s]; sz = sz + pz[s];
    }
    float mx = sx / 10.0f, my = sy / 10.0f, mz = sz / 10.0f;
    float c00=0.f,c01=0.f,c02=0.f,c11=0.f,c12=0.f,c22=0.f;
    #pragma unroll
    for (int s = 0; s < KNN; ++s) {
        float dx = px[s]-mx, dy = py[s]-my, dz = pz[s]-mz;
        c00 = c00 + dx*dx; c01 = c01 + dx*dy; c02 = c02 + dx*dz;
        c11 = c11 + dy*dy; c12 = c12 + dy*dz; c22 = c22 + dz*dz;
    }
    c[0] = c00/10.0f; c[1] = c01/10.0f; c[2] = c02/10.0f;
    c[3] = c11/10.0f; c[4] = c12/10.0f; c[5] = c22/10.0f;
}

// ---------------------------------------------------------------------------
// Insert: gate = min(own 10th, quad bound). Dropping candidates >= the quad
// bound is exact: some lane already holds 10 strictly-better keys. In phase 2
// qbK is set to ~0ull so the gate degenerates to the (exact) own 10th.
// ---------------------------------------------------------------------------
#define PROC(p) do { \
    float ddx = qx - (p).x, ddy = qy - (p).y, ddz = qz - (p).z; \
    float dd = fmaf(ddz, ddz, fmaf(ddy, ddy, ddx*ddx)); \
    unsigned long long key = \
        ((unsigned long long)__float_as_uint(dd) << 32) | \
        (unsigned)__float_as_int((p).w); \
    if (key < kgate) { \
        unsigned long long ck = key; \
        _Pragma("unroll") \
        for (int s = 0; s < KNN; ++s) { \
            unsigned long long ok2 = keys[s]; \
            bool sw = ok2 > ck; \
            keys[s] = sw ? ck : ok2; \
            ck      = sw ? ok2 : ck; \
        } \
        k9 = keys[KNN-1]; \
        kgate = (k9 < qbK) ? k9 : qbK; \
    } \
} while (0)

// stream a contiguous candidate segment [b, b+n) of S — 2 loads in flight
#define SEGPROC(b, n) do { \
    int _j = (b), _je = (b) + (n); \
    for (; _j + 2 <= _je; _j += 2) { \
        float4 _p0 = cs[_j]; float4 _p1 = cs[_j+1]; \
        PROC(_p0); PROC(_p1); \
    } \
    if (_j < _je) { float4 _p0 = cs[_j]; PROC(_p0); } \
} while (0)

// quad-min of the four lanes' current 10th keys; low word forced to all-ones
// so ties on the distance bits still pass the gate (tie-exact).
#define QEXCH() do { \
    unsigned long long _o1 = __shfl_xor(k9, 1, 4); \
    unsigned long long _m1 = (_o1 < k9) ? _o1 : k9; \
    unsigned long long _o2 = __shfl_xor(_m1, 2, 4); \
    unsigned long long _qm = (_o2 < _m1) ? _o2 : _m1; \
    qbK = _qm | 0xFFFFFFFFull; \
    kgate = (k9 < qbK) ? k9 : qbK; \
} while (0)

// 4-way compile-time coordinate select (3 cndmasks, once per slot)
#define SEL4(A,B,C,D) (sub == 0 ? (A) : (sub == 1 ? (B) : (sub == 2 ? (C) : (D))))

// ---------------------------------------------------------------------------
// Kernel D (R21): grid 10-NN, FOUR lanes per query, ONE list per lane.
// After the rho<=1 cube walk the 4 phase-1 lists are merged (butterfly, no
// dups possible: lane cell-subsets disjoint) -> every lane holds the EXACT
// cube top-10. Gives (a) exact phase-2 skip (H^2 > worstM: any exterior
// point is >= H away), (b) tight row/cell pruning with worstM. Phase-2
// candidates insert DIRECTLY into the merged list (gate key < k9 is exact);
// the final cross-lane merge then needs a dedupe test (cube survivors are in
// all 4 lists) and only runs when some lane actually inserted (k9 != k9M;
// every successful insert strictly lowers k9). Union of the 4 lists provably
// contains the true top-10, and dedupe-top10 of the union is exact =>
// bit-identical output to R18/R19/R20. NO second list => VGPR back to ~R19.
// ---------------------------------------------------------------------------
__global__ __launch_bounds__(256) void knn_main_kernel(
    const float4* __restrict__ P4, const float4* __restrict__ S,
    const int2* __restrict__ combo, float4* __restrict__ Cov,
    int* __restrict__ ovf, unsigned long long* __restrict__ ovf_key,
    int* __restrict__ ovf_count)
{
    int tidg = blockIdx.x * 256 + threadIdx.x;  // 0..262143
    int qid  = tidg >> 2;                       // 0..65535
    int sub  = tidg & 3;
    int pair = qid >> 13;                       // 8 clouds
    int spos = qid & (NN - 1);                  // sorted position
    const float4* __restrict__ cl = P4 + (size_t)pair * NN;
    const float4* __restrict__ cs = S  + (size_t)pair * NN;
    const int2*   __restrict__ cb = combo + (size_t)pair * NCELLS;

    float4 q = cs[spos];
    float qx = q.x, qy = q.y, qz = q.z;
    int qi = __float_as_int(q.w);               // original index in cloud
    int qcx = cellc(qx), qcy = cellc(qy), qcz = cellc(qz);

    unsigned long long keys[KNN];
    #pragma unroll
    for (int s = 0; s < KNN; ++s) keys[s] = 0xFFFFFFFFFFFFFFFFull;
    unsigned long long k9    = 0xFFFFFFFFFFFFFFFFull;
    unsigned long long qbK   = 0xFFFFFFFFFFFFFFFFull;
    unsigned long long kgate = 0xFFFFFFFFFFFFFFFFull;

    // ---- phase 1: rho<=1 cube, 9 rows checkerboarded 3/2/2/2.
    // Each lane's CENTRAL row first, so lists fill with near candidates and
    // the inter-slot quad bound (QEXCH) tightens early.
    int x0 = max(qcx - 1, 0), x1 = min(qcx + 1, G - 1);
#define P1SLOT(i, ZA,YA, ZB,YB, ZC,YC, ZD,YD) \
    int rb##i = 0, re##i = 0; \
    { int zz = qcz + SEL4(ZA,ZB,ZC,ZD); \
      int yy = qcy + SEL4(YA,YB,YC,YD); \
      if ((unsigned)zz < G && (unsigned)yy < G) { \
          int cbase = (zz*G + yy)*G; \
          int2 a = cb[cbase + x0]; \
          int2 b = cb[cbase + x1]; \
          rb##i = a.x; re##i = b.x + b.y; } }
    P1SLOT(0,  0, 0,  0,1, -1,1, 0,-1)
    P1SLOT(1, -1,-1, -1,0,  1,-1, 1, 0)
    P1SLOT(2,  1, 1, 99,99, 99,99, 99,99)   // lanes 1-3 invalid -> bounds fail
#undef P1SLOT
    SEGPROC(rb0, re0 - rb0);
    QEXCH();
    SEGPROC(rb1, re1 - rb1);
    QEXCH();
    SEGPROC(rb2, re2 - rb2);

    // ---- merge the 4 phase-1 lists NOW -> exact top-10 over the cube,
    // identical in all 4 lanes (symmetric butterfly; no dups: disjoint cells).
    #pragma unroll
    for (int m = 1; m < 4; m <<= 1) {
        unsigned long long other[KNN];
        #pragma unroll
        for (int s = 0; s < KNN; ++s)
            other[s] = __shfl_xor(keys[s], m, 4);   // snapshot before inserts
        #pragma unroll
        for (int s = 0; s < KNN; ++s) {
            unsigned long long key = other[s];
            if (key < k9) {
                unsigned long long ck = key;
                #pragma unroll
                for (int t = 0; t < KNN; ++t) {
                    unsigned long long ok2 = keys[t];
                    bool sw = ok2 > ck;
                    keys[t] = sw ? ck : ok2;
                    ck      = sw ? ok2 : ck;
                }
                k9 = keys[KNN-1];
            }
        }
    }
    const unsigned long long k9M = k9;          // exact cube 10th (u64 key)
    float worstM = __uint_as_float((unsigned)(k9M >> 32)); // NaN if <10 found

    // ---- phase 2: rho=2 shell. Exterior of the cube is >= H from q, so
    // skip iff H^2 > worstM is EXACT (NaN-safe: NaN -> walk shell).
    bool skip = (H*H > worstM);                 // quad-uniform (worstM shared)

    // phase-2 inserts go directly into the merged list; gate = own 10th only
    qbK   = 0xFFFFFFFFFFFFFFFFull;
    kgate = k9;
    {
        int xs0 = max(qcx - 2, 0), xs1 = min(qcx + 2, G - 1);
        // 16 outer rows, checkerboarded 4/4/4/4; prune with exact bound worstM
#define S2SLOT(i, ZA,YA, ZB,YB, ZC,YC, ZD,YD) \
        int sb##i = 0, sn##i = 0; \
        if (!skip) { \
          int zz = qcz + SEL4(ZA,ZB,ZC,ZD); \
          int yy = qcy + SEL4(YA,YB,YC,YD); \
          if ((unsigned)zz < G && (unsigned)yy < G) { \
              float loy = fmaf((float)yy, H, GRID_LO); \
              float loz = fmaf((float)zz, H, GRID_LO); \
              float py = fmaxf(0.0f, fmaxf(loy - qy, qy - (loy + H))); \
              float pz = fmaxf(0.0f, fmaxf(loz - qz, qz - (loz + H))); \
              float pyz = fmaf(pz, pz, py*py); \
              if (!(pyz > worstM)) { \
                  int cbase = (zz*G + yy)*G; \
                  int2 a = cb[cbase + xs0]; \
                  int2 b = cb[cbase + xs1]; \
                  sb##i = a.x; sn##i = (b.x + b.y) - a.x; } } }
        S2SLOT(0, -2,-2, -2,-1, -2,0, -2,1)
        S2SLOT(1, -2, 2,  2,-2,  2,-1, 2,0)
        S2SLOT(2,  2, 1,  2, 2, -1,-2, -1,2)
        S2SLOT(3,  0,-2,  0, 2,  1,-2,  1,2)
#undef S2SLOT
        // 18 isolated cells (|dz|<=1,|dy|<=1, dx=+/-2), 5 slots x 4 lanes
#define CSLOT(i, ZA,YA,XA, ZB,YB,XB, ZC,YC,XC, ZD,YD,XD) \
        int tb##i = 0, tn##i = 0; \
        if (!skip) { \
          int zz = qcz + SEL4(ZA,ZB,ZC,ZD); \
          int yy = qcy + SEL4(YA,YB,YC,YD); \
          int xx = qcx + SEL4(XA,XB,XC,XD); \
          if ((unsigned)zz < G && (unsigned)yy < G && (unsigned)xx < G) { \
              float lox = fmaf((float)xx, H, GRID_LO); \
              float loy = fmaf((float)yy, H, GRID_LO); \
              float loz = fmaf((float)zz, H, GRID_LO); \
              float px = fmaxf(0.0f, fmaxf(lox - qx, qx - (lox + H))); \
              float py = fmaxf(0.0f, fmaxf(loy - qy, qy - (loy + H))); \
              float pz = fmaxf(0.0f, fmaxf(loz - qz, qz - (loz + H))); \
              float m2 = fmaf(pz, pz, fmaf(py, py, px*px)); \
              if (!(m2 > worstM)) { \
                  int2 a = cb[(zz*G + yy)*G + xx]; \
                  tb##i = a.x; tn##i = a.y; } } }
        CSLOT(0, -1,-1,-2, -1,-1,2, -1,0,-2, -1,0,2)
        CSLOT(1, -1, 1,-2, -1, 1,2,  0,-1,-2, 0,-1,2)
        CSLOT(2,  0, 0,-2,  0, 0,2,  0, 1,-2, 0, 1,2)
        CSLOT(3,  1,-1,-2,  1,-1,2,  1, 0,-2, 1, 0,2)
        CSLOT(4,  1, 1,-2,  1, 1,2, 99,99,0, 99,99,0)
#undef CSLOT
#define S2GO(i) SEGPROC(sb##i, sn##i);
        S2GO(0) S2GO(1) S2GO(2) S2GO(3)
#undef S2GO
#define CGO(i) SEGPROC(tb##i, tn##i);
        CGO(0) CGO(1) CGO(2) CGO(3) CGO(4)
#undef CGO
    }

    // ---- final: dedupe-merge the 4 lists (cube survivors are shared), but
    // only if some lane actually inserted a shell candidate. Every successful
    // insert strictly lowers k9, so "changed" == (k9 != k9M). skip and ch are
    // quad-uniform -> the shfls inside are safe.
    if (!skip) {
        int ch = (k9 != k9M) ? 1 : 0;
        ch |= __shfl_xor(ch, 1, 4);
        ch |= __shfl_xor(ch, 2, 4);
        if (ch) {
            #pragma unroll
            for (int m = 1; m < 4; m <<= 1) {
                unsigned long long other[KNN];
                #pragma unroll
                for (int s = 0; s < KNN; ++s)
                    other[s] = __shfl_xor(keys[s], m, 4);  // snapshot
                #pragma unroll
                for (int s = 0; s < KNN; ++s) {
                    unsigned long long key = other[s];
                    if (key >= k9) break;       // other sorted ascending
                    bool dup = false;
                    #pragma unroll
                    for (int t = 0; t < KNN; ++t) dup = dup || (keys[t] == key);
                    if (!dup) {
                        unsigned long long ck = key;
                        #pragma unroll
                        for (int t = 0; t < KNN; ++t) {
                            unsigned long long ok2 = keys[t];
                            bool sw = ok2 > ck;
                            keys[t] = sw ? ck : ok2;
                            ck      = sw ? ok2 : ck;
                        }
                        k9 = keys[KNN-1];
                    }
                }
            }
        }
    }
    float worst_m = __uint_as_float((unsigned)(k9 >> 32));

    // resolved iff cells beyond the rho<=2 region (gap >= 2H) cannot contribute
    float bf = (float)RCAP * H;
    bool resolved = (bf*bf > worst_m);          // strict; NaN (unfilled) -> false
    if (resolved && sub == 0) {
        float c[6];
        cov_compute(cl, keys, c);               // sub==0 only: 1/4 gather loads
        size_t o = ((size_t)pair*NN + qi)*2;
        Cov[o]   = make_float4(c[0], c[1], c[2], c[3]);
        Cov[o+1] = make_float4(c[4], c[5], 0.0f, 0.0f);
    } else if (!resolved && sub == 0) {
        int pos = atomicAdd(ovf_count, 1);
        ovf[pos] = (pair << 13) | qi;
        ovf_key[pos] = k9;      // merged 10th-best: valid upper bound on true
    }                           // 10th key (subset 10th >= full-set 10th)
}

// ---------------------------------------------------------------------------
// Kernel D2: brute-force overflow (R14 config), one query per block. Bound
// gate skips the insert chain for provably-excluded candidates. Writes
// covariance (eigh relocated to eigh_loss).
// ---------------------------------------------------------------------------
#define BRUTE_BLOCKS 4096
__global__ __launch_bounds__(256) void brute_kernel(
    const float4* __restrict__ P4, const int* __restrict__ ovf,
    const unsigned long long* __restrict__ ovf_key,
    const int* __restrict__ ovf_count, float4* __restrict__ Cov)
{
    __shared__ unsigned long long wl[4][KNN];
    int tid = threadIdx.x;
    int lane = tid & 63;
    int wid = tid >> 6;
    int count = *ovf_count;

    for (int oi = blockIdx.x; oi < count; oi += BRUTE_BLOCKS) {
        int rec = ovf[oi];
        unsigned long long bound = ovf_key[oi];
        float bound_d = __uint_as_float((unsigned)(bound >> 32)); // NaN if unfilled
        int pair = rec >> 13;
        int qi = rec & (NN - 1);
        const float4* __restrict__ cl = P4 + (size_t)pair * NN;
        float4 q = cl[qi];
        float qx = q.x, qy = q.y, qz = q.z;

        unsigned long long keys[KNN];
        #pragma unroll
        for (int s = 0; s < KNN; ++s) keys[s] = 0xFFFFFFFFFFFFFFFFull;
        unsigned long long k9 = keys[KNN-1];

        // per-lane scan with bound gate; ties at dd==bound_d pass (exact)
#define BPROC(p, jj) do { \
        float ddx = qx - (p).x, ddy = qy - (p).y, ddz = qz - (p).z; \
        float dd = fmaf(ddz, ddz, fmaf(ddy, ddy, ddx*ddx)); \
        if (!(dd > bound_d)) { \
            unsigned long long key = \
                ((unsigned long long)__float_as_uint(dd) << 32) | (unsigned)(jj); \
            if (key < k9) { \
                unsigned long long ck = key; \
                _Pragma("unroll") \
                for (int s = 0; s < KNN; ++s) { \
                    unsigned long long ok2 = keys[s]; \
                    bool sw = ok2 > ck; \
                    keys[s] = sw ? ck : ok2; \
                    ck      = sw ? ok2 : ck; \
                } \
                k9 = keys[KNN-1]; \
            } \
        } \
    } while (0)
        #pragma unroll 1
        for (int j = tid; j < NN; j += 1024) {  // 8 iterations, 4 loads each
            float4 p0 = cl[j];
            float4 p1 = cl[j + 256];
            float4 p2 = cl[j + 512];
            float4 p3 = cl[j + 768];
            BPROC(p0, j);
            BPROC(p1, j + 256);
            BPROC(p2, j + 512);
            BPROC(p3, j + 768);
        }
#undef BPROC

        // in-wave tree merge -> every lane holds its wave's top-10
        #pragma unroll
        for (int m = 1; m < 64; m <<= 1) {
            unsigned long long other[KNN];
            #pragma unroll
            for (int s = 0; s < KNN; ++s)
                other[s] = __shfl_xor(keys[s], m);  // snapshot before inserts
            #pragma unroll
            for (int s = 0; s < KNN; ++s) {
                unsigned long long key = other[s];
                if (key < k9) {
                    unsigned long long ck = key;
                    #pragma unroll
                    for (int t = 0; t < KNN; ++t) {
                        unsigned long long ok2 = keys[t];
                        bool sw = ok2 > ck;
                        keys[t] = sw ? ck : ok2;
                        ck      = sw ? ok2 : ck;
                    }
                    k9 = keys[KNN-1];
                }
            }
        }

        // cross-wave merge via LDS (4 sorted lists)
        if (lane == 0) {
            #pragma unroll
            for (int s = 0; s < KNN; ++s) wl[wid][s] = keys[s];
        }
        __syncthreads();
        if (wid == 0) {
            for (int w2 = 1; w2 < 4; ++w2) {
                #pragma unroll
                for (int s = 0; s < KNN; ++s) {
                    unsigned long long key = wl[w2][s];
                    if (key >= k9) break;       // lists sorted ascending
                    unsigned long long ck = key;
                    #pragma unroll
                    for (int t = 0; t < KNN; ++t) {
                        unsigned long long ok2 = keys[t];
                        bool sw = ok2 > ck;
                        keys[t] = sw ? ck : ok2;
                        ck      = sw ? ok2 : ck;
                    }
                    k9 = keys[KNN-1];
                }
            }
            if (lane == 0) {
                float c[6];
                cov_compute(cl, keys, c);
                size_t o = ((size_t)pair*NN + qi)*2;
                Cov[o]   = make_float4(c[0], c[1], c[2], c[3]);
                Cov[o+1] = make_float4(c[4], c[5], 0.0f, 0.0f);
            }
        }
        __syncthreads();                        // protect wl for next query
    }
}

// ---------------------------------------------------------------------------
// Kernel E (R19): fused eigh + loss, ONE eigh per thread over 2*BN threads.
// Thread 2k handles gt[k], thread 2k+1 handles pred[k]; normals exchanged
// in-wave via shfl_xor(1); even lanes compute 1-cos; block reduce; atomic.
// Identical eigh inputs -> bit-identical normals (summation grouping only).
// ---------------------------------------------------------------------------
__global__ __launch_bounds__(256) void eigh_loss_kernel(
    const float4* __restrict__ Cov, float* __restrict__ accum,
    unsigned* __restrict__ counter, float* __restrict__ out)
{
    int tid = threadIdx.x;
    int t = blockIdx.x * 256 + tid;            // 0..2*BN-1
    int k = t >> 1;                            // pair index 0..BN-1
    int cld = t & 1;                           // 0 = gt, 1 = pred
    size_t ci = ((size_t)(cld ? BN + k : k)) * 2;
    float4 a0 = Cov[ci], a1 = Cov[ci + 1];
    float n[3];
    eigh3_smallest(a0.x, a0.y, a0.z, a0.w, a1.x, a1.y, n);

    // exchange with partner lane (2k <-> 2k+1 always share a wave)
    float ox = __shfl_xor(n[0], 1);
    float oy = __shfl_xor(n[1], 1);
    float oz = __shfl_xor(n[2], 1);

    float v = 0.0f;
    if (cld == 0) {
        float gx=n[0], gy=n[1], gz=n[2];
        float hx=ox,  hy=oy,  hz=oz;
        float dot = fmaf(gx,hx,fmaf(gy,hy,gz*hz));
        float ng  = sqrtf(fmaf(gx,gx,fmaf(gy,gy,gz*gz)));
        float nh  = sqrtf(fmaf(hx,hx,fmaf(hy,hy,hz*hz)));
        float den = fmaxf(ng*nh, 1e-8f);
        v = 1.0f - dot/den;
    }

    __shared__ float red[256];
    red[tid] = v;                              // odd lanes contribute 0
    __syncthreads();
    for (int s = 128; s > 0; s >>= 1) {
        if (tid < s) red[tid] += red[tid+s];
        __syncthreads();
    }
    if (tid == 0) {
        atomicAdd(accum, red[0]);
        __threadfence();
        unsigned old = atomicAdd(counter, 1u);
        if (old == (unsigned)(2*BN/256 - 1)) {
            float tot = atomicAdd(accum, 0.0f);
            out[0] = tot * (1.0f/(float)BN);
        }
    }
}

// ---------------------------------------------------------------------------
extern "C" void kernel_launch(void* const* d_in, const int* in_sizes, int n_in,
                              void* d_out, int out_size, void* d_ws, size_t ws_size,
                              hipStream_t stream)
{
    (void)in_sizes; (void)n_in; (void)out_size; (void)ws_size;
    const float*    gt   = (const float*)d_in[0];
    const float*    pred = (const float*)d_in[1];
    const unsigned* idxw = (const unsigned*)d_in[2];
    float* out = (float*)d_out;

    char* w = (char*)d_ws;
    float4* P4   = (float4*)w;                         w += (size_t)2*BN*16;   // 1 MB
    float4* S    = (float4*)w;                         w += (size_t)2*BN*16;   // 1 MB
    int*    hist = (int*)w;                            w += (size_t)8*NCELLS*4;   // 1 MB
    int2*   combo = (int2*)w;                          w += (size_t)8*NCELLS*8;   // 2 MB
    float4* Cov  = (float4*)w;                         w += (size_t)2*BN*32;   // 2 MB
    float*  accum = (float*)w;                         w += 16;
    unsigned* counter = (unsigned*)(accum + 1);
    int*    ovf_count = (int*)(accum + 2);
    int*    ovf  = (int*)w;                            w += (size_t)2*BN*4;    // 0.25 MB
    unsigned long long* ovf_key = (unsigned long long*)w;  w += (size_t)2*BN*8; // 0.5 MB

    hipMemsetAsync(hist, 0, (size_t)8*NCELLS*4, stream);
    hipLaunchKernelGGL(prep_kernel,    dim3(2*BN/256), dim3(256),  0, stream,
                       gt, pred, idxw, P4, hist, accum, counter, ovf_count);
    hipLaunchKernelGGL(scan_kernel,    dim3(8),        dim3(1024), 0, stream,
                       hist, combo);
    hipLaunchKernelGGL(scatter_kernel, dim3(2*BN/256), dim3(256),  0, stream,
                       P4, hist, combo, S);
    hipLaunchKernelGGL(knn_main_kernel, dim3(2*BN*4/256), dim3(256), 0, stream,
                       P4, S, combo, Cov, ovf, ovf_key, ovf_count);
    hipLaunchKernelGGL(brute_kernel,   dim3(BRUTE_BLOCKS), dim3(256), 0, stream,
                       P4, ovf, ovf_key, ovf_count, Cov);
    hipLaunchKernelGGL(eigh_loss_kernel, dim3(2*BN/256), dim3(256), 0, stream,
                       Cov, accum, counter, out);
}

// Round 3
// 304.689 us; speedup vs baseline: 1.0599x; 1.0209x over previous
//
#include <hip/hip_runtime.h>
#include <math.h>

#define BB   4
#define NN   8192
#define BN   (BB*NN)       // 32768 points per cloud-set; 8 clouds of 8192 total
#define KNN  10
#define G    32            // grid cells per dim
#define NCELLS (G*G*G)     // 32768 cells per cloud
#define GRID_LO (-5.0f)
#define H    0.3125f       // 10/32
#define INV_H 3.2f
#define RCAP 2             // rho<=2 region; beyond -> brute overflow

#define SEPS    5.9604645e-8f        // slamch('E') = 2^-24
#define SEPS2   (SEPS*SEPS)
#define SSAFMIN 1.1754944e-38f

__device__ __forceinline__ int cellc(float v) {
    int c = (int)floorf((v - GRID_LO) * INV_H);
    return min(G - 1, max(0, c));
}

// ---------------------------------------------------------------------------
// Kernel A: build P4[8][8192] = (x,y,z, bitcast orig-idx); clouds 0-3 = gt
// batches, 4-7 = pred[idx12] batches. Histogram cells + zero accumulators.
// ---------------------------------------------------------------------------
__global__ __launch_bounds__(256) void prep_kernel(
    const float* __restrict__ gt, const float* __restrict__ pred,
    const unsigned* __restrict__ idxw, float4* __restrict__ P4,
    int* __restrict__ hist, float* __restrict__ accum,
    unsigned* __restrict__ counter, int* __restrict__ ovf_count)
{
    __shared__ int s_is32;
    int tid = threadIdx.x;
    if (tid == 0) s_is32 = 0;
    __syncthreads();
    if (idxw[2*tid + 1] != 0u) s_is32 = 1;   // int64 => all high words 0
    __syncthreads();
    bool is64 = (s_is32 == 0);

    if (blockIdx.x == 0 && tid == 0) {
        *accum = 0.0f; *counter = 0u; *ovf_count = 0;
    }

    int point = blockIdx.x * 256 + tid;        // 0 .. 2*BN-1
    int pair = point >> 13;                    // 0..7
    int r    = point & (NN - 1);               // idx within cloud
    float x, y, z;
    if (point < BN) {
        const float* s = gt + (size_t)point*3;
        x = s[0]; y = s[1]; z = s[2];
    } else {
        int rr = point - BN;
        int b = rr >> 13;
        unsigned idx = is64 ? idxw[2*(size_t)rr] : idxw[rr];
        const float* s = pred + ((size_t)b*NN + idx)*3;
        x = s[0]; y = s[1]; z = s[2];
    }
    P4[point] = make_float4(x, y, z, __int_as_float(r));
    int cell = (cellc(z)*G + cellc(y))*G + cellc(x);
    atomicAdd(&hist[(size_t)pair*NCELLS + cell], 1);
}

// ---------------------------------------------------------------------------
// Kernel B: per-cloud exclusive scan -> combo[c] = int2(start, count).
// ---------------------------------------------------------------------------
__global__ __launch_bounds__(1024) void scan_kernel(
    const int* __restrict__ hist, int2* __restrict__ combo)
{
    int cloud = blockIdx.x;
    int tid = threadIdx.x;
    int lane = tid & 63, wid = tid >> 6;
    const int* h = hist + (size_t)cloud * NCELLS;
    int2* cb = combo + (size_t)cloud * NCELLS;

    int loc[32];
    int base = tid * 32;
    const int4* h4 = (const int4*)(h + base);
    int sum = 0;
    #pragma unroll
    for (int i = 0; i < 8; ++i) {
        int4 a = h4[i];
        loc[4*i+0] = a.x; loc[4*i+1] = a.y; loc[4*i+2] = a.z; loc[4*i+3] = a.w;
        sum += a.x + a.y + a.z + a.w;
    }
    // inclusive wave scan of sums
    int v = sum;
    #pragma unroll
    for (int off = 1; off < 64; off <<= 1) {
        int o = __shfl_up(v, off, 64);
        if (lane >= off) v += o;
    }
    __shared__ int ws[16], wsx[16];
    if (lane == 63) ws[wid] = v;
    __syncthreads();
    if (tid < 16) {
        int acc = 0;
        for (int i = 0; i < tid; ++i) acc += ws[i];
        wsx[tid] = acc;
    }
    __syncthreads();
    int run = (v - sum) + wsx[wid];            // exclusive prefix for this thread

    int4* cb4 = (int4*)(cb + base);            // 2 cells per int4 store
    #pragma unroll
    for (int i = 0; i < 16; ++i) {
        int4 o;
        o.x = run; o.y = loc[2*i];     run += loc[2*i];
        o.z = run; o.w = loc[2*i+1];   run += loc[2*i+1];
        cb4[i] = o;
    }
}

// ---------------------------------------------------------------------------
// Kernel C: scatter points into cell-sorted S.
// ---------------------------------------------------------------------------
__global__ __launch_bounds__(256) void scatter_kernel(
    const float4* __restrict__ P4, int* __restrict__ hist,
    const int2* __restrict__ combo, float4* __restrict__ S)
{
    int point = blockIdx.x * 256 + threadIdx.x;
    float4 p = P4[point];
    int pair = point >> 13;
    int cell = (cellc(p.z)*G + cellc(p.y))*G + cellc(p.x);
    int old = atomicSub(&hist[(size_t)pair*NCELLS + cell], 1);
    int pos = combo[(size_t)pair*NCELLS + cell].x + old - 1;
    S[(size_t)pair*NN + pos] = p;
}

// ---------------------------------------------------------------------------
// LAPACK ssyevd 3x3 path: ssytrd('L') + sorgtr + ssteqr('V'). Sign-faithful.
// (verified absmax 0.0 in rounds 2-18 — do not touch)
// ---------------------------------------------------------------------------
__device__ __forceinline__ float f_sign(float a, float b) {
    return copysignf(a, b);
}
__device__ __forceinline__ float slapy2(float x, float y) {
#pragma clang fp contract(off)
    float xa = fabsf(x), ya = fabsf(y);
    float w = fmaxf(xa, ya), z = fminf(xa, ya);
    if (z == 0.0f) return w;
    float t = z / w;
    return w * __fsqrt_rn(1.0f + t*t);
}
__device__ __forceinline__ void slartg_(float f, float g, float* cs, float* sn, float* r) {
#pragma clang fp contract(off)
    if (g == 0.0f)      { *cs = 1.0f; *sn = 0.0f; *r = f; }
    else if (f == 0.0f) { *cs = 0.0f; *sn = f_sign(1.0f, g); *r = fabsf(g); }
    else {
        float f1 = fabsf(f);
        float d = __fsqrt_rn(f*f + g*g);
        float p = 1.0f / d;
        *cs = f1 * p;
        *sn = g * f_sign(p, f);
        *r  = f_sign(d, f);
    }
}
__device__ void slaev2_(float a, float b, float c,
                        float* rt1, float* rt2, float* cs1, float* sn1) {
#pragma clang fp contract(off)
    float sm = a + c, df = a - c;
    float adf = fabsf(df);
    float tb = b + b;
    float ab = fabsf(tb);
    float acmx, acmn;
    if (fabsf(a) > fabsf(c)) { acmx = a; acmn = c; } else { acmx = c; acmn = a; }
    float rt;
    if (adf > ab)      { float t = ab/adf; rt = adf*__fsqrt_rn(1.0f + t*t); }
    else if (adf < ab) { float t = adf/ab; rt = ab*__fsqrt_rn(1.0f + t*t); }
    else               { rt = ab*__fsqrt_rn(2.0f); }
    int sgn1;
    if (sm < 0.0f)      { *rt1 = 0.5f*(sm - rt); sgn1 = -1;
                          *rt2 = (acmx / *rt1)*acmn - (b / *rt1)*b; }
    else if (sm > 0.0f) { *rt1 = 0.5f*(sm + rt); sgn1 = 1;
                          *rt2 = (acmx / *rt1)*acmn - (b / *rt1)*b; }
    else                { *rt1 = 0.5f*rt; *rt2 = -0.5f*rt; sgn1 = 1; }
    float cs; int sgn2;
    if (df >= 0.0f) { cs = df + rt; sgn2 = 1; } else { cs = df - rt; sgn2 = -1; }
    float acs = fabsf(cs);
    float c1, s1;
    if (acs > ab) { float ct = -tb/cs; s1 = 1.0f/__fsqrt_rn(1.0f + ct*ct); c1 = ct*s1; }
    else {
        if (ab == 0.0f) { c1 = 1.0f; s1 = 0.0f; }
        else { float tn = -cs/tb; c1 = 1.0f/__fsqrt_rn(1.0f + tn*tn); s1 = tn*c1; }
    }
    if (sgn1 == sgn2) { float tn = c1; c1 = -s1; s1 = tn; }
    *cs1 = c1; *sn1 = s1;
}

__device__ void eigh3_smallest(float c00, float c01, float c02,
                               float c11, float c12, float c22, float nv[3])
{
#pragma clang fp contract(off)
    // ---- ssytrd('L') ----
    float d[4], e[3], z[4][4];
    float tau1, v2 = 0.0f;
    float e1, d2, d3, e2;
    float alpha = c01, x = c02;
    if (x == 0.0f) {
        tau1 = 0.0f; e1 = alpha;
        d2 = c11; d3 = c22; e2 = c12;
    } else {
        float beta = -f_sign(slapy2(alpha, fabsf(x)), alpha);
        tau1 = (beta - alpha) / beta;
        v2 = x / (alpha - beta);
        e1 = beta;
        float w1 = tau1*(c11 + c12*v2);
        float w2 = tau1*(c12 + c22*v2);
        float al = -0.5f*tau1*(w1 + w2*v2);
        w1 = w1 + al;
        w2 = w2 + al*v2;
        d2 = (c11 - w1) - w1;
        e2 = (c12 - v2*w1) - w2;
        d3 = (c22 - v2*w2) - w2*v2;
    }
    d[1] = c00; d[2] = d2; d[3] = d3;
    e[1] = e1;  e[2] = e2;
    z[1][1] = 1.0f; z[1][2] = 0.0f; z[1][3] = 0.0f;
    z[2][1] = 0.0f; z[3][1] = 0.0f;
    z[2][2] = 1.0f - tau1;
    float mtv = -tau1*v2;
    z[2][3] = mtv; z[3][2] = mtv;
    z[3][3] = 1.0f + mtv*v2;

    // ---- ssteqr('V', 3) ----
    const int n = 3, nm1 = 2;
    int l1 = 1, jtot = 0;
    const int nmaxit = 90;
    float cw[3], sw[3];
    int guard = 0;
    while (guard++ < 64) {
        if (l1 > n) break;
        if (l1 > 1) e[l1-1] = 0.0f;
        int m = n;
        if (l1 <= nm1) {
            for (int mi = l1; mi <= nm1; ++mi) {
                float tst = fabsf(e[mi]);
                if (tst == 0.0f) { m = mi; break; }
                if (tst <= (__fsqrt_rn(fabsf(d[mi]))*__fsqrt_rn(fabsf(d[mi+1])))*SEPS) {
                    e[mi] = 0.0f; m = mi; break;
                }
            }
        }
        int l = l1;
        int lsv = l, lend = m, lendsv = lend;
        l1 = m + 1;
        if (lend == l) continue;
        if (fabsf(d[lend]) < fabsf(d[l])) { lend = lsv; l = lendsv; }

        if (lend > l) {
            // QL
            while (true) {
                int m_ = lend;
                if (l != lend) {
                    for (int mi = l; mi <= lend-1; ++mi) {
                        float em = e[mi];
                        float tst = em*em;
                        if (tst <= (SEPS2*fabsf(d[mi]))*fabsf(d[mi+1]) + SSAFMIN) { m_ = mi; break; }
                    }
                }
                if (m_ < lend) e[m_] = 0.0f;
                float p = d[l];
                if (m_ == l) {
                    d[l] = p; l = l + 1;
                    if (l <= lend) continue; else break;
                }
                if (m_ == l + 1) {
                    float rt1, rt2, cc, ss;
                    slaev2_(d[l], e[l], d[l+1], &rt1, &rt2, &cc, &ss);
                    for (int i = 1; i <= 3; ++i) {
                        float tmp = z[i][l+1];
                        z[i][l+1] = cc*tmp - ss*z[i][l];
                        z[i][l]   = ss*tmp + cc*z[i][l];
                    }
                    d[l] = rt1; d[l+1] = rt2; e[l] = 0.0f;
                    l = l + 2;
                    if (l <= lend) continue; else break;
                }
                if (jtot == nmaxit) break;
                jtot++;
                float g = (d[l+1] - p) / (2.0f*e[l]);
                float r = slapy2(g, 1.0f);
                g = d[m_] - p + (e[l] / (g + f_sign(r, g)));
                float s = 1.0f, c = 1.0f;
                p = 0.0f;
                for (int i = m_-1; i >= l; --i) {
                    float f = s*e[i];
                    float b = c*e[i];
                    slartg_(g, f, &c, &s, &r);
                    if (i != m_-1) e[i+1] = r;
                    g = d[i+1] - p;
                    r = (d[i] - g)*s + (2.0f*c)*b;
                    p = s*r;
                    d[i+1] = g + p;
                    g = c*r - b;
                    cw[i] = c; sw[i] = -s;
                }
                for (int j = m_-1; j >= l; --j) {
                    float cc = cw[j], ss = sw[j];
                    for (int i = 1; i <= 3; ++i) {
                        float tmp = z[i][j+1];
                        z[i][j+1] = cc*tmp - ss*z[i][j];
                        z[i][j]   = ss*tmp + cc*z[i][j];
                    }
                }
                d[l] = d[l] - p;
                e[l] = g;
            }
        } else {
            // QR
            while (true) {
                int m_ = lend;
                if (l != lend) {
                    for (int mi = l; mi >= lend+1; --mi) {
                        float em = e[mi-1];
                        float tst = em*em;
                        if (tst <= (SEPS2*fabsf(d[mi]))*fabsf(d[mi-1]) + SSAFMIN) { m_ = mi; break; }
                    }
                }
                if (m_ > lend) e[m_-1] = 0.0f;
                float p = d[l];
                if (m_ == l) {
                    d[l] = p; l = l - 1;
                    if (l >= lend) continue; else break;
                }
                if (m_ == l - 1) {
                    float rt1, rt2, cc, ss;
                    slaev2_(d[l-1], e[l-1], d[l], &rt1, &rt2, &cc, &ss);
                    for (int i = 1; i <= 3; ++i) {
                        float tmp = z[i][l];
                        z[i][l]   = cc*tmp - ss*z[i][l-1];
                        z[i][l-1] = ss*tmp + cc*z[i][l-1];
                    }
                    d[l-1] = rt1; d[l] = rt2; e[l-1] = 0.0f;
                    l = l - 2;
                    if (l >= lend) continue; else break;
                }
                if (jtot == nmaxit) break;
                jtot++;
                float g = (d[l-1] - p) / (2.0f*e[l-1]);
                float r = slapy2(g, 1.0f);
                g = d[m_] - p + (e[l-1] / (g + f_sign(r, g)));
                float s = 1.0f, c = 1.0f;
                p = 0.0f;
                for (int i = m_; i <= l-1; ++i) {
                    float f = s*e[i];
                    float b = c*e[i];
                    slartg_(g, f, &c, &s, &r);
                    if (i != m_) e[i-1] = r;
                    g = d[i] - p;
                    r = (d[i+1] - g)*s + (2.0f*c)*b;
                    p = s*r;
                    d[i] = g + p;
                    g = c*r - b;
                    cw[i] = c; sw[i] = s;
                }
                for (int j = m_; j <= l-1; ++j) {
                    float cc = cw[j], ss = sw[j];
                    for (int i = 1; i <= 3; ++i) {
                        float tmp = z[i][j+1];
                        z[i][j+1] = cc*tmp - ss*z[i][j];
                        z[i][j]   = ss*tmp + cc*z[i][j];
                    }
                }
                d[l] = d[l] - p;
                e[l-1] = g;
            }
        }
    }
    for (int ii = 2; ii <= 3; ++ii) {
        int i = ii - 1, k = i;
        float p = d[i];
        for (int j = ii; j <= 3; ++j) if (d[j] < p) { k = j; p = d[j]; }
        if (k != i) {
            d[k] = d[i]; d[i] = p;
            for (int r2 = 1; r2 <= 3; ++r2) {
                float t = z[r2][i]; z[r2][i] = z[r2][k]; z[r2][k] = t;
            }
        }
    }
    nv[0] = z[1][1]; nv[1] = z[2][1]; nv[2] = z[3][1];
}

// Covariance of the sorted 10-neighborhood (same op order as rounds 2-18).
__device__ void cov_compute(const float4* __restrict__ cl,
                            const unsigned long long keys[KNN], float c[6])
{
#pragma clang fp contract(off)
    float px[KNN], py[KNN], pz[KNN];
    float sx = 0.f, sy = 0.f, sz = 0.f;
    #pragma unroll
    for (int s = 0; s < KNN; ++s) {
        int ni = (int)(unsigned)(keys[s] & 0xFFFFFFFFull);
        float4 np = cl[ni];
        px[s] = np.x; py[s] = np.y; pz[s] = np.z;
        sx = sx + px[s]; sy = sy + py[s]; sz = sz + pz[s];
    }
    float mx = sx / 10.0f, my = sy / 10.0f, mz = sz / 10.0f;
    float c00=0.f,c01=0.f,c02=0.f,c11=0.f,c12=0.f,c22=0.f;
    #pragma unroll
    for (int s = 0; s < KNN; ++s) {
        float dx = px[s]-mx, dy = py[s]-my, dz = pz[s]-mz;
        c00 = c00 + dx*dx; c01 = c01 + dx*dy; c02 = c02 + dx*dz;
        c11 = c11 + dy*dy; c12 = c12 + dy*dz; c22 = c22 + dz*dz;
    }
    c[0] = c00/10.0f; c[1] = c01/10.0f; c[2] = c02/10.0f;
    c[3] = c11/10.0f; c[4] = c12/10.0f; c[5] = c22/10.0f;
}

// ---------------------------------------------------------------------------
// Insert: gate = min(own 10th, quad bound). Dropping candidates >= the quad
// bound is exact: some lane already holds 10 strictly-better keys. In phase 2
// qbK is set to ~0ull so the gate degenerates to the (exact) own 10th.
// ---------------------------------------------------------------------------
#define PROC(p) do { \
    float ddx = qx - (p).x, ddy = qy - (p).y, ddz = qz - (p).z; \
    float dd = fmaf(ddz, ddz, fmaf(ddy, ddy, ddx*ddx)); \
    unsigned long long key = \
        ((unsigned long long)__float_as_uint(dd) << 32) | \
        (unsigned)__float_as_int((p).w); \
    if (key < kgate) { \
        unsigned long long ck = key; \
        _Pragma("unroll") \
        for (int s = 0; s < KNN; ++s) { \
            unsigned long long ok2 = keys[s]; \
            bool sw = ok2 > ck; \
            keys[s] = sw ? ck : ok2; \
            ck      = sw ? ok2 : ck; \
        } \
        k9 = keys[KNN-1]; \
        kgate = (k9 < qbK) ? k9 : qbK; \
    } \
} while (0)

// stream a contiguous candidate segment [b, b+n) of S — 2 loads in flight
#define SEGPROC(b, n) do { \
    int _j = (b), _je = (b) + (n); \
    for (; _j + 2 <= _je; _j += 2) { \
        float4 _p0 = cs[_j]; float4 _p1 = cs[_j+1]; \
        PROC(_p0); PROC(_p1); \
    } \
    if (_j < _je) { float4 _p0 = cs[_j]; PROC(_p0); } \
} while (0)

// quad-min of the four lanes' current 10th keys; low word forced to all-ones
// so ties on the distance bits still pass the gate (tie-exact).
#define QEXCH() do { \
    unsigned long long _o1 = __shfl_xor(k9, 1, 4); \
    unsigned long long _m1 = (_o1 < k9) ? _o1 : k9; \
    unsigned long long _o2 = __shfl_xor(_m1, 2, 4); \
    unsigned long long _qm = (_o2 < _m1) ? _o2 : _m1; \
    qbK = _qm | 0xFFFFFFFFull; \
    kgate = (k9 < qbK) ? k9 : qbK; \
} while (0)

// 4-way compile-time coordinate select (3 cndmasks, once per slot)
#define SEL4(A,B,C,D) (sub == 0 ? (A) : (sub == 1 ? (B) : (sub == 2 ? (C) : (D))))

// ---------------------------------------------------------------------------
// Kernel D (R21 structure, unchanged in R22): grid 10-NN, FOUR lanes per
// query, ONE list per lane. After the rho<=1 cube walk the 4 phase-1 lists
// are merged -> every lane holds the EXACT cube top-10 -> exact phase-2 skip
// + tight pruning. Phase-2 inserts go directly into the merged list; final
// dedupe-merge only when some lane inserted. Bit-identical output.
// ---------------------------------------------------------------------------
__global__ __launch_bounds__(256) void knn_main_kernel(
    const float4* __restrict__ P4, const float4* __restrict__ S,
    const int2* __restrict__ combo, float4* __restrict__ Cov,
    int* __restrict__ ovf, unsigned long long* __restrict__ ovf_key,
    int* __restrict__ ovf_count)
{
    int tidg = blockIdx.x * 256 + threadIdx.x;  // 0..262143
    int qid  = tidg >> 2;                       // 0..65535
    int sub  = tidg & 3;
    int pair = qid >> 13;                       // 8 clouds
    int spos = qid & (NN - 1);                  // sorted position
    const float4* __restrict__ cl = P4 + (size_t)pair * NN;
    const float4* __restrict__ cs = S  + (size_t)pair * NN;
    const int2*   __restrict__ cb = combo + (size_t)pair * NCELLS;

    float4 q = cs[spos];
    float qx = q.x, qy = q.y, qz = q.z;
    int qi = __float_as_int(q.w);               // original index in cloud
    int qcx = cellc(qx), qcy = cellc(qy), qcz = cellc(qz);

    unsigned long long keys[KNN];
    #pragma unroll
    for (int s = 0; s < KNN; ++s) keys[s] = 0xFFFFFFFFFFFFFFFFull;
    unsigned long long k9    = 0xFFFFFFFFFFFFFFFFull;
    unsigned long long qbK   = 0xFFFFFFFFFFFFFFFFull;
    unsigned long long kgate = 0xFFFFFFFFFFFFFFFFull;

    // ---- phase 1: rho<=1 cube, 9 rows checkerboarded 3/2/2/2.
    // Each lane's CENTRAL row first, so lists fill with near candidates and
    // the inter-slot quad bound (QEXCH) tightens early.
    int x0 = max(qcx - 1, 0), x1 = min(qcx + 1, G - 1);
#define P1SLOT(i, ZA,YA, ZB,YB, ZC,YC, ZD,YD) \
    int rb##i = 0, re##i = 0; \
    { int zz = qcz + SEL4(ZA,ZB,ZC,ZD); \
      int yy = qcy + SEL4(YA,YB,YC,YD); \
      if ((unsigned)zz < G && (unsigned)yy < G) { \
          int cbase = (zz*G + yy)*G; \
          int2 a = cb[cbase + x0]; \
          int2 b = cb[cbase + x1]; \
          rb##i = a.x; re##i = b.x + b.y; } }
    P1SLOT(0,  0, 0,  0,1, -1,1, 0,-1)
    P1SLOT(1, -1,-1, -1,0,  1,-1, 1, 0)
    P1SLOT(2,  1, 1, 99,99, 99,99, 99,99)   // lanes 1-3 invalid -> bounds fail
#undef P1SLOT
    SEGPROC(rb0, re0 - rb0);
    QEXCH();
    SEGPROC(rb1, re1 - rb1);
    QEXCH();
    SEGPROC(rb2, re2 - rb2);

    // ---- merge the 4 phase-1 lists NOW -> exact top-10 over the cube,
    // identical in all 4 lanes (symmetric butterfly; no dups: disjoint cells).
    #pragma unroll
    for (int m = 1; m < 4; m <<= 1) {
        unsigned long long other[KNN];
        #pragma unroll
        for (int s = 0; s < KNN; ++s)
            other[s] = __shfl_xor(keys[s], m, 4);   // snapshot before inserts
        #pragma unroll
        for (int s = 0; s < KNN; ++s) {
            unsigned long long key = other[s];
            if (key < k9) {
                unsigned long long ck = key;
                #pragma unroll
                for (int t = 0; t < KNN; ++t) {
                    unsigned long long ok2 = keys[t];
                    bool sw = ok2 > ck;
                    keys[t] = sw ? ck : ok2;
                    ck      = sw ? ok2 : ck;
                }
                k9 = keys[KNN-1];
            }
        }
    }
    const unsigned long long k9M = k9;          // exact cube 10th (u64 key)
    float worstM = __uint_as_float((unsigned)(k9M >> 32)); // NaN if <10 found

    // ---- phase 2: rho=2 shell. Exterior of the cube is >= H from q, so
    // skip iff H^2 > worstM is EXACT (NaN-safe: NaN -> walk shell).
    bool skip = (H*H > worstM);                 // quad-uniform (worstM shared)

    // phase-2 inserts go directly into the merged list; gate = own 10th only
    qbK   = 0xFFFFFFFFFFFFFFFFull;
    kgate = k9;
    {
        int xs0 = max(qcx - 2, 0), xs1 = min(qcx + 2, G - 1);
        // 16 outer rows, checkerboarded 4/4/4/4; prune with exact bound worstM
#define S2SLOT(i, ZA,YA, ZB,YB, ZC,YC, ZD,YD) \
        int sb##i = 0, sn##i = 0; \
        if (!skip) { \
          int zz = qcz + SEL4(ZA,ZB,ZC,ZD); \
          int yy = qcy + SEL4(YA,YB,YC,YD); \
          if ((unsigned)zz < G && (unsigned)yy < G) { \
              float loy = fmaf((float)yy, H, GRID_LO); \
              float loz = fmaf((float)zz, H, GRID_LO); \
              float py = fmaxf(0.0f, fmaxf(loy - qy, qy - (loy + H))); \
              float pz = fmaxf(0.0f, fmaxf(loz - qz, qz - (loz + H))); \
              float pyz = fmaf(pz, pz, py*py); \
              if (!(pyz > worstM)) { \
                  int cbase = (zz*G + yy)*G; \
                  int2 a = cb[cbase + xs0]; \
                  int2 b = cb[cbase + xs1]; \
                  sb##i = a.x; sn##i = (b.x + b.y) - a.x; } } }
        S2SLOT(0, -2,-2, -2,-1, -2,0, -2,1)
        S2SLOT(1, -2, 2,  2,-2,  2,-1, 2,0)
        S2SLOT(2,  2, 1,  2, 2, -1,-2, -1,2)
        S2SLOT(3,  0,-2,  0, 2,  1,-2,  1,2)
#undef S2SLOT
        // 18 isolated cells (|dz|<=1,|dy|<=1, dx=+/-2), 5 slots x 4 lanes
#define CSLOT(i, ZA,YA,XA, ZB,YB,XB, ZC,YC,XC, ZD,YD,XD) \
        int tb##i = 0, tn##i = 0; \
        if (!skip) { \
          int zz = qcz + SEL4(ZA,ZB,ZC,ZD); \
          int yy = qcy + SEL4(YA,YB,YC,YD); \
          int xx = qcx + SEL4(XA,XB,XC,XD); \
          if ((unsigned)zz < G && (unsigned)yy < G && (unsigned)xx < G) { \
              float lox = fmaf((float)xx, H, GRID_LO); \
              float loy = fmaf((float)yy, H, GRID_LO); \
              float loz = fmaf((float)zz, H, GRID_LO); \
              float px = fmaxf(0.0f, fmaxf(lox - qx, qx - (lox + H))); \
              float py = fmaxf(0.0f, fmaxf(loy - qy, qy - (loy + H))); \
              float pz = fmaxf(0.0f, fmaxf(loz - qz, qz - (loz + H))); \
              float m2 = fmaf(pz, pz, fmaf(py, py, px*px)); \
              if (!(m2 > worstM)) { \
                  int2 a = cb[(zz*G + yy)*G + xx]; \
                  tb##i = a.x; tn##i = a.y; } } }
        CSLOT(0, -1,-1,-2, -1,-1,2, -1,0,-2, -1,0,2)
        CSLOT(1, -1, 1,-2, -1, 1,2,  0,-1,-2, 0,-1,2)
        CSLOT(2,  0, 0,-2,  0, 0,2,  0, 1,-2, 0, 1,2)
        CSLOT(3,  1,-1,-2,  1,-1,2,  1, 0,-2, 1, 0,2)
        CSLOT(4,  1, 1,-2,  1, 1,2, 99,99,0, 99,99,0)
#undef CSLOT
#define S2GO(i) SEGPROC(sb##i, sn##i);
        S2GO(0) S2GO(1) S2GO(2) S2GO(3)
#undef S2GO
#define CGO(i) SEGPROC(tb##i, tn##i);
        CGO(0) CGO(1) CGO(2) CGO(3) CGO(4)
#undef CGO
    }

    // ---- final: dedupe-merge the 4 lists (cube survivors are shared), but
    // only if some lane actually inserted a shell candidate. Every successful
    // insert strictly lowers k9, so "changed" == (k9 != k9M). skip and ch are
    // quad-uniform -> the shfls inside are safe.
    if (!skip) {
        int ch = (k9 != k9M) ? 1 : 0;
        ch |= __shfl_xor(ch, 1, 4);
        ch |= __shfl_xor(ch, 2, 4);
        if (ch) {
            #pragma unroll
            for (int m = 1; m < 4; m <<= 1) {
                unsigned long long other[KNN];
                #pragma unroll
                for (int s = 0; s < KNN; ++s)
                    other[s] = __shfl_xor(keys[s], m, 4);  // snapshot
                #pragma unroll
                for (int s = 0; s < KNN; ++s) {
                    unsigned long long key = other[s];
                    if (key >= k9) break;       // other sorted ascending
                    bool dup = false;
                    #pragma unroll
                    for (int t = 0; t < KNN; ++t) dup = dup || (keys[t] == key);
                    if (!dup) {
                        unsigned long long ck = key;
                        #pragma unroll
                        for (int t = 0; t < KNN; ++t) {
                            unsigned long long ok2 = keys[t];
                            bool sw = ok2 > ck;
                            keys[t] = sw ? ck : ok2;
                            ck      = sw ? ok2 : ck;
                        }
                        k9 = keys[KNN-1];
                    }
                }
            }
        }
    }
    float worst_m = __uint_as_float((unsigned)(k9 >> 32));

    // resolved iff cells beyond the rho<=2 region (gap >= 2H) cannot contribute
    float bf = (float)RCAP * H;
    bool resolved = (bf*bf > worst_m);          // strict; NaN (unfilled) -> false
    if (resolved && sub == 0) {
        float c[6];
        cov_compute(cl, keys, c);               // sub==0 only: 1/4 gather loads
        size_t o = ((size_t)pair*NN + qi)*2;
        Cov[o]   = make_float4(c[0], c[1], c[2], c[3]);
        Cov[o+1] = make_float4(c[4], c[5], 0.0f, 0.0f);
    } else if (!resolved && sub == 0) {
        int pos = atomicAdd(ovf_count, 1);
        ovf[pos] = (pair << 13) | qi;
        ovf_key[pos] = k9;      // merged 10th-best: valid upper bound on true
    }                           // 10th key (subset 10th >= full-set 10th)
}

// ---------------------------------------------------------------------------
// Kernel D2 (R22): brute-force overflow, ONE WAVE per query (4 per block),
// no LDS, no __syncthreads. Per-lane bound-gated scan of a disjoint 1/64
// slice (coalesced cl[i*64+lane]), then a 10-round EXTRACTION merge: per
// round, wave-wide u64-min butterfly finds the global min (keys unique by
// index low-word -> unique owner), every lane records it, the owning lane
// shifts its sorted list down one (static indexing). This replaces the old
// 6-stage x 10-key butterfly whose exec-masked 75-instr insert chain fired
// on nearly every stage x slot (~36K cycles/query -> the whole 103 us).
// Extraction of the 10 smallest of the union, ascending, == exact top-10 in
// the same sorted order as before => bit-identical cov => absmax 0.0.
// ---------------------------------------------------------------------------
#define BRUTE_BLOCKS 2048
__global__ __launch_bounds__(256) void brute_kernel(
    const float4* __restrict__ P4, const int* __restrict__ ovf,
    const unsigned long long* __restrict__ ovf_key,
    const int* __restrict__ ovf_count, float4* __restrict__ Cov)
{
    int tid = threadIdx.x;
    int lane = tid & 63;
    int wid = tid >> 6;
    int count = *ovf_count;

    for (int oi = blockIdx.x * 4 + wid; oi < count; oi += BRUTE_BLOCKS * 4) {
        int rec = ovf[oi];
        unsigned long long bound = ovf_key[oi];
        float bound_d = __uint_as_float((unsigned)(bound >> 32)); // NaN if unfilled
        int pair = rec >> 13;
        int qi = rec & (NN - 1);
        const float4* __restrict__ cl = P4 + (size_t)pair * NN;
        float4 q = cl[qi];
        float qx = q.x, qy = q.y, qz = q.z;

        unsigned long long keys[KNN];
        #pragma unroll
        for (int s = 0; s < KNN; ++s) keys[s] = 0xFFFFFFFFFFFFFFFFull;
        unsigned long long k9 = keys[KNN-1];

        // per-lane scan with bound gate; ties at dd==bound_d pass (exact).
        // The true 10 NN all satisfy dd <= true 10th <= bound_d, so >=10
        // real keys survive across the wave (NaN bound -> all pass).
#define BPROC(p, jj) do { \
        float ddx = qx - (p).x, ddy = qy - (p).y, ddz = qz - (p).z; \
        float dd = fmaf(ddz, ddz, fmaf(ddy, ddy, ddx*ddx)); \
        if (!(dd > bound_d)) { \
            unsigned long long key = \
                ((unsigned long long)__float_as_uint(dd) << 32) | (unsigned)(jj); \
            if (key < k9) { \
                unsigned long long ck = key; \
                _Pragma("unroll") \
                for (int s = 0; s < KNN; ++s) { \
                    unsigned long long ok2 = keys[s]; \
                    bool sw = ok2 > ck; \
                    keys[s] = sw ? ck : ok2; \
                    ck      = sw ? ok2 : ck; \
                } \
                k9 = keys[KNN-1]; \
            } \
        } \
    } while (0)
        #pragma unroll 1
        for (int i = 0; i < NN/64; i += 4) {    // 32 iters, 4 loads in flight
            float4 p0 = cl[(i+0)*64 + lane];
            float4 p1 = cl[(i+1)*64 + lane];
            float4 p2 = cl[(i+2)*64 + lane];
            float4 p3 = cl[(i+3)*64 + lane];
            BPROC(p0, (i+0)*64 + lane);
            BPROC(p1, (i+1)*64 + lane);
            BPROC(p2, (i+2)*64 + lane);
            BPROC(p3, (i+3)*64 + lane);
        }
#undef BPROC

        // 10-round extraction merge: exact top-10 of the union, ascending.
        unsigned long long fin[KNN];
        #pragma unroll
        for (int r = 0; r < KNN; ++r) {
            unsigned long long m = keys[0];
            #pragma unroll
            for (int off = 1; off < 64; off <<= 1) {
                unsigned long long o = __shfl_xor(m, off);
                m = (o < m) ? o : m;
            }
            fin[r] = m;
            if (keys[0] == m) {                 // unique owner (keys unique)
                #pragma unroll
                for (int t = 0; t < KNN-1; ++t) keys[t] = keys[t+1];
                keys[KNN-1] = 0xFFFFFFFFFFFFFFFFull;
            }
        }

        if (lane == 0) {
            float c[6];
            cov_compute(cl, fin, c);
            size_t o = ((size_t)pair*NN + qi)*2;
            Cov[o]   = make_float4(c[0], c[1], c[2], c[3]);
            Cov[o+1] = make_float4(c[4], c[5], 0.0f, 0.0f);
        }
    }
}

// ---------------------------------------------------------------------------
// Kernel E (R19): fused eigh + loss, ONE eigh per thread over 2*BN threads.
// Thread 2k handles gt[k], thread 2k+1 handles pred[k]; normals exchanged
// in-wave via shfl_xor(1); even lanes compute 1-cos; block reduce; atomic.
// Identical eigh inputs -> bit-identical normals (summation grouping only).
// ---------------------------------------------------------------------------
__global__ __launch_bounds__(256) void eigh_loss_kernel(
    const float4* __restrict__ Cov, float* __restrict__ accum,
    unsigned* __restrict__ counter, float* __restrict__ out)
{
    int tid = threadIdx.x;
    int t = blockIdx.x * 256 + tid;            // 0..2*BN-1
    int k = t >> 1;                            // pair index 0..BN-1
    int cld = t & 1;                           // 0 = gt, 1 = pred
    size_t ci = ((size_t)(cld ? BN + k : k)) * 2;
    float4 a0 = Cov[ci], a1 = Cov[ci + 1];
    float n[3];
    eigh3_smallest(a0.x, a0.y, a0.z, a0.w, a1.x, a1.y, n);

    // exchange with partner lane (2k <-> 2k+1 always share a wave)
    float ox = __shfl_xor(n[0], 1);
    float oy = __shfl_xor(n[1], 1);
    float oz = __shfl_xor(n[2], 1);

    float v = 0.0f;
    if (cld == 0) {
        float gx=n[0], gy=n[1], gz=n[2];
        float hx=ox,  hy=oy,  hz=oz;
        float dot = fmaf(gx,hx,fmaf(gy,hy,gz*hz));
        float ng  = sqrtf(fmaf(gx,gx,fmaf(gy,gy,gz*gz)));
        float nh  = sqrtf(fmaf(hx,hx,fmaf(hy,hy,hz*hz)));
        float den = fmaxf(ng*nh, 1e-8f);
        v = 1.0f - dot/den;
    }

    __shared__ float red[256];
    red[tid] = v;                              // odd lanes contribute 0
    __syncthreads();
    for (int s = 128; s > 0; s >>= 1) {
        if (tid < s) red[tid] += red[tid+s];
        __syncthreads();
    }
    if (tid == 0) {
        atomicAdd(accum, red[0]);
        __threadfence();
        unsigned old = atomicAdd(counter, 1u);
        if (old == (unsigned)(2*BN/256 - 1)) {
            float tot = atomicAdd(accum, 0.0f);
            out[0] = tot * (1.0f/(float)BN);
        }
    }
}

// ---------------------------------------------------------------------------
extern "C" void kernel_launch(void* const* d_in, const int* in_sizes, int n_in,
                              void* d_out, int out_size, void* d_ws, size_t ws_size,
                              hipStream_t stream)
{
    (void)in_sizes; (void)n_in; (void)out_size; (void)ws_size;
    const float*    gt   = (const float*)d_in[0];
    const float*    pred = (const float*)d_in[1];
    const unsigned* idxw = (const unsigned*)d_in[2];
    float* out = (float*)d_out;

    char* w = (char*)d_ws;
    float4* P4   = (float4*)w;                         w += (size_t)2*BN*16;   // 1 MB
    float4* S    = (float4*)w;                         w += (size_t)2*BN*16;   // 1 MB
    int*    hist = (int*)w;                            w += (size_t)8*NCELLS*4;   // 1 MB
    int2*   combo = (int2*)w;                          w += (size_t)8*NCELLS*8;   // 2 MB
    float4* Cov  = (float4*)w;                         w += (size_t)2*BN*32;   // 2 MB
    float*  accum = (float*)w;                         w += 16;
    unsigned* counter = (unsigned*)(accum + 1);
    int*    ovf_count = (int*)(accum + 2);
    int*    ovf  = (int*)w;                            w += (size_t)2*BN*4;    // 0.25 MB
    unsigned long long* ovf_key = (unsigned long long*)w;  w += (size_t)2*BN*8; // 0.5 MB

    hipMemsetAsync(hist, 0, (size_t)8*NCELLS*4, stream);
    hipLaunchKernelGGL(prep_kernel,    dim3(2*BN/256), dim3(256),  0, stream,
                       gt, pred, idxw, P4, hist, accum, counter, ovf_count);
    hipLaunchKernelGGL(scan_kernel,    dim3(8),        dim3(1024), 0, stream,
                       hist, combo);
    hipLaunchKernelGGL(scatter_kernel, dim3(2*BN/256), dim3(256),  0, stream,
                       P4, hist, combo, S);
    hipLaunchKernelGGL(knn_main_kernel, dim3(2*BN*4/256), dim3(256), 0, stream,
                       P4, S, combo, Cov, ovf, ovf_key, ovf_count);
    hipLaunchKernelGGL(brute_kernel,   dim3(BRUTE_BLOCKS), dim3(256), 0, stream,
                       P4, ovf, ovf_key, ovf_count, Cov);
    hipLaunchKernelGGL(eigh_loss_kernel, dim3(2*BN/256), dim3(256), 0, stream,
                       Cov, accum, counter, out);
}

// Round 4
// 300.684 us; speedup vs baseline: 1.0740x; 1.0133x over previous
//
#include <hip/hip_runtime.h>
#include <math.h>

#define BB   4
#define NN   8192
#define BN   (BB*NN)       // 32768 points per cloud-set; 8 clouds of 8192 total
#define KNN  10
#define G    32            // grid cells per dim
#define NCELLS (G*G*G)     // 32768 cells per cloud
#define GRID_LO (-5.0f)
#define H    0.3125f       // 10/32
#define INV_H 3.2f
#define RCAP 2             // rho<=2 region; beyond -> brute overflow

#define SEPS    5.9604645e-8f        // slamch('E') = 2^-24
#define SEPS2   (SEPS*SEPS)
#define SSAFMIN 1.1754944e-38f

__device__ __forceinline__ int cellc(float v) {
    int c = (int)floorf((v - GRID_LO) * INV_H);
    return min(G - 1, max(0, c));
}

// ---------------------------------------------------------------------------
// Kernel A: build P4[8][8192] = (x,y,z, bitcast orig-idx); clouds 0-3 = gt
// batches, 4-7 = pred[idx12] batches. Histogram cells + zero accumulators.
// ---------------------------------------------------------------------------
__global__ __launch_bounds__(256) void prep_kernel(
    const float* __restrict__ gt, const float* __restrict__ pred,
    const unsigned* __restrict__ idxw, float4* __restrict__ P4,
    int* __restrict__ hist, float* __restrict__ accum,
    unsigned* __restrict__ counter, int* __restrict__ ovf_count)
{
    __shared__ int s_is32;
    int tid = threadIdx.x;
    if (tid == 0) s_is32 = 0;
    __syncthreads();
    if (idxw[2*tid + 1] != 0u) s_is32 = 1;   // int64 => all high words 0
    __syncthreads();
    bool is64 = (s_is32 == 0);

    if (blockIdx.x == 0 && tid == 0) {
        *accum = 0.0f; *counter = 0u; *ovf_count = 0;
    }

    int point = blockIdx.x * 256 + tid;        // 0 .. 2*BN-1
    int pair = point >> 13;                    // 0..7
    int r    = point & (NN - 1);               // idx within cloud
    float x, y, z;
    if (point < BN) {
        const float* s = gt + (size_t)point*3;
        x = s[0]; y = s[1]; z = s[2];
    } else {
        int rr = point - BN;
        int b = rr >> 13;
        unsigned idx = is64 ? idxw[2*(size_t)rr] : idxw[rr];
        const float* s = pred + ((size_t)b*NN + idx)*3;
        x = s[0]; y = s[1]; z = s[2];
    }
    P4[point] = make_float4(x, y, z, __int_as_float(r));
    int cell = (cellc(z)*G + cellc(y))*G + cellc(x);
    atomicAdd(&hist[(size_t)pair*NCELLS + cell], 1);
}

// ---------------------------------------------------------------------------
// Kernel B: per-cloud exclusive scan -> combo[c] = int2(start, count).
// ---------------------------------------------------------------------------
__global__ __launch_bounds__(1024) void scan_kernel(
    const int* __restrict__ hist, int2* __restrict__ combo)
{
    int cloud = blockIdx.x;
    int tid = threadIdx.x;
    int lane = tid & 63, wid = tid >> 6;
    const int* h = hist + (size_t)cloud * NCELLS;
    int2* cb = combo + (size_t)cloud * NCELLS;

    int loc[32];
    int base = tid * 32;
    const int4* h4 = (const int4*)(h + base);
    int sum = 0;
    #pragma unroll
    for (int i = 0; i < 8; ++i) {
        int4 a = h4[i];
        loc[4*i+0] = a.x; loc[4*i+1] = a.y; loc[4*i+2] = a.z; loc[4*i+3] = a.w;
        sum += a.x + a.y + a.z + a.w;
    }
    // inclusive wave scan of sums
    int v = sum;
    #pragma unroll
    for (int off = 1; off < 64; off <<= 1) {
        int o = __shfl_up(v, off, 64);
        if (lane >= off) v += o;
    }
    __shared__ int ws[16], wsx[16];
    if (lane == 63) ws[wid] = v;
    __syncthreads();
    if (tid < 16) {
        int acc = 0;
        for (int i = 0; i < tid; ++i) acc += ws[i];
        wsx[tid] = acc;
    }
    __syncthreads();
    int run = (v - sum) + wsx[wid];            // exclusive prefix for this thread

    int4* cb4 = (int4*)(cb + base);            // 2 cells per int4 store
    #pragma unroll
    for (int i = 0; i < 16; ++i) {
        int4 o;
        o.x = run; o.y = loc[2*i];     run += loc[2*i];
        o.z = run; o.w = loc[2*i+1];   run += loc[2*i+1];
        cb4[i] = o;
    }
}

// ---------------------------------------------------------------------------
// Kernel C: scatter points into cell-sorted S.
// ---------------------------------------------------------------------------
__global__ __launch_bounds__(256) void scatter_kernel(
    const float4* __restrict__ P4, int* __restrict__ hist,
    const int2* __restrict__ combo, float4* __restrict__ S)
{
    int point = blockIdx.x * 256 + threadIdx.x;
    float4 p = P4[point];
    int pair = point >> 13;
    int cell = (cellc(p.z)*G + cellc(p.y))*G + cellc(p.x);
    int old = atomicSub(&hist[(size_t)pair*NCELLS + cell], 1);
    int pos = combo[(size_t)pair*NCELLS + cell].x + old - 1;
    S[(size_t)pair*NN + pos] = p;
}

// ---------------------------------------------------------------------------
// LAPACK ssyevd 3x3 path: ssytrd('L') + sorgtr + ssteqr('V'). Sign-faithful.
// (verified absmax 0.0 in rounds 2-18 — do not touch)
// ---------------------------------------------------------------------------
__device__ __forceinline__ float f_sign(float a, float b) {
    return copysignf(a, b);
}
__device__ __forceinline__ float slapy2(float x, float y) {
#pragma clang fp contract(off)
    float xa = fabsf(x), ya = fabsf(y);
    float w = fmaxf(xa, ya), z = fminf(xa, ya);
    if (z == 0.0f) return w;
    float t = z / w;
    return w * __fsqrt_rn(1.0f + t*t);
}
__device__ __forceinline__ void slartg_(float f, float g, float* cs, float* sn, float* r) {
#pragma clang fp contract(off)
    if (g == 0.0f)      { *cs = 1.0f; *sn = 0.0f; *r = f; }
    else if (f == 0.0f) { *cs = 0.0f; *sn = f_sign(1.0f, g); *r = fabsf(g); }
    else {
        float f1 = fabsf(f);
        float d = __fsqrt_rn(f*f + g*g);
        float p = 1.0f / d;
        *cs = f1 * p;
        *sn = g * f_sign(p, f);
        *r  = f_sign(d, f);
    }
}
__device__ void slaev2_(float a, float b, float c,
                        float* rt1, float* rt2, float* cs1, float* sn1) {
#pragma clang fp contract(off)
    float sm = a + c, df = a - c;
    float adf = fabsf(df);
    float tb = b + b;
    float ab = fabsf(tb);
    float acmx, acmn;
    if (fabsf(a) > fabsf(c)) { acmx = a; acmn = c; } else { acmx = c; acmn = a; }
    float rt;
    if (adf > ab)      { float t = ab/adf; rt = adf*__fsqrt_rn(1.0f + t*t); }
    else if (adf < ab) { float t = adf/ab; rt = ab*__fsqrt_rn(1.0f + t*t); }
    else               { rt = ab*__fsqrt_rn(2.0f); }
    int sgn1;
    if (sm < 0.0f)      { *rt1 = 0.5f*(sm - rt); sgn1 = -1;
                          *rt2 = (acmx / *rt1)*acmn - (b / *rt1)*b; }
    else if (sm > 0.0f) { *rt1 = 0.5f*(sm + rt); sgn1 = 1;
                          *rt2 = (acmx / *rt1)*acmn - (b / *rt1)*b; }
    else                { *rt1 = 0.5f*rt; *rt2 = -0.5f*rt; sgn1 = 1; }
    float cs; int sgn2;
    if (df >= 0.0f) { cs = df + rt; sgn2 = 1; } else { cs = df - rt; sgn2 = -1; }
    float acs = fabsf(cs);
    float c1, s1;
    if (acs > ab) { float ct = -tb/cs; s1 = 1.0f/__fsqrt_rn(1.0f + ct*ct); c1 = ct*s1; }
    else {
        if (ab == 0.0f) { c1 = 1.0f; s1 = 0.0f; }
        else { float tn = -cs/tb; c1 = 1.0f/__fsqrt_rn(1.0f + tn*tn); s1 = tn*c1; }
    }
    if (sgn1 == sgn2) { float tn = c1; c1 = -s1; s1 = tn; }
    *cs1 = c1; *sn1 = s1;
}

__device__ void eigh3_smallest(float c00, float c01, float c02,
                               float c11, float c12, float c22, float nv[3])
{
#pragma clang fp contract(off)
    // ---- ssytrd('L') ----
    float d[4], e[3], z[4][4];
    float tau1, v2 = 0.0f;
    float e1, d2, d3, e2;
    float alpha = c01, x = c02;
    if (x == 0.0f) {
        tau1 = 0.0f; e1 = alpha;
        d2 = c11; d3 = c22; e2 = c12;
    } else {
        float beta = -f_sign(slapy2(alpha, fabsf(x)), alpha);
        tau1 = (beta - alpha) / beta;
        v2 = x / (alpha - beta);
        e1 = beta;
        float w1 = tau1*(c11 + c12*v2);
        float w2 = tau1*(c12 + c22*v2);
        float al = -0.5f*tau1*(w1 + w2*v2);
        w1 = w1 + al;
        w2 = w2 + al*v2;
        d2 = (c11 - w1) - w1;
        e2 = (c12 - v2*w1) - w2;
        d3 = (c22 - v2*w2) - w2*v2;
    }
    d[1] = c00; d[2] = d2; d[3] = d3;
    e[1] = e1;  e[2] = e2;
    z[1][1] = 1.0f; z[1][2] = 0.0f; z[1][3] = 0.0f;
    z[2][1] = 0.0f; z[3][1] = 0.0f;
    z[2][2] = 1.0f - tau1;
    float mtv = -tau1*v2;
    z[2][3] = mtv; z[3][2] = mtv;
    z[3][3] = 1.0f + mtv*v2;

    // ---- ssteqr('V', 3) ----
    const int n = 3, nm1 = 2;
    int l1 = 1, jtot = 0;
    const int nmaxit = 90;
    float cw[3], sw[3];
    int guard = 0;
    while (guard++ < 64) {
        if (l1 > n) break;
        if (l1 > 1) e[l1-1] = 0.0f;
        int m = n;
        if (l1 <= nm1) {
            for (int mi = l1; mi <= nm1; ++mi) {
                float tst = fabsf(e[mi]);
                if (tst == 0.0f) { m = mi; break; }
                if (tst <= (__fsqrt_rn(fabsf(d[mi]))*__fsqrt_rn(fabsf(d[mi+1])))*SEPS) {
                    e[mi] = 0.0f; m = mi; break;
                }
            }
        }
        int l = l1;
        int lsv = l, lend = m, lendsv = lend;
        l1 = m + 1;
        if (lend == l) continue;
        if (fabsf(d[lend]) < fabsf(d[l])) { lend = lsv; l = lendsv; }

        if (lend > l) {
            // QL
            while (true) {
                int m_ = lend;
                if (l != lend) {
                    for (int mi = l; mi <= lend-1; ++mi) {
                        float em = e[mi];
                        float tst = em*em;
                        if (tst <= (SEPS2*fabsf(d[mi]))*fabsf(d[mi+1]) + SSAFMIN) { m_ = mi; break; }
                    }
                }
                if (m_ < lend) e[m_] = 0.0f;
                float p = d[l];
                if (m_ == l) {
                    d[l] = p; l = l + 1;
                    if (l <= lend) continue; else break;
                }
                if (m_ == l + 1) {
                    float rt1, rt2, cc, ss;
                    slaev2_(d[l], e[l], d[l+1], &rt1, &rt2, &cc, &ss);
                    for (int i = 1; i <= 3; ++i) {
                        float tmp = z[i][l+1];
                        z[i][l+1] = cc*tmp - ss*z[i][l];
                        z[i][l]   = ss*tmp + cc*z[i][l];
                    }
                    d[l] = rt1; d[l+1] = rt2; e[l] = 0.0f;
                    l = l + 2;
                    if (l <= lend) continue; else break;
                }
                if (jtot == nmaxit) break;
                jtot++;
                float g = (d[l+1] - p) / (2.0f*e[l]);
                float r = slapy2(g, 1.0f);
                g = d[m_] - p + (e[l] / (g + f_sign(r, g)));
                float s = 1.0f, c = 1.0f;
                p = 0.0f;
                for (int i = m_-1; i >= l; --i) {
                    float f = s*e[i];
                    float b = c*e[i];
                    slartg_(g, f, &c, &s, &r);
                    if (i != m_-1) e[i+1] = r;
                    g = d[i+1] - p;
                    r = (d[i] - g)*s + (2.0f*c)*b;
                    p = s*r;
                    d[i+1] = g + p;
                    g = c*r - b;
                    cw[i] = c; sw[i] = -s;
                }
                for (int j = m_-1; j >= l; --j) {
                    float cc = cw[j], ss = sw[j];
                    for (int i = 1; i <= 3; ++i) {
                        float tmp = z[i][j+1];
                        z[i][j+1] = cc*tmp - ss*z[i][j];
                        z[i][j]   = ss*tmp + cc*z[i][j];
                    }
                }
                d[l] = d[l] - p;
                e[l] = g;
            }
        } else {
            // QR
            while (true) {
                int m_ = lend;
                if (l != lend) {
                    for (int mi = l; mi >= lend+1; --mi) {
                        float em = e[mi-1];
                        float tst = em*em;
                        if (tst <= (SEPS2*fabsf(d[mi]))*fabsf(d[mi-1]) + SSAFMIN) { m_ = mi; break; }
                    }
                }
                if (m_ > lend) e[m_-1] = 0.0f;
                float p = d[l];
                if (m_ == l) {
                    d[l] = p; l = l - 1;
                    if (l >= lend) continue; else break;
                }
                if (m_ == l - 1) {
                    float rt1, rt2, cc, ss;
                    slaev2_(d[l-1], e[l-1], d[l], &rt1, &rt2, &cc, &ss);
                    for (int i = 1; i <= 3; ++i) {
                        float tmp = z[i][l];
                        z[i][l]   = cc*tmp - ss*z[i][l-1];
                        z[i][l-1] = ss*tmp + cc*z[i][l-1];
                    }
                    d[l-1] = rt1; d[l] = rt2; e[l-1] = 0.0f;
                    l = l - 2;
                    if (l >= lend) continue; else break;
                }
                if (jtot == nmaxit) break;
                jtot++;
                float g = (d[l-1] - p) / (2.0f*e[l-1]);
                float r = slapy2(g, 1.0f);
                g = d[m_] - p + (e[l-1] / (g + f_sign(r, g)));
                float s = 1.0f, c = 1.0f;
                p = 0.0f;
                for (int i = m_; i <= l-1; ++i) {
                    float f = s*e[i];
                    float b = c*e[i];
                    slartg_(g, f, &c, &s, &r);
                    if (i != m_) e[i-1] = r;
                    g = d[i] - p;
                    r = (d[i+1] - g)*s + (2.0f*c)*b;
                    p = s*r;
                    d[i] = g + p;
                    g = c*r - b;
                    cw[i] = c; sw[i] = s;
                }
                for (int j = m_; j <= l-1; ++j) {
                    float cc = cw[j], ss = sw[j];
                    for (int i = 1; i <= 3; ++i) {
                        float tmp = z[i][j+1];
                        z[i][j+1] = cc*tmp - ss*z[i][j];
                        z[i][j]   = ss*tmp + cc*z[i][j];
                    }
                }
                d[l] = d[l] - p;
                e[l-1] = g;
            }
        }
    }
    for (int ii = 2; ii <= 3; ++ii) {
        int i = ii - 1, k = i;
        float p = d[i];
        for (int j = ii; j <= 3; ++j) if (d[j] < p) { k = j; p = d[j]; }
        if (k != i) {
            d[k] = d[i]; d[i] = p;
            for (int r2 = 1; r2 <= 3; ++r2) {
                float t = z[r2][i]; z[r2][i] = z[r2][k]; z[r2][k] = t;
            }
        }
    }
    nv[0] = z[1][1]; nv[1] = z[2][1]; nv[2] = z[3][1];
}

// Covariance of the sorted 10-neighborhood (same op order as rounds 2-18).
__device__ void cov_compute(const float4* __restrict__ cl,
                            const unsigned long long keys[KNN], float c[6])
{
#pragma clang fp contract(off)
    float px[KNN], py[KNN], pz[KNN];
    float sx = 0.f, sy = 0.f, sz = 0.f;
    #pragma unroll
    for (int s = 0; s < KNN; ++s) {
        int ni = (int)(unsigned)(keys[s] & 0xFFFFFFFFull);
        float4 np = cl[ni];
        px[s] = np.x; py[s] = np.y; pz[s] = np.z;
        sx = sx + px[s]; sy = sy + py[s]; sz = sz + pz[s];
    }
    float mx = sx / 10.0f, my = sy / 10.0f, mz = sz / 10.0f;
    float c00=0.f,c01=0.f,c02=0.f,c11=0.f,c12=0.f,c22=0.f;
    #pragma unroll
    for (int s = 0; s < KNN; ++s) {
        float dx = px[s]-mx, dy = py[s]-my, dz = pz[s]-mz;
        c00 = c00 + dx*dx; c01 = c01 + dx*dy; c02 = c02 + dx*dz;
        c11 = c11 + dy*dy; c12 = c12 + dy*dz; c22 = c22 + dz*dz;
    }
    c[0] = c00/10.0f; c[1] = c01/10.0f; c[2] = c02/10.0f;
    c[3] = c11/10.0f; c[4] = c12/10.0f; c[5] = c22/10.0f;
}

// ---------------------------------------------------------------------------
// Insert: gate = min(own 10th, quad bound). Dropping candidates >= the quad
// bound is exact: some lane already holds 10 strictly-better keys. In phase 2
// qbK is set to ~0ull so the gate degenerates to the (exact) own 10th.
// ---------------------------------------------------------------------------
#define PROC(p) do { \
    float ddx = qx - (p).x, ddy = qy - (p).y, ddz = qz - (p).z; \
    float dd = fmaf(ddz, ddz, fmaf(ddy, ddy, ddx*ddx)); \
    unsigned long long key = \
        ((unsigned long long)__float_as_uint(dd) << 32) | \
        (unsigned)__float_as_int((p).w); \
    if (key < kgate) { \
        unsigned long long ck = key; \
        _Pragma("unroll") \
        for (int s = 0; s < KNN; ++s) { \
            unsigned long long ok2 = keys[s]; \
            bool sw = ok2 > ck; \
            keys[s] = sw ? ck : ok2; \
            ck      = sw ? ok2 : ck; \
        } \
        k9 = keys[KNN-1]; \
        kgate = (k9 < qbK) ? k9 : qbK; \
    } \
} while (0)

// stream a contiguous candidate segment [b, b+n) of S — 2 loads in flight
#define SEGPROC(b, n) do { \
    int _j = (b), _je = (b) + (n); \
    for (; _j + 2 <= _je; _j += 2) { \
        float4 _p0 = cs[_j]; float4 _p1 = cs[_j+1]; \
        PROC(_p0); PROC(_p1); \
    } \
    if (_j < _je) { float4 _p0 = cs[_j]; PROC(_p0); } \
} while (0)

// quad-min of the four lanes' current 10th keys; low word forced to all-ones
// so ties on the distance bits still pass the gate (tie-exact).
#define QEXCH() do { \
    unsigned long long _o1 = __shfl_xor(k9, 1, 4); \
    unsigned long long _m1 = (_o1 < k9) ? _o1 : k9; \
    unsigned long long _o2 = __shfl_xor(_m1, 2, 4); \
    unsigned long long _qm = (_o2 < _m1) ? _o2 : _m1; \
    qbK = _qm | 0xFFFFFFFFull; \
    kgate = (k9 < qbK) ? k9 : qbK; \
} while (0)

// 4-way compile-time coordinate select (3 cndmasks, once per slot)
#define SEL4(A,B,C,D) (sub == 0 ? (A) : (sub == 1 ? (B) : (sub == 2 ? (C) : (D))))

// ---------------------------------------------------------------------------
// Kernel D (R23): R21/R22 algorithm unchanged; ONE new line — a 5<->5 bit
// swap of blockIdx. WHY: each cloud = 8192 queries = exactly 32 blocks, and
// a CU receives blocks {c, c+256, c+512, c+768}; 256 == 0 (mod 32), so all
// four sat at the SAME z-order position (same density class) in 4 identical
// Gaussian clouds -> CUs with sparse-z slices got 4 all-hard (shell-walking)
// blocks and set the critical path (Occupancy 16.5% = drained CUs waiting on
// straggler CUs). bb = ((b&31)<<5)|(b>>5) places a CU's blocks at z-positions
// p, p+8, p+16, p+24 (mod 32) -> density-diverse, CU totals balanced. Waves
// remain contiguous-16-quad (uniform cost internally — mixing WITHIN a wave
// would make every wave pay the exec-masked max). Pure scheduling permutation
// -> bit-identical output.
// ---------------------------------------------------------------------------
__global__ __launch_bounds__(256) void knn_main_kernel(
    const float4* __restrict__ P4, const float4* __restrict__ S,
    const int2* __restrict__ combo, float4* __restrict__ Cov,
    int* __restrict__ ovf, unsigned long long* __restrict__ ovf_key,
    int* __restrict__ ovf_count)
{
    int b = blockIdx.x;                         // 0..1023
    int bb = ((b & 31) << 5) | (b >> 5);        // 5<->5 bit swap (bijective)
    int tidg = bb * 256 + threadIdx.x;          // 0..262143
    int qid  = tidg >> 2;                       // 0..65535
    int sub  = tidg & 3;
    int pair = qid >> 13;                       // 8 clouds
    int spos = qid & (NN - 1);                  // sorted position
    const float4* __restrict__ cl = P4 + (size_t)pair * NN;
    const float4* __restrict__ cs = S  + (size_t)pair * NN;
    const int2*   __restrict__ cb = combo + (size_t)pair * NCELLS;

    float4 q = cs[spos];
    float qx = q.x, qy = q.y, qz = q.z;
    int qi = __float_as_int(q.w);               // original index in cloud
    int qcx = cellc(qx), qcy = cellc(qy), qcz = cellc(qz);

    unsigned long long keys[KNN];
    #pragma unroll
    for (int s = 0; s < KNN; ++s) keys[s] = 0xFFFFFFFFFFFFFFFFull;
    unsigned long long k9    = 0xFFFFFFFFFFFFFFFFull;
    unsigned long long qbK   = 0xFFFFFFFFFFFFFFFFull;
    unsigned long long kgate = 0xFFFFFFFFFFFFFFFFull;

    // ---- phase 1: rho<=1 cube, 9 rows checkerboarded 3/2/2/2.
    // Each lane's CENTRAL row first, so lists fill with near candidates and
    // the inter-slot quad bound (QEXCH) tightens early.
    int x0 = max(qcx - 1, 0), x1 = min(qcx + 1, G - 1);
#define P1SLOT(i, ZA,YA, ZB,YB, ZC,YC, ZD,YD) \
    int rb##i = 0, re##i = 0; \
    { int zz = qcz + SEL4(ZA,ZB,ZC,ZD); \
      int yy = qcy + SEL4(YA,YB,YC,YD); \
      if ((unsigned)zz < G && (unsigned)yy < G) { \
          int cbase = (zz*G + yy)*G; \
          int2 a = cb[cbase + x0]; \
          int2 b2 = cb[cbase + x1]; \
          rb##i = a.x; re##i = b2.x + b2.y; } }
    P1SLOT(0,  0, 0,  0,1, -1,1, 0,-1)
    P1SLOT(1, -1,-1, -1,0,  1,-1, 1, 0)
    P1SLOT(2,  1, 1, 99,99, 99,99, 99,99)   // lanes 1-3 invalid -> bounds fail
#undef P1SLOT
    SEGPROC(rb0, re0 - rb0);
    QEXCH();
    SEGPROC(rb1, re1 - rb1);
    QEXCH();
    SEGPROC(rb2, re2 - rb2);

    // ---- merge the 4 phase-1 lists NOW -> exact top-10 over the cube,
    // identical in all 4 lanes (symmetric butterfly; no dups: disjoint cells).
    #pragma unroll
    for (int m = 1; m < 4; m <<= 1) {
        unsigned long long other[KNN];
        #pragma unroll
        for (int s = 0; s < KNN; ++s)
            other[s] = __shfl_xor(keys[s], m, 4);   // snapshot before inserts
        #pragma unroll
        for (int s = 0; s < KNN; ++s) {
            unsigned long long key = other[s];
            if (key < k9) {
                unsigned long long ck = key;
                #pragma unroll
                for (int t = 0; t < KNN; ++t) {
                    unsigned long long ok2 = keys[t];
                    bool sw = ok2 > ck;
                    keys[t] = sw ? ck : ok2;
                    ck      = sw ? ok2 : ck;
                }
                k9 = keys[KNN-1];
            }
        }
    }
    const unsigned long long k9M = k9;          // exact cube 10th (u64 key)
    float worstM = __uint_as_float((unsigned)(k9M >> 32)); // NaN if <10 found

    // ---- phase 2: rho=2 shell. Exterior of the cube is >= H from q, so
    // skip iff H^2 > worstM is EXACT (NaN-safe: NaN -> walk shell).
    bool skip = (H*H > worstM);                 // quad-uniform (worstM shared)

    // phase-2 inserts go directly into the merged list; gate = own 10th only
    qbK   = 0xFFFFFFFFFFFFFFFFull;
    kgate = k9;
    {
        int xs0 = max(qcx - 2, 0), xs1 = min(qcx + 2, G - 1);
        // 16 outer rows, checkerboarded 4/4/4/4; prune with exact bound worstM
#define S2SLOT(i, ZA,YA, ZB,YB, ZC,YC, ZD,YD) \
        int sb##i = 0, sn##i = 0; \
        if (!skip) { \
          int zz = qcz + SEL4(ZA,ZB,ZC,ZD); \
          int yy = qcy + SEL4(YA,YB,YC,YD); \
          if ((unsigned)zz < G && (unsigned)yy < G) { \
              float loy = fmaf((float)yy, H, GRID_LO); \
              float loz = fmaf((float)zz, H, GRID_LO); \
              float py = fmaxf(0.0f, fmaxf(loy - qy, qy - (loy + H))); \
              float pz = fmaxf(0.0f, fmaxf(loz - qz, qz - (loz + H))); \
              float pyz = fmaf(pz, pz, py*py); \
              if (!(pyz > worstM)) { \
                  int cbase = (zz*G + yy)*G; \
                  int2 a = cb[cbase + xs0]; \
                  int2 b2 = cb[cbase + xs1]; \
                  sb##i = a.x; sn##i = (b2.x + b2.y) - a.x; } } }
        S2SLOT(0, -2,-2, -2,-1, -2,0, -2,1)
        S2SLOT(1, -2, 2,  2,-2,  2,-1, 2,0)
        S2SLOT(2,  2, 1,  2, 2, -1,-2, -1,2)
        S2SLOT(3,  0,-2,  0, 2,  1,-2,  1,2)
#undef S2SLOT
        // 18 isolated cells (|dz|<=1,|dy|<=1, dx=+/-2), 5 slots x 4 lanes
#define CSLOT(i, ZA,YA,XA, ZB,YB,XB, ZC,YC,XC, ZD,YD,XD) \
        int tb##i = 0, tn##i = 0; \
        if (!skip) { \
          int zz = qcz + SEL4(ZA,ZB,ZC,ZD); \
          int yy = qcy + SEL4(YA,YB,YC,YD); \
          int xx = qcx + SEL4(XA,XB,XC,XD); \
          if ((unsigned)zz < G && (unsigned)yy < G && (unsigned)xx < G) { \
              float lox = fmaf((float)xx, H, GRID_LO); \
              float loy = fmaf((float)yy, H, GRID_LO); \
              float loz = fmaf((float)zz, H, GRID_LO); \
              float px = fmaxf(0.0f, fmaxf(lox - qx, qx - (lox + H))); \
              float py = fmaxf(0.0f, fmaxf(loy - qy, qy - (loy + H))); \
              float pz = fmaxf(0.0f, fmaxf(loz - qz, qz - (loz + H))); \
              float m2 = fmaf(pz, pz, fmaf(py, py, px*px)); \
              if (!(m2 > worstM)) { \
                  int2 a = cb[(zz*G + yy)*G + xx]; \
                  tb##i = a.x; tn##i = a.y; } } }
        CSLOT(0, -1,-1,-2, -1,-1,2, -1,0,-2, -1,0,2)
        CSLOT(1, -1, 1,-2, -1, 1,2,  0,-1,-2, 0,-1,2)
        CSLOT(2,  0, 0,-2,  0, 0,2,  0, 1,-2, 0, 1,2)
        CSLOT(3,  1,-1,-2,  1,-1,2,  1, 0,-2, 1, 0,2)
        CSLOT(4,  1, 1,-2,  1, 1,2, 99,99,0, 99,99,0)
#undef CSLOT
#define S2GO(i) SEGPROC(sb##i, sn##i);
        S2GO(0) S2GO(1) S2GO(2) S2GO(3)
#undef S2GO
#define CGO(i) SEGPROC(tb##i, tn##i);
        CGO(0) CGO(1) CGO(2) CGO(3) CGO(4)
#undef CGO
    }

    // ---- final: dedupe-merge the 4 lists (cube survivors are shared), but
    // only if some lane actually inserted a shell candidate. Every successful
    // insert strictly lowers k9, so "changed" == (k9 != k9M). skip and ch are
    // quad-uniform -> the shfls inside are safe.
    if (!skip) {
        int ch = (k9 != k9M) ? 1 : 0;
        ch |= __shfl_xor(ch, 1, 4);
        ch |= __shfl_xor(ch, 2, 4);
        if (ch) {
            #pragma unroll
            for (int m = 1; m < 4; m <<= 1) {
                unsigned long long other[KNN];
                #pragma unroll
                for (int s = 0; s < KNN; ++s)
                    other[s] = __shfl_xor(keys[s], m, 4);  // snapshot
                #pragma unroll
                for (int s = 0; s < KNN; ++s) {
                    unsigned long long key = other[s];
                    if (key >= k9) break;       // other sorted ascending
                    bool dup = false;
                    #pragma unroll
                    for (int t = 0; t < KNN; ++t) dup = dup || (keys[t] == key);
                    if (!dup) {
                        unsigned long long ck = key;
                        #pragma unroll
                        for (int t = 0; t < KNN; ++t) {
                            unsigned long long ok2 = keys[t];
                            bool sw = ok2 > ck;
                            keys[t] = sw ? ck : ok2;
                            ck      = sw ? ok2 : ck;
                        }
                        k9 = keys[KNN-1];
                    }
                }
            }
        }
    }
    float worst_m = __uint_as_float((unsigned)(k9 >> 32));

    // resolved iff cells beyond the rho<=2 region (gap >= 2H) cannot contribute
    float bf = (float)RCAP * H;
    bool resolved = (bf*bf > worst_m);          // strict; NaN (unfilled) -> false
    if (resolved && sub == 0) {
        float c[6];
        cov_compute(cl, keys, c);               // sub==0 only: 1/4 gather loads
        size_t o = ((size_t)pair*NN + qi)*2;
        Cov[o]   = make_float4(c[0], c[1], c[2], c[3]);
        Cov[o+1] = make_float4(c[4], c[5], 0.0f, 0.0f);
    } else if (!resolved && sub == 0) {
        int pos = atomicAdd(ovf_count, 1);
        ovf[pos] = (pair << 13) | qi;
        ovf_key[pos] = k9;      // merged 10th-best: valid upper bound on true
    }                           // 10th key (subset 10th >= full-set 10th)
}

// ---------------------------------------------------------------------------
// Kernel D2 (R22): brute-force overflow, ONE WAVE per query (4 per block),
// no LDS, no __syncthreads. Per-lane bound-gated scan of a disjoint 1/64
// slice (coalesced cl[i*64+lane]), then a 10-round EXTRACTION merge: per
// round, wave-wide u64-min butterfly finds the global min (keys unique by
// index low-word -> unique owner), every lane records it, the owning lane
// shifts its sorted list down one (static indexing). Extraction of the 10
// smallest of the union, ascending, == exact top-10 in the same sorted order
// => bit-identical cov => absmax 0.0.
// ---------------------------------------------------------------------------
#define BRUTE_BLOCKS 2048
__global__ __launch_bounds__(256) void brute_kernel(
    const float4* __restrict__ P4, const int* __restrict__ ovf,
    const unsigned long long* __restrict__ ovf_key,
    const int* __restrict__ ovf_count, float4* __restrict__ Cov)
{
    int tid = threadIdx.x;
    int lane = tid & 63;
    int wid = tid >> 6;
    int count = *ovf_count;

    for (int oi = blockIdx.x * 4 + wid; oi < count; oi += BRUTE_BLOCKS * 4) {
        int rec = ovf[oi];
        unsigned long long bound = ovf_key[oi];
        float bound_d = __uint_as_float((unsigned)(bound >> 32)); // NaN if unfilled
        int pair = rec >> 13;
        int qi = rec & (NN - 1);
        const float4* __restrict__ cl = P4 + (size_t)pair * NN;
        float4 q = cl[qi];
        float qx = q.x, qy = q.y, qz = q.z;

        unsigned long long keys[KNN];
        #pragma unroll
        for (int s = 0; s < KNN; ++s) keys[s] = 0xFFFFFFFFFFFFFFFFull;
        unsigned long long k9 = keys[KNN-1];

        // per-lane scan with bound gate; ties at dd==bound_d pass (exact).
        // The true 10 NN all satisfy dd <= true 10th <= bound_d, so >=10
        // real keys survive across the wave (NaN bound -> all pass).
#define BPROC(p, jj) do { \
        float ddx = qx - (p).x, ddy = qy - (p).y, ddz = qz - (p).z; \
        float dd = fmaf(ddz, ddz, fmaf(ddy, ddy, ddx*ddx)); \
        if (!(dd > bound_d)) { \
            unsigned long long key = \
                ((unsigned long long)__float_as_uint(dd) << 32) | (unsigned)(jj); \
            if (key < k9) { \
                unsigned long long ck = key; \
                _Pragma("unroll") \
                for (int s = 0; s < KNN; ++s) { \
                    unsigned long long ok2 = keys[s]; \
                    bool sw = ok2 > ck; \
                    keys[s] = sw ? ck : ok2; \
                    ck      = sw ? ok2 : ck; \
                } \
                k9 = keys[KNN-1]; \
            } \
        } \
    } while (0)
        #pragma unroll 1
        for (int i = 0; i < NN/64; i += 4) {    // 32 iters, 4 loads in flight
            float4 p0 = cl[(i+0)*64 + lane];
            float4 p1 = cl[(i+1)*64 + lane];
            float4 p2 = cl[(i+2)*64 + lane];
            float4 p3 = cl[(i+3)*64 + lane];
            BPROC(p0, (i+0)*64 + lane);
            BPROC(p1, (i+1)*64 + lane);
            BPROC(p2, (i+2)*64 + lane);
            BPROC(p3, (i+3)*64 + lane);
        }
#undef BPROC

        // 10-round extraction merge: exact top-10 of the union, ascending.
        unsigned long long fin[KNN];
        #pragma unroll
        for (int r = 0; r < KNN; ++r) {
            unsigned long long m = keys[0];
            #pragma unroll
            for (int off = 1; off < 64; off <<= 1) {
                unsigned long long o = __shfl_xor(m, off);
                m = (o < m) ? o : m;
            }
            fin[r] = m;
            if (keys[0] == m) {                 // unique owner (keys unique)
                #pragma unroll
                for (int t = 0; t < KNN-1; ++t) keys[t] = keys[t+1];
                keys[KNN-1] = 0xFFFFFFFFFFFFFFFFull;
            }
        }

        if (lane == 0) {
            float c[6];
            cov_compute(cl, fin, c);
            size_t o = ((size_t)pair*NN + qi)*2;
            Cov[o]   = make_float4(c[0], c[1], c[2], c[3]);
            Cov[o+1] = make_float4(c[4], c[5], 0.0f, 0.0f);
        }
    }
}

// ---------------------------------------------------------------------------
// Kernel E (R19): fused eigh + loss, ONE eigh per thread over 2*BN threads.
// Thread 2k handles gt[k], thread 2k+1 handles pred[k]; normals exchanged
// in-wave via shfl_xor(1); even lanes compute 1-cos; block reduce; atomic.
// Identical eigh inputs -> bit-identical normals (summation grouping only).
// ---------------------------------------------------------------------------
__global__ __launch_bounds__(256) void eigh_loss_kernel(
    const float4* __restrict__ Cov, float* __restrict__ accum,
    unsigned* __restrict__ counter, float* __restrict__ out)
{
    int tid = threadIdx.x;
    int t = blockIdx.x * 256 + tid;            // 0..2*BN-1
    int k = t >> 1;                            // pair index 0..BN-1
    int cld = t & 1;                           // 0 = gt, 1 = pred
    size_t ci = ((size_t)(cld ? BN + k : k)) * 2;
    float4 a0 = Cov[ci], a1 = Cov[ci + 1];
    float n[3];
    eigh3_smallest(a0.x, a0.y, a0.z, a0.w, a1.x, a1.y, n);

    // exchange with partner lane (2k <-> 2k+1 always share a wave)
    float ox = __shfl_xor(n[0], 1);
    float oy = __shfl_xor(n[1], 1);
    float oz = __shfl_xor(n[2], 1);

    float v = 0.0f;
    if (cld == 0) {
        float gx=n[0], gy=n[1], gz=n[2];
        float hx=ox,  hy=oy,  hz=oz;
        float dot = fmaf(gx,hx,fmaf(gy,hy,gz*hz));
        float ng  = sqrtf(fmaf(gx,gx,fmaf(gy,gy,gz*gz)));
        float nh  = sqrtf(fmaf(hx,hx,fmaf(hy,hy,hz*hz)));
        float den = fmaxf(ng*nh, 1e-8f);
        v = 1.0f - dot/den;
    }

    __shared__ float red[256];
    red[tid] = v;                              // odd lanes contribute 0
    __syncthreads();
    for (int s = 128; s > 0; s >>= 1) {
        if (tid < s) red[tid] += red[tid+s];
        __syncthreads();
    }
    if (tid == 0) {
        atomicAdd(accum, red[0]);
        __threadfence();
        unsigned old = atomicAdd(counter, 1u);
        if (old == (unsigned)(2*BN/256 - 1)) {
            float tot = atomicAdd(accum, 0.0f);
            out[0] = tot * (1.0f/(float)BN);
        }
    }
}

// ---------------------------------------------------------------------------
extern "C" void kernel_launch(void* const* d_in, const int* in_sizes, int n_in,
                              void* d_out, int out_size, void* d_ws, size_t ws_size,
                              hipStream_t stream)
{
    (void)in_sizes; (void)n_in; (void)out_size; (void)ws_size;
    const float*    gt   = (const float*)d_in[0];
    const float*    pred = (const float*)d_in[1];
    const unsigned* idxw = (const unsigned*)d_in[2];
    float* out = (float*)d_out;

    char* w = (char*)d_ws;
    float4* P4   = (float4*)w;                         w += (size_t)2*BN*16;   // 1 MB
    float4* S    = (float4*)w;                         w += (size_t)2*BN*16;   // 1 MB
    int*    hist = (int*)w;                            w += (size_t)8*NCELLS*4;   // 1 MB
    int2*   combo = (int2*)w;                          w += (size_t)8*NCELLS*8;   // 2 MB
    float4* Cov  = (float4*)w;                         w += (size_t)2*BN*32;   // 2 MB
    float*  accum = (float*)w;                         w += 16;
    unsigned* counter = (unsigned*)(accum + 1);
    int*    ovf_count = (int*)(accum + 2);
    int*    ovf  = (int*)w;                            w += (size_t)2*BN*4;    // 0.25 MB
    unsigned long long* ovf_key = (unsigned long long*)w;  w += (size_t)2*BN*8; // 0.5 MB

    hipMemsetAsync(hist, 0, (size_t)8*NCELLS*4, stream);
    hipLaunchKernelGGL(prep_kernel,    dim3(2*BN/256), dim3(256),  0, stream,
                       gt, pred, idxw, P4, hist, accum, counter, ovf_count);
    hipLaunchKernelGGL(scan_kernel,    dim3(8),        dim3(1024), 0, stream,
                       hist, combo);
    hipLaunchKernelGGL(scatter_kernel, dim3(2*BN/256), dim3(256),  0, stream,
                       P4, hist, combo, S);
    hipLaunchKernelGGL(knn_main_kernel, dim3(2*BN*4/256), dim3(256), 0, stream,
                       P4, S, combo, Cov, ovf, ovf_key, ovf_count);
    hipLaunchKernelGGL(brute_kernel,   dim3(BRUTE_BLOCKS), dim3(256), 0, stream,
                       P4, ovf, ovf_key, ovf_count, Cov);
    hipLaunchKernelGGL(eigh_loss_kernel, dim3(2*BN/256), dim3(256), 0, stream,
                       Cov, accum, counter, out);
}

// Round 5
// 267.888 us; speedup vs baseline: 1.2055x; 1.1224x over previous
//
#include <hip/hip_runtime.h>
#include <math.h>

#define BB   4
#define NN   8192
#define BN   (BB*NN)       // 32768 points per cloud-set; 8 clouds of 8192 total
#define KNN  10
#define G    32            // grid cells per dim
#define NCELLS (G*G*G)     // 32768 cells per cloud
#define GRID_LO (-5.0f)
#define H    0.3125f       // 10/32
#define INV_H 3.2f
#define RCAP 2             // rho<=2 region; beyond -> brute overflow

#define SEPS    5.9604645e-8f        // slamch('E') = 2^-24
#define SEPS2   (SEPS*SEPS)
#define SSAFMIN 1.1754944e-38f

__device__ __forceinline__ int cellc(float v) {
    int c = (int)floorf((v - GRID_LO) * INV_H);
    return min(G - 1, max(0, c));
}

// ---------------------------------------------------------------------------
// Kernel A: build P4[8][8192] = (x,y,z, bitcast orig-idx); clouds 0-3 = gt
// batches, 4-7 = pred[idx12] batches. Histogram cells + zero accumulators.
// ---------------------------------------------------------------------------
__global__ __launch_bounds__(256) void prep_kernel(
    const float* __restrict__ gt, const float* __restrict__ pred,
    const unsigned* __restrict__ idxw, float4* __restrict__ P4,
    int* __restrict__ hist, float* __restrict__ accum,
    unsigned* __restrict__ counter, int* __restrict__ ovf_count)
{
    __shared__ int s_is32;
    int tid = threadIdx.x;
    if (tid == 0) s_is32 = 0;
    __syncthreads();
    if (idxw[2*tid + 1] != 0u) s_is32 = 1;   // int64 => all high words 0
    __syncthreads();
    bool is64 = (s_is32 == 0);

    if (blockIdx.x == 0 && tid == 0) {
        *accum = 0.0f; *counter = 0u; *ovf_count = 0;
    }

    int point = blockIdx.x * 256 + tid;        // 0 .. 2*BN-1
    int pair = point >> 13;                    // 0..7
    int r    = point & (NN - 1);               // idx within cloud
    float x, y, z;
    if (point < BN) {
        const float* s = gt + (size_t)point*3;
        x = s[0]; y = s[1]; z = s[2];
    } else {
        int rr = point - BN;
        int b = rr >> 13;
        unsigned idx = is64 ? idxw[2*(size_t)rr] : idxw[rr];
        const float* s = pred + ((size_t)b*NN + idx)*3;
        x = s[0]; y = s[1]; z = s[2];
    }
    P4[point] = make_float4(x, y, z, __int_as_float(r));
    int cell = (cellc(z)*G + cellc(y))*G + cellc(x);
    atomicAdd(&hist[(size_t)pair*NCELLS + cell], 1);
}

// ---------------------------------------------------------------------------
// Kernel B: per-cloud exclusive scan -> combo[c] = int2(start, count).
// ---------------------------------------------------------------------------
__global__ __launch_bounds__(1024) void scan_kernel(
    const int* __restrict__ hist, int2* __restrict__ combo)
{
    int cloud = blockIdx.x;
    int tid = threadIdx.x;
    int lane = tid & 63, wid = tid >> 6;
    const int* h = hist + (size_t)cloud * NCELLS;
    int2* cb = combo + (size_t)cloud * NCELLS;

    int loc[32];
    int base = tid * 32;
    const int4* h4 = (const int4*)(h + base);
    int sum = 0;
    #pragma unroll
    for (int i = 0; i < 8; ++i) {
        int4 a = h4[i];
        loc[4*i+0] = a.x; loc[4*i+1] = a.y; loc[4*i+2] = a.z; loc[4*i+3] = a.w;
        sum += a.x + a.y + a.z + a.w;
    }
    // inclusive wave scan of sums
    int v = sum;
    #pragma unroll
    for (int off = 1; off < 64; off <<= 1) {
        int o = __shfl_up(v, off, 64);
        if (lane >= off) v += o;
    }
    __shared__ int ws[16], wsx[16];
    if (lane == 63) ws[wid] = v;
    __syncthreads();
    if (tid < 16) {
        int acc = 0;
        for (int i = 0; i < tid; ++i) acc += ws[i];
        wsx[tid] = acc;
    }
    __syncthreads();
    int run = (v - sum) + wsx[wid];            // exclusive prefix for this thread

    int4* cb4 = (int4*)(cb + base);            // 2 cells per int4 store
    #pragma unroll
    for (int i = 0; i < 16; ++i) {
        int4 o;
        o.x = run; o.y = loc[2*i];     run += loc[2*i];
        o.z = run; o.w = loc[2*i+1];   run += loc[2*i+1];
        cb4[i] = o;
    }
}

// ---------------------------------------------------------------------------
// Kernel C: scatter points into cell-sorted S.
// ---------------------------------------------------------------------------
__global__ __launch_bounds__(256) void scatter_kernel(
    const float4* __restrict__ P4, int* __restrict__ hist,
    const int2* __restrict__ combo, float4* __restrict__ S)
{
    int point = blockIdx.x * 256 + threadIdx.x;
    float4 p = P4[point];
    int pair = point >> 13;
    int cell = (cellc(p.z)*G + cellc(p.y))*G + cellc(p.x);
    int old = atomicSub(&hist[(size_t)pair*NCELLS + cell], 1);
    int pos = combo[(size_t)pair*NCELLS + cell].x + old - 1;
    S[(size_t)pair*NN + pos] = p;
}

// ---------------------------------------------------------------------------
// LAPACK ssyevd 3x3 path: ssytrd('L') + sorgtr + ssteqr('V'). Sign-faithful.
// (verified absmax 0.0 in rounds 2-18 — do not touch)
// ---------------------------------------------------------------------------
__device__ __forceinline__ float f_sign(float a, float b) {
    return copysignf(a, b);
}
__device__ __forceinline__ float slapy2(float x, float y) {
#pragma clang fp contract(off)
    float xa = fabsf(x), ya = fabsf(y);
    float w = fmaxf(xa, ya), z = fminf(xa, ya);
    if (z == 0.0f) return w;
    float t = z / w;
    return w * __fsqrt_rn(1.0f + t*t);
}
__device__ __forceinline__ void slartg_(float f, float g, float* cs, float* sn, float* r) {
#pragma clang fp contract(off)
    if (g == 0.0f)      { *cs = 1.0f; *sn = 0.0f; *r = f; }
    else if (f == 0.0f) { *cs = 0.0f; *sn = f_sign(1.0f, g); *r = fabsf(g); }
    else {
        float f1 = fabsf(f);
        float d = __fsqrt_rn(f*f + g*g);
        float p = 1.0f / d;
        *cs = f1 * p;
        *sn = g * f_sign(p, f);
        *r  = f_sign(d, f);
    }
}
__device__ void slaev2_(float a, float b, float c,
                        float* rt1, float* rt2, float* cs1, float* sn1) {
#pragma clang fp contract(off)
    float sm = a + c, df = a - c;
    float adf = fabsf(df);
    float tb = b + b;
    float ab = fabsf(tb);
    float acmx, acmn;
    if (fabsf(a) > fabsf(c)) { acmx = a; acmn = c; } else { acmx = c; acmn = a; }
    float rt;
    if (adf > ab)      { float t = ab/adf; rt = adf*__fsqrt_rn(1.0f + t*t); }
    else if (adf < ab) { float t = adf/ab; rt = ab*__fsqrt_rn(1.0f + t*t); }
    else               { rt = ab*__fsqrt_rn(2.0f); }
    int sgn1;
    if (sm < 0.0f)      { *rt1 = 0.5f*(sm - rt); sgn1 = -1;
                          *rt2 = (acmx / *rt1)*acmn - (b / *rt1)*b; }
    else if (sm > 0.0f) { *rt1 = 0.5f*(sm + rt); sgn1 = 1;
                          *rt2 = (acmx / *rt1)*acmn - (b / *rt1)*b; }
    else                { *rt1 = 0.5f*rt; *rt2 = -0.5f*rt; sgn1 = 1; }
    float cs; int sgn2;
    if (df >= 0.0f) { cs = df + rt; sgn2 = 1; } else { cs = df - rt; sgn2 = -1; }
    float acs = fabsf(cs);
    float c1, s1;
    if (acs > ab) { float ct = -tb/cs; s1 = 1.0f/__fsqrt_rn(1.0f + ct*ct); c1 = ct*s1; }
    else {
        if (ab == 0.0f) { c1 = 1.0f; s1 = 0.0f; }
        else { float tn = -cs/tb; c1 = 1.0f/__fsqrt_rn(1.0f + tn*tn); s1 = tn*c1; }
    }
    if (sgn1 == sgn2) { float tn = c1; c1 = -s1; s1 = tn; }
    *cs1 = c1; *sn1 = s1;
}

__device__ void eigh3_smallest(float c00, float c01, float c02,
                               float c11, float c12, float c22, float nv[3])
{
#pragma clang fp contract(off)
    // ---- ssytrd('L') ----
    float d[4], e[3], z[4][4];
    float tau1, v2 = 0.0f;
    float e1, d2, d3, e2;
    float alpha = c01, x = c02;
    if (x == 0.0f) {
        tau1 = 0.0f; e1 = alpha;
        d2 = c11; d3 = c22; e2 = c12;
    } else {
        float beta = -f_sign(slapy2(alpha, fabsf(x)), alpha);
        tau1 = (beta - alpha) / beta;
        v2 = x / (alpha - beta);
        e1 = beta;
        float w1 = tau1*(c11 + c12*v2);
        float w2 = tau1*(c12 + c22*v2);
        float al = -0.5f*tau1*(w1 + w2*v2);
        w1 = w1 + al;
        w2 = w2 + al*v2;
        d2 = (c11 - w1) - w1;
        e2 = (c12 - v2*w1) - w2;
        d3 = (c22 - v2*w2) - w2*v2;
    }
    d[1] = c00; d[2] = d2; d[3] = d3;
    e[1] = e1;  e[2] = e2;
    z[1][1] = 1.0f; z[1][2] = 0.0f; z[1][3] = 0.0f;
    z[2][1] = 0.0f; z[3][1] = 0.0f;
    z[2][2] = 1.0f - tau1;
    float mtv = -tau1*v2;
    z[2][3] = mtv; z[3][2] = mtv;
    z[3][3] = 1.0f + mtv*v2;

    // ---- ssteqr('V', 3) ----
    const int n = 3, nm1 = 2;
    int l1 = 1, jtot = 0;
    const int nmaxit = 90;
    float cw[3], sw[3];
    int guard = 0;
    while (guard++ < 64) {
        if (l1 > n) break;
        if (l1 > 1) e[l1-1] = 0.0f;
        int m = n;
        if (l1 <= nm1) {
            for (int mi = l1; mi <= nm1; ++mi) {
                float tst = fabsf(e[mi]);
                if (tst == 0.0f) { m = mi; break; }
                if (tst <= (__fsqrt_rn(fabsf(d[mi]))*__fsqrt_rn(fabsf(d[mi+1])))*SEPS) {
                    e[mi] = 0.0f; m = mi; break;
                }
            }
        }
        int l = l1;
        int lsv = l, lend = m, lendsv = lend;
        l1 = m + 1;
        if (lend == l) continue;
        if (fabsf(d[lend]) < fabsf(d[l])) { lend = lsv; l = lendsv; }

        if (lend > l) {
            // QL
            while (true) {
                int m_ = lend;
                if (l != lend) {
                    for (int mi = l; mi <= lend-1; ++mi) {
                        float em = e[mi];
                        float tst = em*em;
                        if (tst <= (SEPS2*fabsf(d[mi]))*fabsf(d[mi+1]) + SSAFMIN) { m_ = mi; break; }
                    }
                }
                if (m_ < lend) e[m_] = 0.0f;
                float p = d[l];
                if (m_ == l) {
                    d[l] = p; l = l + 1;
                    if (l <= lend) continue; else break;
                }
                if (m_ == l + 1) {
                    float rt1, rt2, cc, ss;
                    slaev2_(d[l], e[l], d[l+1], &rt1, &rt2, &cc, &ss);
                    for (int i = 1; i <= 3; ++i) {
                        float tmp = z[i][l+1];
                        z[i][l+1] = cc*tmp - ss*z[i][l];
                        z[i][l]   = ss*tmp + cc*z[i][l];
                    }
                    d[l] = rt1; d[l+1] = rt2; e[l] = 0.0f;
                    l = l + 2;
                    if (l <= lend) continue; else break;
                }
                if (jtot == nmaxit) break;
                jtot++;
                float g = (d[l+1] - p) / (2.0f*e[l]);
                float r = slapy2(g, 1.0f);
                g = d[m_] - p + (e[l] / (g + f_sign(r, g)));
                float s = 1.0f, c = 1.0f;
                p = 0.0f;
                for (int i = m_-1; i >= l; --i) {
                    float f = s*e[i];
                    float b = c*e[i];
                    slartg_(g, f, &c, &s, &r);
                    if (i != m_-1) e[i+1] = r;
                    g = d[i+1] - p;
                    r = (d[i] - g)*s + (2.0f*c)*b;
                    p = s*r;
                    d[i+1] = g + p;
                    g = c*r - b;
                    cw[i] = c; sw[i] = -s;
                }
                for (int j = m_-1; j >= l; --j) {
                    float cc = cw[j], ss = sw[j];
                    for (int i = 1; i <= 3; ++i) {
                        float tmp = z[i][j+1];
                        z[i][j+1] = cc*tmp - ss*z[i][j];
                        z[i][j]   = ss*tmp + cc*z[i][j];
                    }
                }
                d[l] = d[l] - p;
                e[l] = g;
            }
        } else {
            // QR
            while (true) {
                int m_ = lend;
                if (l != lend) {
                    for (int mi = l; mi >= lend+1; --mi) {
                        float em = e[mi-1];
                        float tst = em*em;
                        if (tst <= (SEPS2*fabsf(d[mi]))*fabsf(d[mi-1]) + SSAFMIN) { m_ = mi; break; }
                    }
                }
                if (m_ > lend) e[m_-1] = 0.0f;
                float p = d[l];
                if (m_ == l) {
                    d[l] = p; l = l - 1;
                    if (l >= lend) continue; else break;
                }
                if (m_ == l - 1) {
                    float rt1, rt2, cc, ss;
                    slaev2_(d[l-1], e[l-1], d[l], &rt1, &rt2, &cc, &ss);
                    for (int i = 1; i <= 3; ++i) {
                        float tmp = z[i][l];
                        z[i][l]   = cc*tmp - ss*z[i][l-1];
                        z[i][l-1] = ss*tmp + cc*z[i][l-1];
                    }
                    d[l-1] = rt1; d[l] = rt2; e[l-1] = 0.0f;
                    l = l - 2;
                    if (l >= lend) continue; else break;
                }
                if (jtot == nmaxit) break;
                jtot++;
                float g = (d[l-1] - p) / (2.0f*e[l-1]);
                float r = slapy2(g, 1.0f);
                g = d[m_] - p + (e[l-1] / (g + f_sign(r, g)));
                float s = 1.0f, c = 1.0f;
                p = 0.0f;
                for (int i = m_; i <= l-1; ++i) {
                    float f = s*e[i];
                    float b = c*e[i];
                    slartg_(g, f, &c, &s, &r);
                    if (i != m_) e[i-1] = r;
                    g = d[i] - p;
                    r = (d[i+1] - g)*s + (2.0f*c)*b;
                    p = s*r;
                    d[i] = g + p;
                    g = c*r - b;
                    cw[i] = c; sw[i] = s;
                }
                for (int j = m_; j <= l-1; ++j) {
                    float cc = cw[j], ss = sw[j];
                    for (int i = 1; i <= 3; ++i) {
                        float tmp = z[i][j+1];
                        z[i][j+1] = cc*tmp - ss*z[i][j];
                        z[i][j]   = ss*tmp + cc*z[i][j];
                    }
                }
                d[l] = d[l] - p;
                e[l-1] = g;
            }
        }
    }
    for (int ii = 2; ii <= 3; ++ii) {
        int i = ii - 1, k = i;
        float p = d[i];
        for (int j = ii; j <= 3; ++j) if (d[j] < p) { k = j; p = d[j]; }
        if (k != i) {
            d[k] = d[i]; d[i] = p;
            for (int r2 = 1; r2 <= 3; ++r2) {
                float t = z[r2][i]; z[r2][i] = z[r2][k]; z[r2][k] = t;
            }
        }
    }
    nv[0] = z[1][1]; nv[1] = z[2][1]; nv[2] = z[3][1];
}

// Covariance of the sorted 10-neighborhood (same op order as rounds 2-18).
__device__ void cov_compute(const float4* __restrict__ cl,
                            const unsigned long long keys[KNN], float c[6])
{
#pragma clang fp contract(off)
    float px[KNN], py[KNN], pz[KNN];
    float sx = 0.f, sy = 0.f, sz = 0.f;
    #pragma unroll
    for (int s = 0; s < KNN; ++s) {
        int ni = (int)(unsigned)(keys[s] & 0xFFFFFFFFull);
        float4 np = cl[ni];
        px[s] = np.x; py[s] = np.y; pz[s] = np.z;
        sx = sx + px[s]; sy = sy + py[s]; sz = sz + pz[s];
    }
    float mx = sx / 10.0f, my = sy / 10.0f, mz = sz / 10.0f;
    float c00=0.f,c01=0.f,c02=0.f,c11=0.f,c12=0.f,c22=0.f;
    #pragma unroll
    for (int s = 0; s < KNN; ++s) {
        float dx = px[s]-mx, dy = py[s]-my, dz = pz[s]-mz;
        c00 = c00 + dx*dx; c01 = c01 + dx*dy; c02 = c02 + dx*dz;
        c11 = c11 + dy*dy; c12 = c12 + dy*dz; c22 = c22 + dz*dz;
    }
    c[0] = c00/10.0f; c[1] = c01/10.0f; c[2] = c02/10.0f;
    c[3] = c11/10.0f; c[4] = c12/10.0f; c[5] = c22/10.0f;
}

// ---------------------------------------------------------------------------
// Insert: gate = min(own 10th, quad bound). Dropping candidates >= the quad
// bound is exact: some lane already holds 10 strictly-better keys. In phase 2
// qbK is ~0ull so the gate degenerates to the (exact) own 10th.
// ---------------------------------------------------------------------------
#define PROC(p) do { \
    float ddx = qx - (p).x, ddy = qy - (p).y, ddz = qz - (p).z; \
    float dd = fmaf(ddz, ddz, fmaf(ddy, ddy, ddx*ddx)); \
    unsigned long long key = \
        ((unsigned long long)__float_as_uint(dd) << 32) | \
        (unsigned)__float_as_int((p).w); \
    if (key < kgate) { \
        unsigned long long ck = key; \
        _Pragma("unroll") \
        for (int s = 0; s < KNN; ++s) { \
            unsigned long long ok2 = keys[s]; \
            bool sw = ok2 > ck; \
            keys[s] = sw ? ck : ok2; \
            ck      = sw ? ok2 : ck; \
        } \
        k9 = keys[KNN-1]; \
        kgate = (k9 < qbK) ? k9 : qbK; \
    } \
} while (0)

// R24 cooperative stride-4 segment walk: the QUAD jointly covers [bgn,end);
// lane sub takes elements bgn+sub, +4, +8, ... Perfect quad balance (steps =
// ceil(len/4), no per-lane row raggedness) and the quad's 4 loads are one
// contiguous 64B chunk (4x fewer cache lines per step than per-lane rows).
// Disjointness across lanes preserved -> per-lane exact reservoirs.
#define SEGPROC(bgn, end) do { \
    int _j = (bgn) + sub, _je = (end); \
    for (; _j + 4 < _je; _j += 8) { \
        float4 _p0 = cs[_j]; float4 _p1 = cs[_j+4]; \
        PROC(_p0); PROC(_p1); \
    } \
    if (_j < _je) { float4 _p0 = cs[_j]; PROC(_p0); } \
} while (0)

// quad-min of the four lanes' current 10th keys; low word forced to all-ones
// so ties on the distance bits still pass the gate (tie-exact).
#define QEXCH() do { \
    unsigned long long _o1 = __shfl_xor(k9, 1, 4); \
    unsigned long long _m1 = (_o1 < k9) ? _o1 : k9; \
    unsigned long long _o2 = __shfl_xor(_m1, 2, 4); \
    unsigned long long _qm = (_o2 < _m1) ? _o2 : _m1; \
    qbK = _qm | 0xFFFFFFFFull; \
    kgate = (k9 < qbK) ? k9 : qbK; \
} while (0)

// R24 quad EXTRACTION merge (R22's brute trick ported): 10 rounds; per round
// a 2-stage u64-min butterfly finds the global min of the 4 sorted lists,
// every lane records it, and every lane whose head equals it shifts down
// (shared keys collapse -> natural dedupe; disjoint phase-1 keys have unique
// owners). Produces the exact top-10 of the union, ascending, IDENTICAL in
// all 4 lanes. ~380 instr vs ~1600-2600 for the exec-masked butterfly-insert
// merge it replaces (whose 75-instr chain fired on nearly every stage x slot).
#define QMERGE() do { \
    unsigned long long fin[KNN]; \
    _Pragma("unroll") \
    for (int r = 0; r < KNN; ++r) { \
        unsigned long long m = keys[0]; \
        unsigned long long _o1 = __shfl_xor(m, 1, 4); m = (_o1 < m) ? _o1 : m; \
        unsigned long long _o2 = __shfl_xor(m, 2, 4); m = (_o2 < m) ? _o2 : m; \
        fin[r] = m; \
        bool own = (keys[0] == m); \
        _Pragma("unroll") \
        for (int t = 0; t < KNN-1; ++t) keys[t] = own ? keys[t+1] : keys[t]; \
        keys[KNN-1] = own ? 0xFFFFFFFFFFFFFFFFull : keys[KNN-1]; \
    } \
    _Pragma("unroll") \
    for (int s = 0; s < KNN; ++s) keys[s] = fin[s]; \
    k9 = keys[KNN-1]; \
} while (0)

// ---------------------------------------------------------------------------
// Kernel D (R24): grid 10-NN, FOUR lanes per query. Phase 1 walks the 9-row
// rho<=1 cube center-out, quad-cooperative stride-4 (balance + coalescing).
// Quad extraction-merge -> every lane holds the EXACT cube top-10 -> exact
// phase-2 skip (H^2 > worstM) + tight worstM pruning. Phase 2 walks surviving
// shell rows/cells the same cooperative way (box tests quad-redundant but
// quad-uniform -> coverage safe; prune bound MUST be the quad-uniform worstM
// since coverage is cooperative). Final extraction-merge dedupes shared cube
// survivors naturally. Union of lane lists provably contains the true top-10
// (a lane evicts a key only when holding 10 strictly-better real keys), and
// extraction emits the same ascending order as before => bit-identical cov.
// R23 block swizzle kept.
// ---------------------------------------------------------------------------
__global__ __launch_bounds__(256) void knn_main_kernel(
    const float4* __restrict__ P4, const float4* __restrict__ S,
    const int2* __restrict__ combo, float4* __restrict__ Cov,
    int* __restrict__ ovf, unsigned long long* __restrict__ ovf_key,
    int* __restrict__ ovf_count)
{
    int b = blockIdx.x;                         // 0..1023
    int bb = ((b & 31) << 5) | (b >> 5);        // 5<->5 bit swap (bijective)
    int tidg = bb * 256 + threadIdx.x;          // 0..262143
    int qid  = tidg >> 2;                       // 0..65535
    int sub  = tidg & 3;
    int pair = qid >> 13;                       // 8 clouds
    int spos = qid & (NN - 1);                  // sorted position
    const float4* __restrict__ cl = P4 + (size_t)pair * NN;
    const float4* __restrict__ cs = S  + (size_t)pair * NN;
    const int2*   __restrict__ cb = combo + (size_t)pair * NCELLS;

    float4 q = cs[spos];
    float qx = q.x, qy = q.y, qz = q.z;
    int qi = __float_as_int(q.w);               // original index in cloud
    int qcx = cellc(qx), qcy = cellc(qy), qcz = cellc(qz);

    unsigned long long keys[KNN];
    #pragma unroll
    for (int s = 0; s < KNN; ++s) keys[s] = 0xFFFFFFFFFFFFFFFFull;
    unsigned long long k9    = 0xFFFFFFFFFFFFFFFFull;
    unsigned long long qbK   = 0xFFFFFFFFFFFFFFFFull;
    unsigned long long kgate = 0xFFFFFFFFFFFFFFFFull;

    // ---- phase 1: rho<=1 cube = 9 (z,y) rows, center-out order so gates
    // tighten early; QEXCH between rows shares the quad bound.
    int x0 = max(qcx - 1, 0), x1 = min(qcx + 1, G - 1);
    {
        const int DZ9[9] = { 0,  0,  0, -1,  1, -1, -1,  1,  1};
        const int DY9[9] = { 0,  1, -1,  0,  0, -1,  1, -1,  1};
        int rb[9], re[9];
        #pragma unroll
        for (int r = 0; r < 9; ++r) {
            int zz = qcz + DZ9[r], yy = qcy + DY9[r];
            rb[r] = 0; re[r] = 0;
            if ((unsigned)zz < G && (unsigned)yy < G) {
                int cbase = (zz*G + yy)*G;
                int2 a  = cb[cbase + x0];
                int2 b2 = cb[cbase + x1];
                rb[r] = a.x; re[r] = b2.x + b2.y;
            }
        }
        #pragma unroll
        for (int r = 0; r < 9; ++r) {
            SEGPROC(rb[r], re[r]);
            if (r == 0 || r == 2 || r == 4 || r == 6) QEXCH();
        }
    }

    // ---- quad extraction-merge -> exact cube top-10, identical in all lanes
    QMERGE();
    const unsigned long long k9M = k9;          // exact cube 10th (u64 key)
    float worstM = __uint_as_float((unsigned)(k9M >> 32)); // NaN if <10 found

    // ---- phase 2: rho=2 shell. Exterior of the cube is >= H from q, so
    // skip iff H^2 > worstM is EXACT (NaN-safe: NaN -> walk shell).
    bool skip = (H*H > worstM);                 // quad-uniform (worstM shared)

    qbK   = 0xFFFFFFFFFFFFFFFFull;              // phase-2 gate = own 10th
    kgate = k9;
    if (!skip) {
        int xs0 = max(qcx - 2, 0), xs1 = min(qcx + 2, G - 1);
        // 16 outer rows; box test redundant in all 4 lanes (same q -> same
        // result, quad-uniform branch), then cooperative stride-4 walk.
        const int SZ16[16] = {-2,-2,-2,-2,-2,  2, 2, 2, 2, 2, -1,-1, 0, 0, 1, 1};
        const int SY16[16] = {-2,-1, 0, 1, 2, -2,-1, 0, 1, 2, -2, 2,-2, 2,-2, 2};
        #pragma unroll
        for (int r = 0; r < 16; ++r) {
            int zz = qcz + SZ16[r], yy = qcy + SY16[r];
            if ((unsigned)zz < G && (unsigned)yy < G) {
                float loy = fmaf((float)yy, H, GRID_LO);
                float loz = fmaf((float)zz, H, GRID_LO);
                float py = fmaxf(0.0f, fmaxf(loy - qy, qy - (loy + H)));
                float pz = fmaxf(0.0f, fmaxf(loz - qz, qz - (loz + H)));
                float pyz = fmaf(pz, pz, py*py);
                if (!(pyz > worstM)) {
                    int cbase = (zz*G + yy)*G;
                    int2 a  = cb[cbase + xs0];
                    int2 b2 = cb[cbase + xs1];
                    SEGPROC(a.x, b2.x + b2.y);
                }
            }
        }
        // 18 isolated cells (|dz|<=1,|dy|<=1, dx=+/-2)
        const int CZ18[18] = {-1,-1,-1,-1,-1,-1,  0, 0, 0, 0, 0, 0,  1, 1, 1, 1, 1, 1};
        const int CY18[18] = {-1,-1, 0, 0, 1, 1, -1,-1, 0, 0, 1, 1, -1,-1, 0, 0, 1, 1};
        const int CX18[18] = {-2, 2,-2, 2,-2, 2, -2, 2,-2, 2,-2, 2, -2, 2,-2, 2,-2, 2};
        #pragma unroll
        for (int r = 0; r < 18; ++r) {
            int zz = qcz + CZ18[r], yy = qcy + CY18[r], xx = qcx + CX18[r];
            if ((unsigned)zz < G && (unsigned)yy < G && (unsigned)xx < G) {
                float lox = fmaf((float)xx, H, GRID_LO);
                float loy = fmaf((float)yy, H, GRID_LO);
                float loz = fmaf((float)zz, H, GRID_LO);
                float px = fmaxf(0.0f, fmaxf(lox - qx, qx - (lox + H)));
                float py = fmaxf(0.0f, fmaxf(loy - qy, qy - (loy + H)));
                float pz = fmaxf(0.0f, fmaxf(loz - qz, qz - (loz + H)));
                float m2 = fmaf(pz, pz, fmaf(py, py, px*px));
                if (!(m2 > worstM)) {
                    int2 a = cb[(zz*G + yy)*G + xx];
                    SEGPROC(a.x, a.x + a.y);
                }
            }
        }
    }

    // ---- final: extraction-merge again, but only if some lane inserted a
    // shell candidate (every successful insert strictly lowers k9). Shared
    // cube survivors are held by all 4 lanes -> all owners shift in the same
    // round -> natural exact dedupe. skip and ch are quad-uniform.
    if (!skip) {
        int ch = (k9 != k9M) ? 1 : 0;
        ch |= __shfl_xor(ch, 1, 4);
        ch |= __shfl_xor(ch, 2, 4);
        if (ch) QMERGE();
    }
    float worst_m = __uint_as_float((unsigned)(k9 >> 32));

    // resolved iff cells beyond the rho<=2 region (gap >= 2H) cannot contribute
    float bf = (float)RCAP * H;
    bool resolved = (bf*bf > worst_m);          // strict; NaN (unfilled) -> false
    if (resolved && sub == 0) {
        float c[6];
        cov_compute(cl, keys, c);               // sub==0 only: 1/4 gather loads
        size_t o = ((size_t)pair*NN + qi)*2;
        Cov[o]   = make_float4(c[0], c[1], c[2], c[3]);
        Cov[o+1] = make_float4(c[4], c[5], 0.0f, 0.0f);
    } else if (!resolved && sub == 0) {
        int pos = atomicAdd(ovf_count, 1);
        ovf[pos] = (pair << 13) | qi;
        ovf_key[pos] = k9;      // exact 10th over examined set: valid upper
    }                           // bound on the true 10th key
}

// ---------------------------------------------------------------------------
// Kernel D2 (R22): brute-force overflow, ONE WAVE per query (4 per block),
// no LDS, no __syncthreads. Per-lane bound-gated scan of a disjoint 1/64
// slice (coalesced cl[i*64+lane]), then a 10-round EXTRACTION merge.
// ---------------------------------------------------------------------------
#define BRUTE_BLOCKS 2048
__global__ __launch_bounds__(256) void brute_kernel(
    const float4* __restrict__ P4, const int* __restrict__ ovf,
    const unsigned long long* __restrict__ ovf_key,
    const int* __restrict__ ovf_count, float4* __restrict__ Cov)
{
    int tid = threadIdx.x;
    int lane = tid & 63;
    int wid = tid >> 6;
    int count = *ovf_count;

    for (int oi = blockIdx.x * 4 + wid; oi < count; oi += BRUTE_BLOCKS * 4) {
        int rec = ovf[oi];
        unsigned long long bound = ovf_key[oi];
        float bound_d = __uint_as_float((unsigned)(bound >> 32)); // NaN if unfilled
        int pair = rec >> 13;
        int qi = rec & (NN - 1);
        const float4* __restrict__ cl = P4 + (size_t)pair * NN;
        float4 q = cl[qi];
        float qx = q.x, qy = q.y, qz = q.z;

        unsigned long long keys[KNN];
        #pragma unroll
        for (int s = 0; s < KNN; ++s) keys[s] = 0xFFFFFFFFFFFFFFFFull;
        unsigned long long k9 = keys[KNN-1];

        // per-lane scan with bound gate; ties at dd==bound_d pass (exact).
#define BPROC(p, jj) do { \
        float ddx = qx - (p).x, ddy = qy - (p).y, ddz = qz - (p).z; \
        float dd = fmaf(ddz, ddz, fmaf(ddy, ddy, ddx*ddx)); \
        if (!(dd > bound_d)) { \
            unsigned long long key = \
                ((unsigned long long)__float_as_uint(dd) << 32) | (unsigned)(jj); \
            if (key < k9) { \
                unsigned long long ck = key; \
                _Pragma("unroll") \
                for (int s = 0; s < KNN; ++s) { \
                    unsigned long long ok2 = keys[s]; \
                    bool sw = ok2 > ck; \
                    keys[s] = sw ? ck : ok2; \
                    ck      = sw ? ok2 : ck; \
                } \
                k9 = keys[KNN-1]; \
            } \
        } \
    } while (0)
        #pragma unroll 1
        for (int i = 0; i < NN/64; i += 4) {    // 32 iters, 4 loads in flight
            float4 p0 = cl[(i+0)*64 + lane];
            float4 p1 = cl[(i+1)*64 + lane];
            float4 p2 = cl[(i+2)*64 + lane];
            float4 p3 = cl[(i+3)*64 + lane];
            BPROC(p0, (i+0)*64 + lane);
            BPROC(p1, (i+1)*64 + lane);
            BPROC(p2, (i+2)*64 + lane);
            BPROC(p3, (i+3)*64 + lane);
        }
#undef BPROC

        // 10-round extraction merge: exact top-10 of the union, ascending.
        unsigned long long fin[KNN];
        #pragma unroll
        for (int r = 0; r < KNN; ++r) {
            unsigned long long m = keys[0];
            #pragma unroll
            for (int off = 1; off < 64; off <<= 1) {
                unsigned long long o = __shfl_xor(m, off);
                m = (o < m) ? o : m;
            }
            fin[r] = m;
            if (keys[0] == m) {                 // unique owner (keys unique)
                #pragma unroll
                for (int t = 0; t < KNN-1; ++t) keys[t] = keys[t+1];
                keys[KNN-1] = 0xFFFFFFFFFFFFFFFFull;
            }
        }

        if (lane == 0) {
            float c[6];
            cov_compute(cl, fin, c);
            size_t o = ((size_t)pair*NN + qi)*2;
            Cov[o]   = make_float4(c[0], c[1], c[2], c[3]);
            Cov[o+1] = make_float4(c[4], c[5], 0.0f, 0.0f);
        }
    }
}

// ---------------------------------------------------------------------------
// Kernel E (R19): fused eigh + loss, ONE eigh per thread over 2*BN threads.
// Thread 2k handles gt[k], thread 2k+1 handles pred[k]; normals exchanged
// in-wave via shfl_xor(1); even lanes compute 1-cos; block reduce; atomic.
// Identical eigh inputs -> bit-identical normals (summation grouping only).
// ---------------------------------------------------------------------------
__global__ __launch_bounds__(256) void eigh_loss_kernel(
    const float4* __restrict__ Cov, float* __restrict__ accum,
    unsigned* __restrict__ counter, float* __restrict__ out)
{
    int tid = threadIdx.x;
    int t = blockIdx.x * 256 + tid;            // 0..2*BN-1
    int k = t >> 1;                            // pair index 0..BN-1
    int cld = t & 1;                           // 0 = gt, 1 = pred
    size_t ci = ((size_t)(cld ? BN + k : k)) * 2;
    float4 a0 = Cov[ci], a1 = Cov[ci + 1];
    float n[3];
    eigh3_smallest(a0.x, a0.y, a0.z, a0.w, a1.x, a1.y, n);

    // exchange with partner lane (2k <-> 2k+1 always share a wave)
    float ox = __shfl_xor(n[0], 1);
    float oy = __shfl_xor(n[1], 1);
    float oz = __shfl_xor(n[2], 1);

    float v = 0.0f;
    if (cld == 0) {
        float gx=n[0], gy=n[1], gz=n[2];
        float hx=ox,  hy=oy,  hz=oz;
        float dot = fmaf(gx,hx,fmaf(gy,hy,gz*hz));
        float ng  = sqrtf(fmaf(gx,gx,fmaf(gy,gy,gz*gz)));
        float nh  = sqrtf(fmaf(hx,hx,fmaf(hy,hy,hz*hz)));
        float den = fmaxf(ng*nh, 1e-8f);
        v = 1.0f - dot/den;
    }

    __shared__ float red[256];
    red[tid] = v;                              // odd lanes contribute 0
    __syncthreads();
    for (int s = 128; s > 0; s >>= 1) {
        if (tid < s) red[tid] += red[tid+s];
        __syncthreads();
    }
    if (tid == 0) {
        atomicAdd(accum, red[0]);
        __threadfence();
        unsigned old = atomicAdd(counter, 1u);
        if (old == (unsigned)(2*BN/256 - 1)) {
            float tot = atomicAdd(accum, 0.0f);
            out[0] = tot * (1.0f/(float)BN);
        }
    }
}

// ---------------------------------------------------------------------------
extern "C" void kernel_launch(void* const* d_in, const int* in_sizes, int n_in,
                              void* d_out, int out_size, void* d_ws, size_t ws_size,
                              hipStream_t stream)
{
    (void)in_sizes; (void)n_in; (void)out_size; (void)ws_size;
    const float*    gt   = (const float*)d_in[0];
    const float*    pred = (const float*)d_in[1];
    const unsigned* idxw = (const unsigned*)d_in[2];
    float* out = (float*)d_out;

    char* w = (char*)d_ws;
    float4* P4   = (float4*)w;                         w += (size_t)2*BN*16;   // 1 MB
    float4* S    = (float4*)w;                         w += (size_t)2*BN*16;   // 1 MB
    int*    hist = (int*)w;                            w += (size_t)8*NCELLS*4;   // 1 MB
    int2*   combo = (int2*)w;                          w += (size_t)8*NCELLS*8;   // 2 MB
    float4* Cov  = (float4*)w;                         w += (size_t)2*BN*32;   // 2 MB
    float*  accum = (float*)w;                         w += 16;
    unsigned* counter = (unsigned*)(accum + 1);
    int*    ovf_count = (int*)(accum + 2);
    int*    ovf  = (int*)w;                            w += (size_t)2*BN*4;    // 0.25 MB
    unsigned long long* ovf_key = (unsigned long long*)w;  w += (size_t)2*BN*8; // 0.5 MB

    hipMemsetAsync(hist, 0, (size_t)8*NCELLS*4, stream);
    hipLaunchKernelGGL(prep_kernel,    dim3(2*BN/256), dim3(256),  0, stream,
                       gt, pred, idxw, P4, hist, accum, counter, ovf_count);
    hipLaunchKernelGGL(scan_kernel,    dim3(8),        dim3(1024), 0, stream,
                       hist, combo);
    hipLaunchKernelGGL(scatter_kernel, dim3(2*BN/256), dim3(256),  0, stream,
                       P4, hist, combo, S);
    hipLaunchKernelGGL(knn_main_kernel, dim3(2*BN*4/256), dim3(256), 0, stream,
                       P4, S, combo, Cov, ovf, ovf_key, ovf_count);
    hipLaunchKernelGGL(brute_kernel,   dim3(BRUTE_BLOCKS), dim3(256), 0, stream,
                       P4, ovf, ovf_key, ovf_count, Cov);
    hipLaunchKernelGGL(eigh_loss_kernel, dim3(2*BN/256), dim3(256), 0, stream,
                       Cov, accum, counter, out);
}

// Round 6
// 233.260 us; speedup vs baseline: 1.3844x; 1.1485x over previous
//
#include <hip/hip_runtime.h>
#include <math.h>

#define BB   4
#define NN   8192
#define BN   (BB*NN)       // 32768 points per cloud-set; 8 clouds of 8192 total
#define KNN  10
#define G    32            // grid cells per dim
#define NCELLS (G*G*G)     // 32768 cells per cloud
#define GRID_LO (-5.0f)
#define H    0.3125f       // 10/32
#define INV_H 3.2f
#define RCAP 2             // rho<=2 region; beyond -> brute overflow

#define SEPS    5.9604645e-8f        // slamch('E') = 2^-24
#define SEPS2   (SEPS*SEPS)
#define SSAFMIN 1.1754944e-38f

__device__ __forceinline__ int cellc(float v) {
    int c = (int)floorf((v - GRID_LO) * INV_H);
    return min(G - 1, max(0, c));
}

// ---------------------------------------------------------------------------
// Kernel A: build P4[8][8192] = (x,y,z, bitcast orig-idx); clouds 0-3 = gt
// batches, 4-7 = pred[idx12] batches. Histogram cells + zero accumulators.
// ---------------------------------------------------------------------------
__global__ __launch_bounds__(256) void prep_kernel(
    const float* __restrict__ gt, const float* __restrict__ pred,
    const unsigned* __restrict__ idxw, float4* __restrict__ P4,
    int* __restrict__ hist, float* __restrict__ accum,
    unsigned* __restrict__ counter, int* __restrict__ ovf_count)
{
    __shared__ int s_is32;
    int tid = threadIdx.x;
    if (tid == 0) s_is32 = 0;
    __syncthreads();
    if (idxw[2*tid + 1] != 0u) s_is32 = 1;   // int64 => all high words 0
    __syncthreads();
    bool is64 = (s_is32 == 0);

    if (blockIdx.x == 0 && tid == 0) {
        *accum = 0.0f; *counter = 0u; *ovf_count = 0;
    }

    int point = blockIdx.x * 256 + tid;        // 0 .. 2*BN-1
    int pair = point >> 13;                    // 0..7
    int r    = point & (NN - 1);               // idx within cloud
    float x, y, z;
    if (point < BN) {
        const float* s = gt + (size_t)point*3;
        x = s[0]; y = s[1]; z = s[2];
    } else {
        int rr = point - BN;
        int b = rr >> 13;
        unsigned idx = is64 ? idxw[2*(size_t)rr] : idxw[rr];
        const float* s = pred + ((size_t)b*NN + idx)*3;
        x = s[0]; y = s[1]; z = s[2];
    }
    P4[point] = make_float4(x, y, z, __int_as_float(r));
    int cell = (cellc(z)*G + cellc(y))*G + cellc(x);
    atomicAdd(&hist[(size_t)pair*NCELLS + cell], 1);
}

// ---------------------------------------------------------------------------
// Kernel B: per-cloud exclusive scan -> combo[c] = int2(start, count).
// ---------------------------------------------------------------------------
__global__ __launch_bounds__(1024) void scan_kernel(
    const int* __restrict__ hist, int2* __restrict__ combo)
{
    int cloud = blockIdx.x;
    int tid = threadIdx.x;
    int lane = tid & 63, wid = tid >> 6;
    const int* h = hist + (size_t)cloud * NCELLS;
    int2* cb = combo + (size_t)cloud * NCELLS;

    int loc[32];
    int base = tid * 32;
    const int4* h4 = (const int4*)(h + base);
    int sum = 0;
    #pragma unroll
    for (int i = 0; i < 8; ++i) {
        int4 a = h4[i];
        loc[4*i+0] = a.x; loc[4*i+1] = a.y; loc[4*i+2] = a.z; loc[4*i+3] = a.w;
        sum += a.x + a.y + a.z + a.w;
    }
    // inclusive wave scan of sums
    int v = sum;
    #pragma unroll
    for (int off = 1; off < 64; off <<= 1) {
        int o = __shfl_up(v, off, 64);
        if (lane >= off) v += o;
    }
    __shared__ int ws[16], wsx[16];
    if (lane == 63) ws[wid] = v;
    __syncthreads();
    if (tid < 16) {
        int acc = 0;
        for (int i = 0; i < tid; ++i) acc += ws[i];
        wsx[tid] = acc;
    }
    __syncthreads();
    int run = (v - sum) + wsx[wid];            // exclusive prefix for this thread

    int4* cb4 = (int4*)(cb + base);            // 2 cells per int4 store
    #pragma unroll
    for (int i = 0; i < 16; ++i) {
        int4 o;
        o.x = run; o.y = loc[2*i];     run += loc[2*i];
        o.z = run; o.w = loc[2*i+1];   run += loc[2*i+1];
        cb4[i] = o;
    }
}

// ---------------------------------------------------------------------------
// Kernel C: scatter points into cell-sorted S.
// ---------------------------------------------------------------------------
__global__ __launch_bounds__(256) void scatter_kernel(
    const float4* __restrict__ P4, int* __restrict__ hist,
    const int2* __restrict__ combo, float4* __restrict__ S)
{
    int point = blockIdx.x * 256 + threadIdx.x;
    float4 p = P4[point];
    int pair = point >> 13;
    int cell = (cellc(p.z)*G + cellc(p.y))*G + cellc(p.x);
    int old = atomicSub(&hist[(size_t)pair*NCELLS + cell], 1);
    int pos = combo[(size_t)pair*NCELLS + cell].x + old - 1;
    S[(size_t)pair*NN + pos] = p;
}

// ---------------------------------------------------------------------------
// LAPACK ssyevd 3x3 path: ssytrd('L') + sorgtr + ssteqr('V'). Sign-faithful.
// (verified absmax 0.0 in rounds 2-18 — do not touch)
// ---------------------------------------------------------------------------
__device__ __forceinline__ float f_sign(float a, float b) {
    return copysignf(a, b);
}
__device__ __forceinline__ float slapy2(float x, float y) {
#pragma clang fp contract(off)
    float xa = fabsf(x), ya = fabsf(y);
    float w = fmaxf(xa, ya), z = fminf(xa, ya);
    if (z == 0.0f) return w;
    float t = z / w;
    return w * __fsqrt_rn(1.0f + t*t);
}
__device__ __forceinline__ void slartg_(float f, float g, float* cs, float* sn, float* r) {
#pragma clang fp contract(off)
    if (g == 0.0f)      { *cs = 1.0f; *sn = 0.0f; *r = f; }
    else if (f == 0.0f) { *cs = 0.0f; *sn = f_sign(1.0f, g); *r = fabsf(g); }
    else {
        float f1 = fabsf(f);
        float d = __fsqrt_rn(f*f + g*g);
        float p = 1.0f / d;
        *cs = f1 * p;
        *sn = g * f_sign(p, f);
        *r  = f_sign(d, f);
    }
}
__device__ void slaev2_(float a, float b, float c,
                        float* rt1, float* rt2, float* cs1, float* sn1) {
#pragma clang fp contract(off)
    float sm = a + c, df = a - c;
    float adf = fabsf(df);
    float tb = b + b;
    float ab = fabsf(tb);
    float acmx, acmn;
    if (fabsf(a) > fabsf(c)) { acmx = a; acmn = c; } else { acmx = c; acmn = a; }
    float rt;
    if (adf > ab)      { float t = ab/adf; rt = adf*__fsqrt_rn(1.0f + t*t); }
    else if (adf < ab) { float t = adf/ab; rt = ab*__fsqrt_rn(1.0f + t*t); }
    else               { rt = ab*__fsqrt_rn(2.0f); }
    int sgn1;
    if (sm < 0.0f)      { *rt1 = 0.5f*(sm - rt); sgn1 = -1;
                          *rt2 = (acmx / *rt1)*acmn - (b / *rt1)*b; }
    else if (sm > 0.0f) { *rt1 = 0.5f*(sm + rt); sgn1 = 1;
                          *rt2 = (acmx / *rt1)*acmn - (b / *rt1)*b; }
    else                { *rt1 = 0.5f*rt; *rt2 = -0.5f*rt; sgn1 = 1; }
    float cs; int sgn2;
    if (df >= 0.0f) { cs = df + rt; sgn2 = 1; } else { cs = df - rt; sgn2 = -1; }
    float acs = fabsf(cs);
    float c1, s1;
    if (acs > ab) { float ct = -tb/cs; s1 = 1.0f/__fsqrt_rn(1.0f + ct*ct); c1 = ct*s1; }
    else {
        if (ab == 0.0f) { c1 = 1.0f; s1 = 0.0f; }
        else { float tn = -cs/tb; c1 = 1.0f/__fsqrt_rn(1.0f + tn*tn); s1 = tn*c1; }
    }
    if (sgn1 == sgn2) { float tn = c1; c1 = -s1; s1 = tn; }
    *cs1 = c1; *sn1 = s1;
}

__device__ void eigh3_smallest(float c00, float c01, float c02,
                               float c11, float c12, float c22, float nv[3])
{
#pragma clang fp contract(off)
    // ---- ssytrd('L') ----
    float d[4], e[3], z[4][4];
    float tau1, v2 = 0.0f;
    float e1, d2, d3, e2;
    float alpha = c01, x = c02;
    if (x == 0.0f) {
        tau1 = 0.0f; e1 = alpha;
        d2 = c11; d3 = c22; e2 = c12;
    } else {
        float beta = -f_sign(slapy2(alpha, fabsf(x)), alpha);
        tau1 = (beta - alpha) / beta;
        v2 = x / (alpha - beta);
        e1 = beta;
        float w1 = tau1*(c11 + c12*v2);
        float w2 = tau1*(c12 + c22*v2);
        float al = -0.5f*tau1*(w1 + w2*v2);
        w1 = w1 + al;
        w2 = w2 + al*v2;
        d2 = (c11 - w1) - w1;
        e2 = (c12 - v2*w1) - w2;
        d3 = (c22 - v2*w2) - w2*v2;
    }
    d[1] = c00; d[2] = d2; d[3] = d3;
    e[1] = e1;  e[2] = e2;
    z[1][1] = 1.0f; z[1][2] = 0.0f; z[1][3] = 0.0f;
    z[2][1] = 0.0f; z[3][1] = 0.0f;
    z[2][2] = 1.0f - tau1;
    float mtv = -tau1*v2;
    z[2][3] = mtv; z[3][2] = mtv;
    z[3][3] = 1.0f + mtv*v2;

    // ---- ssteqr('V', 3) ----
    const int n = 3, nm1 = 2;
    int l1 = 1, jtot = 0;
    const int nmaxit = 90;
    float cw[3], sw[3];
    int guard = 0;
    while (guard++ < 64) {
        if (l1 > n) break;
        if (l1 > 1) e[l1-1] = 0.0f;
        int m = n;
        if (l1 <= nm1) {
            for (int mi = l1; mi <= nm1; ++mi) {
                float tst = fabsf(e[mi]);
                if (tst == 0.0f) { m = mi; break; }
                if (tst <= (__fsqrt_rn(fabsf(d[mi]))*__fsqrt_rn(fabsf(d[mi+1])))*SEPS) {
                    e[mi] = 0.0f; m = mi; break;
                }
            }
        }
        int l = l1;
        int lsv = l, lend = m, lendsv = lend;
        l1 = m + 1;
        if (lend == l) continue;
        if (fabsf(d[lend]) < fabsf(d[l])) { lend = lsv; l = lendsv; }

        if (lend > l) {
            // QL
            while (true) {
                int m_ = lend;
                if (l != lend) {
                    for (int mi = l; mi <= lend-1; ++mi) {
                        float em = e[mi];
                        float tst = em*em;
                        if (tst <= (SEPS2*fabsf(d[mi]))*fabsf(d[mi+1]) + SSAFMIN) { m_ = mi; break; }
                    }
                }
                if (m_ < lend) e[m_] = 0.0f;
                float p = d[l];
                if (m_ == l) {
                    d[l] = p; l = l + 1;
                    if (l <= lend) continue; else break;
                }
                if (m_ == l + 1) {
                    float rt1, rt2, cc, ss;
                    slaev2_(d[l], e[l], d[l+1], &rt1, &rt2, &cc, &ss);
                    for (int i = 1; i <= 3; ++i) {
                        float tmp = z[i][l+1];
                        z[i][l+1] = cc*tmp - ss*z[i][l];
                        z[i][l]   = ss*tmp + cc*z[i][l];
                    }
                    d[l] = rt1; d[l+1] = rt2; e[l] = 0.0f;
                    l = l + 2;
                    if (l <= lend) continue; else break;
                }
                if (jtot == nmaxit) break;
                jtot++;
                float g = (d[l+1] - p) / (2.0f*e[l]);
                float r = slapy2(g, 1.0f);
                g = d[m_] - p + (e[l] / (g + f_sign(r, g)));
                float s = 1.0f, c = 1.0f;
                p = 0.0f;
                for (int i = m_-1; i >= l; --i) {
                    float f = s*e[i];
                    float b = c*e[i];
                    slartg_(g, f, &c, &s, &r);
                    if (i != m_-1) e[i+1] = r;
                    g = d[i+1] - p;
                    r = (d[i] - g)*s + (2.0f*c)*b;
                    p = s*r;
                    d[i+1] = g + p;
                    g = c*r - b;
                    cw[i] = c; sw[i] = -s;
                }
                for (int j = m_-1; j >= l; --j) {
                    float cc = cw[j], ss = sw[j];
                    for (int i = 1; i <= 3; ++i) {
                        float tmp = z[i][j+1];
                        z[i][j+1] = cc*tmp - ss*z[i][j];
                        z[i][j]   = ss*tmp + cc*z[i][j];
                    }
                }
                d[l] = d[l] - p;
                e[l] = g;
            }
        } else {
            // QR
            while (true) {
                int m_ = lend;
                if (l != lend) {
                    for (int mi = l; mi >= lend+1; --mi) {
                        float em = e[mi-1];
                        float tst = em*em;
                        if (tst <= (SEPS2*fabsf(d[mi]))*fabsf(d[mi-1]) + SSAFMIN) { m_ = mi; break; }
                    }
                }
                if (m_ > lend) e[m_-1] = 0.0f;
                float p = d[l];
                if (m_ == l) {
                    d[l] = p; l = l - 1;
                    if (l >= lend) continue; else break;
                }
                if (m_ == l - 1) {
                    float rt1, rt2, cc, ss;
                    slaev2_(d[l-1], e[l-1], d[l], &rt1, &rt2, &cc, &ss);
                    for (int i = 1; i <= 3; ++i) {
                        float tmp = z[i][l];
                        z[i][l]   = cc*tmp - ss*z[i][l-1];
                        z[i][l-1] = ss*tmp + cc*z[i][l-1];
                    }
                    d[l-1] = rt1; d[l] = rt2; e[l-1] = 0.0f;
                    l = l - 2;
                    if (l >= lend) continue; else break;
                }
                if (jtot == nmaxit) break;
                jtot++;
                float g = (d[l-1] - p) / (2.0f*e[l-1]);
                float r = slapy2(g, 1.0f);
                g = d[m_] - p + (e[l-1] / (g + f_sign(r, g)));
                float s = 1.0f, c = 1.0f;
                p = 0.0f;
                for (int i = m_; i <= l-1; ++i) {
                    float f = s*e[i];
                    float b = c*e[i];
                    slartg_(g, f, &c, &s, &r);
                    if (i != m_) e[i-1] = r;
                    g = d[i] - p;
                    r = (d[i+1] - g)*s + (2.0f*c)*b;
                    p = s*r;
                    d[i] = g + p;
                    g = c*r - b;
                    cw[i] = c; sw[i] = s;
                }
                for (int j = m_; j <= l-1; ++j) {
                    float cc = cw[j], ss = sw[j];
                    for (int i = 1; i <= 3; ++i) {
                        float tmp = z[i][j+1];
                        z[i][j+1] = cc*tmp - ss*z[i][j];
                        z[i][j]   = ss*tmp + cc*z[i][j];
                    }
                }
                d[l] = d[l] - p;
                e[l-1] = g;
            }
        }
    }
    for (int ii = 2; ii <= 3; ++ii) {
        int i = ii - 1, k = i;
        float p = d[i];
        for (int j = ii; j <= 3; ++j) if (d[j] < p) { k = j; p = d[j]; }
        if (k != i) {
            d[k] = d[i]; d[i] = p;
            for (int r2 = 1; r2 <= 3; ++r2) {
                float t = z[r2][i]; z[r2][i] = z[r2][k]; z[r2][k] = t;
            }
        }
    }
    nv[0] = z[1][1]; nv[1] = z[2][1]; nv[2] = z[3][1];
}

// Covariance of the sorted 10-neighborhood (same op order as rounds 2-18).
__device__ void cov_compute(const float4* __restrict__ cl,
                            const unsigned long long keys[KNN], float c[6])
{
#pragma clang fp contract(off)
    float px[KNN], py[KNN], pz[KNN];
    float sx = 0.f, sy = 0.f, sz = 0.f;
    #pragma unroll
    for (int s = 0; s < KNN; ++s) {
        int ni = (int)(unsigned)(keys[s] & 0xFFFFFFFFull);
        float4 np = cl[ni];
        px[s] = np.x; py[s] = np.y; pz[s] = np.z;
        sx = sx + px[s]; sy = sy + py[s]; sz = sz + pz[s];
    }
    float mx = sx / 10.0f, my = sy / 10.0f, mz = sz / 10.0f;
    float c00=0.f,c01=0.f,c02=0.f,c11=0.f,c12=0.f,c22=0.f;
    #pragma unroll
    for (int s = 0; s < KNN; ++s) {
        float dx = px[s]-mx, dy = py[s]-my, dz = pz[s]-mz;
        c00 = c00 + dx*dx; c01 = c01 + dx*dy; c02 = c02 + dx*dz;
        c11 = c11 + dy*dy; c12 = c12 + dy*dz; c22 = c22 + dz*dz;
    }
    c[0] = c00/10.0f; c[1] = c01/10.0f; c[2] = c02/10.0f;
    c[3] = c11/10.0f; c[4] = c12/10.0f; c[5] = c22/10.0f;
}

// ---------------------------------------------------------------------------
// Insert: gate = min(own 10th, quad bound). Dropping candidates >= the quad
// bound is exact: some lane already holds 10 strictly-better keys. In phase 2
// qbK is ~0ull so the gate degenerates to the (exact) own 10th.
// ---------------------------------------------------------------------------
#define PROC(p) do { \
    float ddx = qx - (p).x, ddy = qy - (p).y, ddz = qz - (p).z; \
    float dd = fmaf(ddz, ddz, fmaf(ddy, ddy, ddx*ddx)); \
    unsigned long long key = \
        ((unsigned long long)__float_as_uint(dd) << 32) | \
        (unsigned)__float_as_int((p).w); \
    if (key < kgate) { \
        unsigned long long ck = key; \
        _Pragma("unroll") \
        for (int s = 0; s < KNN; ++s) { \
            unsigned long long ok2 = keys[s]; \
            bool sw = ok2 > ck; \
            keys[s] = sw ? ck : ok2; \
            ck      = sw ? ok2 : ck; \
        } \
        k9 = keys[KNN-1]; \
        kgate = (k9 < qbK) ? k9 : qbK; \
    } \
} while (0)

// R24 cooperative stride-4 segment walk: the QUAD jointly covers [bgn,end);
// lane sub takes elements bgn+sub, +4, +8, ... Perfect quad balance (steps =
// ceil(len/4), no per-lane row raggedness) and the quad's 4 loads are one
// contiguous 64B chunk (4x fewer cache lines per step than per-lane rows).
// Disjointness across lanes preserved -> per-lane exact reservoirs.
#define SEGPROC(bgn, end) do { \
    int _j = (bgn) + sub, _je = (end); \
    for (; _j + 4 < _je; _j += 8) { \
        float4 _p0 = cs[_j]; float4 _p1 = cs[_j+4]; \
        PROC(_p0); PROC(_p1); \
    } \
    if (_j < _je) { float4 _p0 = cs[_j]; PROC(_p0); } \
} while (0)

// quad-min of the four lanes' current 10th keys; low word forced to all-ones
// so ties on the distance bits still pass the gate (tie-exact).
#define QEXCH() do { \
    unsigned long long _o1 = __shfl_xor(k9, 1, 4); \
    unsigned long long _m1 = (_o1 < k9) ? _o1 : k9; \
    unsigned long long _o2 = __shfl_xor(_m1, 2, 4); \
    unsigned long long _qm = (_o2 < _m1) ? _o2 : _m1; \
    qbK = _qm | 0xFFFFFFFFull; \
    kgate = (k9 < qbK) ? k9 : qbK; \
} while (0)

// R24 quad EXTRACTION merge: 10 rounds; per round a 2-stage u64-min butterfly
// finds the global min of the 4 sorted lists, every lane records it, every
// lane whose head equals it shifts down (shared keys collapse -> natural
// dedupe). Exact top-10 of the union, ascending, IDENTICAL in all 4 lanes.
#define QMERGE() do { \
    unsigned long long fin[KNN]; \
    _Pragma("unroll") \
    for (int r = 0; r < KNN; ++r) { \
        unsigned long long m = keys[0]; \
        unsigned long long _o1 = __shfl_xor(m, 1, 4); m = (_o1 < m) ? _o1 : m; \
        unsigned long long _o2 = __shfl_xor(m, 2, 4); m = (_o2 < m) ? _o2 : m; \
        fin[r] = m; \
        bool own = (keys[0] == m); \
        _Pragma("unroll") \
        for (int t = 0; t < KNN-1; ++t) keys[t] = own ? keys[t+1] : keys[t]; \
        keys[KNN-1] = own ? 0xFFFFFFFFFFFFFFFFull : keys[KNN-1]; \
    } \
    _Pragma("unroll") \
    for (int s = 0; s < KNN; ++s) keys[s] = fin[s]; \
    k9 = keys[KNN-1]; \
} while (0)

// ---------------------------------------------------------------------------
// Kernel D (R24, unchanged in R25): grid 10-NN, FOUR lanes per query.
// Cooperative stride-4 cube walk, quad extraction-merge -> exact cube top-10
// -> exact phase-2 skip + tight worstM pruning -> cooperative shell walk ->
// final extraction-merge. R23 block swizzle kept. Bit-identical output.
// ---------------------------------------------------------------------------
__global__ __launch_bounds__(256) void knn_main_kernel(
    const float4* __restrict__ P4, const float4* __restrict__ S,
    const int2* __restrict__ combo, float4* __restrict__ Cov,
    int* __restrict__ ovf, unsigned long long* __restrict__ ovf_key,
    int* __restrict__ ovf_count)
{
    int b = blockIdx.x;                         // 0..1023
    int bb = ((b & 31) << 5) | (b >> 5);        // 5<->5 bit swap (bijective)
    int tidg = bb * 256 + threadIdx.x;          // 0..262143
    int qid  = tidg >> 2;                       // 0..65535
    int sub  = tidg & 3;
    int pair = qid >> 13;                       // 8 clouds
    int spos = qid & (NN - 1);                  // sorted position
    const float4* __restrict__ cl = P4 + (size_t)pair * NN;
    const float4* __restrict__ cs = S  + (size_t)pair * NN;
    const int2*   __restrict__ cb = combo + (size_t)pair * NCELLS;

    float4 q = cs[spos];
    float qx = q.x, qy = q.y, qz = q.z;
    int qi = __float_as_int(q.w);               // original index in cloud
    int qcx = cellc(qx), qcy = cellc(qy), qcz = cellc(qz);

    unsigned long long keys[KNN];
    #pragma unroll
    for (int s = 0; s < KNN; ++s) keys[s] = 0xFFFFFFFFFFFFFFFFull;
    unsigned long long k9    = 0xFFFFFFFFFFFFFFFFull;
    unsigned long long qbK   = 0xFFFFFFFFFFFFFFFFull;
    unsigned long long kgate = 0xFFFFFFFFFFFFFFFFull;

    // ---- phase 1: rho<=1 cube = 9 (z,y) rows, center-out order so gates
    // tighten early; QEXCH between rows shares the quad bound.
    int x0 = max(qcx - 1, 0), x1 = min(qcx + 1, G - 1);
    {
        const int DZ9[9] = { 0,  0,  0, -1,  1, -1, -1,  1,  1};
        const int DY9[9] = { 0,  1, -1,  0,  0, -1,  1, -1,  1};
        int rb[9], re[9];
        #pragma unroll
        for (int r = 0; r < 9; ++r) {
            int zz = qcz + DZ9[r], yy = qcy + DY9[r];
            rb[r] = 0; re[r] = 0;
            if ((unsigned)zz < G && (unsigned)yy < G) {
                int cbase = (zz*G + yy)*G;
                int2 a  = cb[cbase + x0];
                int2 b2 = cb[cbase + x1];
                rb[r] = a.x; re[r] = b2.x + b2.y;
            }
        }
        #pragma unroll
        for (int r = 0; r < 9; ++r) {
            SEGPROC(rb[r], re[r]);
            if (r == 0 || r == 2 || r == 4 || r == 6) QEXCH();
        }
    }

    // ---- quad extraction-merge -> exact cube top-10, identical in all lanes
    QMERGE();
    const unsigned long long k9M = k9;          // exact cube 10th (u64 key)
    float worstM = __uint_as_float((unsigned)(k9M >> 32)); // NaN if <10 found

    // ---- phase 2: rho=2 shell. Exterior of the cube is >= H from q, so
    // skip iff H^2 > worstM is EXACT (NaN-safe: NaN -> walk shell).
    bool skip = (H*H > worstM);                 // quad-uniform (worstM shared)

    qbK   = 0xFFFFFFFFFFFFFFFFull;              // phase-2 gate = own 10th
    kgate = k9;
    if (!skip) {
        int xs0 = max(qcx - 2, 0), xs1 = min(qcx + 2, G - 1);
        // 16 outer rows; box test redundant in all 4 lanes (same q -> same
        // result, quad-uniform branch), then cooperative stride-4 walk.
        const int SZ16[16] = {-2,-2,-2,-2,-2,  2, 2, 2, 2, 2, -1,-1, 0, 0, 1, 1};
        const int SY16[16] = {-2,-1, 0, 1, 2, -2,-1, 0, 1, 2, -2, 2,-2, 2,-2, 2};
        #pragma unroll
        for (int r = 0; r < 16; ++r) {
            int zz = qcz + SZ16[r], yy = qcy + SY16[r];
            if ((unsigned)zz < G && (unsigned)yy < G) {
                float loy = fmaf((float)yy, H, GRID_LO);
                float loz = fmaf((float)zz, H, GRID_LO);
                float py = fmaxf(0.0f, fmaxf(loy - qy, qy - (loy + H)));
                float pz = fmaxf(0.0f, fmaxf(loz - qz, qz - (loz + H)));
                float pyz = fmaf(pz, pz, py*py);
                if (!(pyz > worstM)) {
                    int cbase = (zz*G + yy)*G;
                    int2 a  = cb[cbase + xs0];
                    int2 b2 = cb[cbase + xs1];
                    SEGPROC(a.x, b2.x + b2.y);
                }
            }
        }
        // 18 isolated cells (|dz|<=1,|dy|<=1, dx=+/-2)
        const int CZ18[18] = {-1,-1,-1,-1,-1,-1,  0, 0, 0, 0, 0, 0,  1, 1, 1, 1, 1, 1};
        const int CY18[18] = {-1,-1, 0, 0, 1, 1, -1,-1, 0, 0, 1, 1, -1,-1, 0, 0, 1, 1};
        const int CX18[18] = {-2, 2,-2, 2,-2, 2, -2, 2,-2, 2,-2, 2, -2, 2,-2, 2,-2, 2};
        #pragma unroll
        for (int r = 0; r < 18; ++r) {
            int zz = qcz + CZ18[r], yy = qcy + CY18[r], xx = qcx + CX18[r];
            if ((unsigned)zz < G && (unsigned)yy < G && (unsigned)xx < G) {
                float lox = fmaf((float)xx, H, GRID_LO);
                float loy = fmaf((float)yy, H, GRID_LO);
                float loz = fmaf((float)zz, H, GRID_LO);
                float px = fmaxf(0.0f, fmaxf(lox - qx, qx - (lox + H)));
                float py = fmaxf(0.0f, fmaxf(loy - qy, qy - (loy + H)));
                float pz = fmaxf(0.0f, fmaxf(loz - qz, qz - (loz + H)));
                float m2 = fmaf(pz, pz, fmaf(py, py, px*px));
                if (!(m2 > worstM)) {
                    int2 a = cb[(zz*G + yy)*G + xx];
                    SEGPROC(a.x, a.x + a.y);
                }
            }
        }
    }

    // ---- final: extraction-merge again, but only if some lane inserted a
    // shell candidate (every successful insert strictly lowers k9). Shared
    // cube survivors are held by all 4 lanes -> all owners shift in the same
    // round -> natural exact dedupe. skip and ch are quad-uniform.
    if (!skip) {
        int ch = (k9 != k9M) ? 1 : 0;
        ch |= __shfl_xor(ch, 1, 4);
        ch |= __shfl_xor(ch, 2, 4);
        if (ch) QMERGE();
    }
    float worst_m = __uint_as_float((unsigned)(k9 >> 32));

    // resolved iff cells beyond the rho<=2 region (gap >= 2H) cannot contribute
    float bf = (float)RCAP * H;
    bool resolved = (bf*bf > worst_m);          // strict; NaN (unfilled) -> false
    if (resolved && sub == 0) {
        float c[6];
        cov_compute(cl, keys, c);               // sub==0 only: 1/4 gather loads
        size_t o = ((size_t)pair*NN + qi)*2;
        Cov[o]   = make_float4(c[0], c[1], c[2], c[3]);
        Cov[o+1] = make_float4(c[4], c[5], 0.0f, 0.0f);
    } else if (!resolved && sub == 0) {
        int pos = atomicAdd(ovf_count, 1);
        ovf[pos] = (pair << 13) | qi;
        ovf_key[pos] = k9;      // exact 10th over examined set: valid upper
    }                           // bound on the true 10th key
}

// ---------------------------------------------------------------------------
// Kernel D2 (R25): brute-force overflow, ONE BLOCK (256 thr = 4 waves) per
// query. R22's one-wave version had ~2240 waves total (2.2/SIMD, occupancy
// 7.7%) and its whole runtime was the per-wave serial scan whose insert chain
// fires at wave-union frequency (NaN/loose-bound queries pass the gate for
// most candidates early). Block-per-query quarters per-wave candidate steps
// (128 -> 32) AND 4x's the wave count (TLP). Merge path: per-wave 10-round
// extraction (exact, ascending), lane 0 posts to LDS, thread 0 runs a 4-list
// head-pointer extraction merge (keys unique; sentinel ~0 ties advance all
// lists harmlessly — reads precede advances, index <= round <= 9). >=10 real
// keys survive block-wide (true 10-NN all pass the bound gate), so the final
// 10 are real. Exact top-10 by u64 value is partition-independent => same
// ascending list as R22 => bit-identical cov => absmax 0.0.
// ---------------------------------------------------------------------------
#define BRUTE_BLOCKS 2048
__global__ __launch_bounds__(256) void brute_kernel(
    const float4* __restrict__ P4, const int* __restrict__ ovf,
    const unsigned long long* __restrict__ ovf_key,
    const int* __restrict__ ovf_count, float4* __restrict__ Cov)
{
    __shared__ unsigned long long wl[4][KNN];
    int tid = threadIdx.x;
    int lane = tid & 63;
    int wid = tid >> 6;
    int count = *ovf_count;

    for (int oi = blockIdx.x; oi < count; oi += BRUTE_BLOCKS) {
        int rec = ovf[oi];
        unsigned long long bound = ovf_key[oi];
        float bound_d = __uint_as_float((unsigned)(bound >> 32)); // NaN if unfilled
        int pair = rec >> 13;
        int qi = rec & (NN - 1);
        const float4* __restrict__ cl = P4 + (size_t)pair * NN;
        float4 q = cl[qi];
        float qx = q.x, qy = q.y, qz = q.z;

        unsigned long long keys[KNN];
        #pragma unroll
        for (int s = 0; s < KNN; ++s) keys[s] = 0xFFFFFFFFFFFFFFFFull;
        unsigned long long k9 = keys[KNN-1];

        // per-thread scan of a disjoint 1/256 slice (32 candidates), bound-
        // gated; ties at dd==bound_d pass (exact). Coalesced cl[i*256+tid].
#define BPROC(p, jj) do { \
        float ddx = qx - (p).x, ddy = qy - (p).y, ddz = qz - (p).z; \
        float dd = fmaf(ddz, ddz, fmaf(ddy, ddy, ddx*ddx)); \
        if (!(dd > bound_d)) { \
            unsigned long long key = \
                ((unsigned long long)__float_as_uint(dd) << 32) | (unsigned)(jj); \
            if (key < k9) { \
                unsigned long long ck = key; \
                _Pragma("unroll") \
                for (int s = 0; s < KNN; ++s) { \
                    unsigned long long ok2 = keys[s]; \
                    bool sw = ok2 > ck; \
                    keys[s] = sw ? ck : ok2; \
                    ck      = sw ? ok2 : ck; \
                } \
                k9 = keys[KNN-1]; \
            } \
        } \
    } while (0)
        #pragma unroll 1
        for (int i = 0; i < 32; i += 4) {       // 8 iters, 4 loads in flight
            float4 p0 = cl[(i+0)*256 + tid];
            float4 p1 = cl[(i+1)*256 + tid];
            float4 p2 = cl[(i+2)*256 + tid];
            float4 p3 = cl[(i+3)*256 + tid];
            BPROC(p0, (i+0)*256 + tid);
            BPROC(p1, (i+1)*256 + tid);
            BPROC(p2, (i+2)*256 + tid);
            BPROC(p3, (i+3)*256 + tid);
        }
#undef BPROC

        // per-wave 10-round extraction merge: exact wave top-10, ascending,
        // identical in all 64 lanes (sentinel ties shift all owners — safe).
        unsigned long long fin[KNN];
        #pragma unroll
        for (int r = 0; r < KNN; ++r) {
            unsigned long long m = keys[0];
            #pragma unroll
            for (int off = 1; off < 64; off <<= 1) {
                unsigned long long o = __shfl_xor(m, off);
                m = (o < m) ? o : m;
            }
            fin[r] = m;
            if (keys[0] == m) {
                #pragma unroll
                for (int t = 0; t < KNN-1; ++t) keys[t] = keys[t+1];
                keys[KNN-1] = 0xFFFFFFFFFFFFFFFFull;
            }
        }

        if (lane == 0) {
            #pragma unroll
            for (int s = 0; s < KNN; ++s) wl[wid][s] = fin[s];
        }
        __syncthreads();
        if (tid == 0) {
            // 4-list head-pointer extraction merge (lists sorted ascending).
            // Real keys unique -> exactly one list advances; equal sentinels
            // advance together (reads precede advances; idx <= round <= 9).
            int i0 = 0, i1 = 0, i2 = 0, i3 = 0;
            unsigned long long outk[KNN];
            #pragma unroll
            for (int r = 0; r < KNN; ++r) {
                unsigned long long h0 = wl[0][i0], h1 = wl[1][i1];
                unsigned long long h2 = wl[2][i2], h3 = wl[3][i3];
                unsigned long long m01 = (h0 < h1) ? h0 : h1;
                unsigned long long m23 = (h2 < h3) ? h2 : h3;
                unsigned long long m   = (m01 < m23) ? m01 : m23;
                outk[r] = m;
                i0 += (h0 == m); i1 += (h1 == m);
                i2 += (h2 == m); i3 += (h3 == m);
            }
            float c[6];
            cov_compute(cl, outk, c);
            size_t o = ((size_t)pair*NN + qi)*2;
            Cov[o]   = make_float4(c[0], c[1], c[2], c[3]);
            Cov[o+1] = make_float4(c[4], c[5], 0.0f, 0.0f);
        }
        __syncthreads();                        // protect wl for next query
    }
}

// ---------------------------------------------------------------------------
// Kernel E (R19): fused eigh + loss, ONE eigh per thread over 2*BN threads.
// Thread 2k handles gt[k], thread 2k+1 handles pred[k]; normals exchanged
// in-wave via shfl_xor(1); even lanes compute 1-cos; block reduce; atomic.
// Identical eigh inputs -> bit-identical normals (summation grouping only).
// ---------------------------------------------------------------------------
__global__ __launch_bounds__(256) void eigh_loss_kernel(
    const float4* __restrict__ Cov, float* __restrict__ accum,
    unsigned* __restrict__ counter, float* __restrict__ out)
{
    int tid = threadIdx.x;
    int t = blockIdx.x * 256 + tid;            // 0..2*BN-1
    int k = t >> 1;                            // pair index 0..BN-1
    int cld = t & 1;                           // 0 = gt, 1 = pred
    size_t ci = ((size_t)(cld ? BN + k : k)) * 2;
    float4 a0 = Cov[ci], a1 = Cov[ci + 1];
    float n[3];
    eigh3_smallest(a0.x, a0.y, a0.z, a0.w, a1.x, a1.y, n);

    // exchange with partner lane (2k <-> 2k+1 always share a wave)
    float ox = __shfl_xor(n[0], 1);
    float oy = __shfl_xor(n[1], 1);
    float oz = __shfl_xor(n[2], 1);

    float v = 0.0f;
    if (cld == 0) {
        float gx=n[0], gy=n[1], gz=n[2];
        float hx=ox,  hy=oy,  hz=oz;
        float dot = fmaf(gx,hx,fmaf(gy,hy,gz*hz));
        float ng  = sqrtf(fmaf(gx,gx,fmaf(gy,gy,gz*gz)));
        float nh  = sqrtf(fmaf(hx,hx,fmaf(hy,hy,hz*hz)));
        float den = fmaxf(ng*nh, 1e-8f);
        v = 1.0f - dot/den;
    }

    __shared__ float red[256];
    red[tid] = v;                              // odd lanes contribute 0
    __syncthreads();
    for (int s = 128; s > 0; s >>= 1) {
        if (tid < s) red[tid] += red[tid+s];
        __syncthreads();
    }
    if (tid == 0) {
        atomicAdd(accum, red[0]);
        __threadfence();
        unsigned old = atomicAdd(counter, 1u);
        if (old == (unsigned)(2*BN/256 - 1)) {
            float tot = atomicAdd(accum, 0.0f);
            out[0] = tot * (1.0f/(float)BN);
        }
    }
}

// ---------------------------------------------------------------------------
extern "C" void kernel_launch(void* const* d_in, const int* in_sizes, int n_in,
                              void* d_out, int out_size, void* d_ws, size_t ws_size,
                              hipStream_t stream)
{
    (void)in_sizes; (void)n_in; (void)out_size; (void)ws_size;
    const float*    gt   = (const float*)d_in[0];
    const float*    pred = (const float*)d_in[1];
    const unsigned* idxw = (const unsigned*)d_in[2];
    float* out = (float*)d_out;

    char* w = (char*)d_ws;
    float4* P4   = (float4*)w;                         w += (size_t)2*BN*16;   // 1 MB
    float4* S    = (float4*)w;                         w += (size_t)2*BN*16;   // 1 MB
    int*    hist = (int*)w;                            w += (size_t)8*NCELLS*4;   // 1 MB
    int2*   combo = (int2*)w;                          w += (size_t)8*NCELLS*8;   // 2 MB
    float4* Cov  = (float4*)w;                         w += (size_t)2*BN*32;   // 2 MB
    float*  accum = (float*)w;                         w += 16;
    unsigned* counter = (unsigned*)(accum + 1);
    int*    ovf_count = (int*)(accum + 2);
    int*    ovf  = (int*)w;                            w += (size_t)2*BN*4;    // 0.25 MB
    unsigned long long* ovf_key = (unsigned long long*)w;  w += (size_t)2*BN*8; // 0.5 MB

    hipMemsetAsync(hist, 0, (size_t)8*NCELLS*4, stream);
    hipLaunchKernelGGL(prep_kernel,    dim3(2*BN/256), dim3(256),  0, stream,
                       gt, pred, idxw, P4, hist, accum, counter, ovf_count);
    hipLaunchKernelGGL(scan_kernel,    dim3(8),        dim3(1024), 0, stream,
                       hist, combo);
    hipLaunchKernelGGL(scatter_kernel, dim3(2*BN/256), dim3(256),  0, stream,
                       P4, hist, combo, S);
    hipLaunchKernelGGL(knn_main_kernel, dim3(2*BN*4/256), dim3(256), 0, stream,
                       P4, S, combo, Cov, ovf, ovf_key, ovf_count);
    hipLaunchKernelGGL(brute_kernel,   dim3(BRUTE_BLOCKS), dim3(256), 0, stream,
                       P4, ovf, ovf_key, ovf_count, Cov);
    hipLaunchKernelGGL(eigh_loss_kernel, dim3(2*BN/256), dim3(256), 0, stream,
                       Cov, accum, counter, out);
}